// Round 2
// baseline (3366.392 us; speedup 1.0000x reference)
//
#include <hip/hip_runtime.h>
#include <hip/hip_bf16.h>
#include <math.h>

#define N_NODES 51200
#define N_GRAPHS 512
#define S_NODES 100
#define N_EDGES 512000
#define HDF 256          // H*D
#define NEGF (-1e30f)
#define MAXD 256

// ---------------------------------------------------------------- util
__global__ void set_int(int* __restrict__ p, int v, int n) {
    int i = blockIdx.x * 256 + threadIdx.x;
    if (i < n) p[i] = v;
}

// ---------------------------------------------------------------- GEMM fp32 (plain, out != A)
// C[rows x NC] = A[rows x K] @ B[K x NC] (+ bias). grid = (NC/64, rows/64).
__global__ __launch_bounds__(256) void gemm_bias(
    const float* __restrict__ A, const float* __restrict__ B,
    const float* __restrict__ bias, float* __restrict__ C,
    int K, int NC)
{
    __shared__ float As[16][65];
    __shared__ float Bs[16][64];
    int row0 = blockIdx.y * 64, col0 = blockIdx.x * 64;
    int t = threadIdx.x;
    int tr = t >> 4, tc = t & 15;
    float acc[4][4] = {{0.f}};
    int mA = t >> 2, kqA = (t & 3) << 2;
    int kB = t >> 4, nqB = (t & 15) << 2;
    for (int k0 = 0; k0 < K; k0 += 16) {
        float4 av = *(const float4*)(A + (size_t)(row0 + mA) * K + k0 + kqA);
        As[kqA + 0][mA] = av.x; As[kqA + 1][mA] = av.y;
        As[kqA + 2][mA] = av.z; As[kqA + 3][mA] = av.w;
        float4 bv = *(const float4*)(B + (size_t)(k0 + kB) * NC + col0 + nqB);
        *(float4*)&Bs[kB][nqB] = bv;
        __syncthreads();
        #pragma unroll
        for (int kk = 0; kk < 16; ++kk) {
            float ra[4], rb[4];
            #pragma unroll
            for (int i = 0; i < 4; ++i) ra[i] = As[kk][tr * 4 + i];
            #pragma unroll
            for (int j = 0; j < 4; ++j) rb[j] = Bs[kk][tc * 4 + j];
            #pragma unroll
            for (int i = 0; i < 4; ++i)
                #pragma unroll
                for (int j = 0; j < 4; ++j)
                    acc[i][j] += ra[i] * rb[j];
        }
        __syncthreads();
    }
    #pragma unroll
    for (int i = 0; i < 4; ++i) {
        int r = row0 + tr * 4 + i;
        int c = col0 + tc * 4;
        float4 o;
        o.x = acc[i][0]; o.y = acc[i][1]; o.z = acc[i][2]; o.w = acc[i][3];
        if (bias) { o.x += bias[c]; o.y += bias[c + 1]; o.z += bias[c + 2]; o.w += bias[c + 3]; }
        *(float4*)(C + (size_t)r * NC + c) = o;
    }
}

// ------------------------------------------------- fused skip-GEMM (in-place safe)
// out[r, 0:256] = relu(agg[r,c] + A[r,:]@B + bias[c]) * nmask[r]
// Each block owns 64 rows x ALL 256 cols -> out may alias A (rows exclusive,
// all A reads complete before epilogue writes).
__global__ __launch_bounds__(256) void fused_skip_gemm(
    const float* __restrict__ A, const float* __restrict__ B,
    const float* __restrict__ bias, const float* __restrict__ agg, int aggStride,
    const int* __restrict__ nmaskArr, float* __restrict__ out, int K)
{
    __shared__ float As[16][65];
    __shared__ float Bs[16][256];
    int row0 = blockIdx.x * 64;
    int t = threadIdx.x;
    int tr = t >> 4, tc = t & 15;
    float4 acc[4][4];
    #pragma unroll
    for (int i = 0; i < 4; ++i)
        #pragma unroll
        for (int u = 0; u < 4; ++u) acc[i][u] = make_float4(0.f, 0.f, 0.f, 0.f);
    int mA = t >> 2, kqA = (t & 3) << 2;
    for (int k0 = 0; k0 < K; k0 += 16) {
        float4 av = *(const float4*)(A + (size_t)(row0 + mA) * K + k0 + kqA);
        As[kqA + 0][mA] = av.x; As[kqA + 1][mA] = av.y;
        As[kqA + 2][mA] = av.z; As[kqA + 3][mA] = av.w;
        #pragma unroll
        for (int u = 0; u < 4; ++u) {
            int idx = t + u * 256;          // 0..1023
            int row = idx >> 6;             // 0..15
            int colq = (idx & 63) << 2;     // 0..252
            float4 bv = *(const float4*)(B + (size_t)(k0 + row) * 256 + colq);
            *(float4*)&Bs[row][colq] = bv;
        }
        __syncthreads();
        #pragma unroll
        for (int kk = 0; kk < 16; ++kk) {
            float ra[4];
            #pragma unroll
            for (int i = 0; i < 4; ++i) ra[i] = As[kk][tr * 4 + i];
            #pragma unroll
            for (int u = 0; u < 4; ++u) {
                float4 rb = *(const float4*)&Bs[kk][tc * 4 + u * 64];
                #pragma unroll
                for (int i = 0; i < 4; ++i) {
                    acc[i][u].x += ra[i] * rb.x;
                    acc[i][u].y += ra[i] * rb.y;
                    acc[i][u].z += ra[i] * rb.z;
                    acc[i][u].w += ra[i] * rb.w;
                }
            }
        }
        __syncthreads();
    }
    #pragma unroll
    for (int i = 0; i < 4; ++i) {
        int r = row0 + tr * 4 + i;
        float nm = nmaskArr[r] ? 1.f : 0.f;
        #pragma unroll
        for (int u = 0; u < 4; ++u) {
            int c = tc * 4 + u * 64;
            float4 v = acc[i][u];
            float4 bv = *(const float4*)&bias[c];
            float4 av = *(const float4*)(agg + (size_t)r * aggStride + c);
            v.x = fmaxf(v.x + av.x + bv.x, 0.f) * nm;
            v.y = fmaxf(v.y + av.y + bv.y, 0.f) * nm;
            v.z = fmaxf(v.z + av.z + bv.z, 0.f) * nm;
            v.w = fmaxf(v.w + av.w + bv.w, 0.f) * nm;
            *(float4*)(out + (size_t)r * HDF + c) = v;
        }
    }
}

// ---------------------------------------------------------------- CSR build
__global__ void count_deg(const int* __restrict__ dst, int* __restrict__ deg) {
    int e = blockIdx.x * 256 + threadIdx.x;
    atomicAdd(&deg[dst[e]], 1);
}

__global__ __launch_bounds__(1024) void scan_deg(const int* __restrict__ deg,
                                                 int* __restrict__ rowStart) {
    __shared__ int part[1024];
    int t = threadIdx.x;
    const int chunk = N_NODES / 1024;      // 50
    int s = t * chunk;
    int sum = 0;
    for (int i = 0; i < chunk; ++i) sum += deg[s + i];
    part[t] = sum;
    __syncthreads();
    for (int d = 1; d < 1024; d <<= 1) {
        int v = (t >= d) ? part[t - d] : 0;
        __syncthreads();
        part[t] += v;
        __syncthreads();
    }
    int excl = (t == 0) ? 0 : part[t - 1];
    for (int i = 0; i < chunk; ++i) { rowStart[s + i] = excl; excl += deg[s + i]; }
    if (t == 1023) rowStart[N_NODES] = part[1023];
}

__global__ void scatter_edges(const int* __restrict__ dst, int* __restrict__ cursor,
                              const int* __restrict__ rowStart, int* __restrict__ edgeIdx) {
    int e = blockIdx.x * 256 + threadIdx.x;
    int d = dst[e];
    int p = atomicAdd(&cursor[d], 1);
    edgeIdx[rowStart[d] + p] = e;
}

// ---------------------------------------------------------------- GAT pieces
__global__ __launch_bounds__(256) void gat_att(const float* __restrict__ hfeat,
                                               const float* __restrict__ att,
                                               float* __restrict__ aS, float* __restrict__ aD) {
    int i = blockIdx.x, t = threadIdx.x, hh = t >> 6, d = t & 63;
    float hv = hfeat[(size_t)i * HDF + t];
    float p0 = hv * att[hh * 64 + d];
    float p1 = hv * att[256 + hh * 64 + d];
    #pragma unroll
    for (int o = 32; o > 0; o >>= 1) { p0 += __shfl_down(p0, o, 64); p1 += __shfl_down(p1, o, 64); }
    if (d == 0) { aS[i * 4 + hh] = p0; aD[i * 4 + hh] = p1; }
}

// per-dst attention aggregation -> aggOut (stride 256)
__global__ __launch_bounds__(256) void gat_edge(
    const float* __restrict__ hfeat, const float* __restrict__ aS, const float* __restrict__ aD,
    const int* __restrict__ rowStart, const int* __restrict__ edgeIdx,
    const int* __restrict__ srcArr, const int* __restrict__ emask, const int* __restrict__ nmask,
    float* __restrict__ aggOut)
{
    int i = blockIdx.x, t = threadIdx.x;
    int hh = t >> 6;
    __shared__ int sSrc[MAXD + 1];
    __shared__ float sL[MAXD + 1][4];
    if (!nmask[i]) { aggOut[(size_t)i * HDF + t] = 0.f; return; }
    int rs = rowStart[i], re = rowStart[i + 1];
    int deg = min(re - rs, MAXD);
    for (int j = t; j < deg; j += 256) {
        int e = edgeIdx[rs + j];
        int ok = emask[e];
        int s_ = srcArr[e];
        sSrc[j] = ok ? s_ : -1;
        #pragma unroll
        for (int h2 = 0; h2 < 4; ++h2) {
            float l = aS[s_ * 4 + h2] + aD[i * 4 + h2];
            l = (l >= 0.f) ? l : 0.2f * l;
            sL[j][h2] = ok ? l : NEGF;
        }
    }
    if (t == 0) {   // self loop, masked by nmask[i]==1 here
        sSrc[deg] = i;
        #pragma unroll
        for (int h2 = 0; h2 < 4; ++h2) {
            float l = aS[i * 4 + h2] + aD[i * 4 + h2];
            sL[deg][h2] = (l >= 0.f) ? l : 0.2f * l;
        }
    }
    __syncthreads();
    int tot = deg + 1;
    float m = NEGF;
    for (int j = 0; j < tot; ++j) if (sSrc[j] >= 0) m = fmaxf(m, sL[j][hh]);
    float ssum = 0.f;
    for (int j = 0; j < tot; ++j) if (sSrc[j] >= 0) ssum += expf(sL[j][hh] - m);
    float inv = 1.f / fmaxf(ssum, 1e-16f);
    float acc = 0.f;
    for (int j = 0; j < tot; ++j) {
        int s_ = sSrc[j];
        if (s_ < 0) continue;
        float a = expf(sL[j][hh] - m) * inv;
        acc += a * hfeat[(size_t)s_ * HDF + t];
    }
    aggOut[(size_t)i * HDF + t] = acc;
}

// ---------------------------------------------------------------- GT piece
// qkv row layout: [q(256) | k(256) | v(256)]. Writes agg over OWN q-slot:
// thread t reads only q[i*768+t] (before) and writes q[i*768+t] (after);
// other blocks never read this block's q row -> race-free.
__global__ __launch_bounds__(256) void gt_edge(
    float* __restrict__ qkv,
    const int* __restrict__ rowStart, const int* __restrict__ edgeIdx,
    const int* __restrict__ srcArr, const int* __restrict__ emask, const int* __restrict__ nmask)
{
    int i = blockIdx.x, t = threadIdx.x;
    int hh = t >> 6, d = t & 63;
    __shared__ int sSrc[MAXD];
    __shared__ float sL[MAXD][4];
    if (!nmask[i]) { qkv[(size_t)i * 768 + t] = 0.f; return; }
    int rs = rowStart[i], re = rowStart[i + 1];
    int deg = min(re - rs, MAXD);
    float qv = qkv[(size_t)i * 768 + t];
    for (int j = 0; j < deg; ++j) {       // each wave handles its own head
        int e = edgeIdx[rs + j];
        int ok = emask[e];
        int s_ = srcArr[e];
        float p = qv * qkv[(size_t)s_ * 768 + 256 + t];
        #pragma unroll
        for (int o = 32; o > 0; o >>= 1) p += __shfl_down(p, o, 64);
        if (d == 0) { sSrc[j] = ok ? s_ : -1; sL[j][hh] = ok ? p * 0.125f : NEGF; }
    }
    __syncthreads();
    float m = NEGF;
    for (int j = 0; j < deg; ++j) if (sSrc[j] >= 0) m = fmaxf(m, sL[j][hh]);
    float ssum = 0.f;
    for (int j = 0; j < deg; ++j) if (sSrc[j] >= 0) ssum += expf(sL[j][hh] - m);
    float inv = 1.f / fmaxf(ssum, 1e-16f);
    float acc = 0.f;
    for (int j = 0; j < deg; ++j) {
        int s_ = sSrc[j];
        if (s_ < 0) continue;
        float a = expf(sL[j][hh] - m) * inv;
        acc += a * qkv[(size_t)s_ * 768 + 512 + t];
    }
    qkv[(size_t)i * 768 + t] = acc;
}

// ---------------------------------------------------------------- pooling
__global__ __launch_bounds__(256) void score_kernel(const float* __restrict__ x,
                                                    const float* __restrict__ w,
                                                    float* __restrict__ score) {
    int wave = threadIdx.x >> 6, lane = threadIdx.x & 63;
    int node = blockIdx.x * 4 + wave;
    float dx = 0.f, dw = 0.f;
    #pragma unroll
    for (int c = 0; c < 4; ++c) {
        int cc = lane + c * 64;
        float wv = w[cc];
        dx += x[(size_t)node * HDF + cc] * wv;
        dw += wv * wv;
    }
    #pragma unroll
    for (int o = 32; o > 0; o >>= 1) { dx += __shfl_down(dx, o, 64); dw += __shfl_down(dw, o, 64); }
    if (lane == 0) score[node] = tanhf(dx / sqrtf(dw));
}

__global__ __launch_bounds__(128) void pool_kernel(const float* __restrict__ score,
                                                   int* __restrict__ nmask) {
    int g = blockIdx.x, t = threadIdx.x;
    __shared__ float kv[128];
    __shared__ int cnt_s;
    if (t == 0) cnt_s = 0;
    int alive = 0;
    float ck = -2.0f;
    int node = g * S_NODES + t;
    if (t < S_NODES) { alive = nmask[node]; ck = alive ? score[node] : -1.5f; }
    kv[t] = ck;
    __syncthreads();
    if (alive) atomicAdd(&cnt_s, 1);
    __syncthreads();
    int k = (int)ceilf(0.8f * (float)cnt_s);   // f32, matches jnp.ceil(RATIO*n)
    int rank = 0;
    for (int j = 0; j < S_NODES; ++j) {
        float o = kv[j];
        rank += (o > ck || (o == ck && j < t)) ? 1 : 0;  // stable desc
    }
    if (t < S_NODES) nmask[node] = (alive && rank < k) ? 1 : 0;
}

__global__ void emask_update(const int* __restrict__ srcArr, const int* __restrict__ dstArr,
                             const int* __restrict__ nmask, int* __restrict__ emask) {
    int e = blockIdx.x * 256 + threadIdx.x;
    emask[e] = (emask[e] && nmask[srcArr[e]] && nmask[dstArr[e]]) ? 1 : 0;
}

__global__ void apply_pool(float* __restrict__ x, const float* __restrict__ score,
                           const int* __restrict__ nmask) {
    size_t idx = (size_t)blockIdx.x * 256 + threadIdx.x;
    int node = (int)(idx >> 8);
    x[idx] = nmask[node] ? x[idx] * score[node] : 0.f;
}

__global__ __launch_bounds__(256) void readout_kernel(const float* __restrict__ x,
                                                      const int* __restrict__ nmask,
                                                      float* __restrict__ acc) {
    int g = blockIdx.x, c = threadIdx.x;
    float mx = NEGF, sm = 0.f, cnt = 0.f;
    int base = g * S_NODES;
    for (int o = 0; o < S_NODES; ++o) {
        if (nmask[base + o]) {
            float v = x[(size_t)(base + o) * HDF + c];
            mx = fmaxf(mx, v);
            sm += v;
            cnt += 1.f;
        }
    }
    acc[(size_t)g * 512 + c] += mx;
    acc[(size_t)g * 512 + 256 + c] += sm / fmaxf(cnt, 1.f);
}

// ---------------------------------------------------------------- MLP head
__global__ __launch_bounds__(128) void mlp_kernel(
    const float* __restrict__ acc1, const float* __restrict__ acc2,
    const float* __restrict__ W1, const float* __restrict__ b1,
    const float* __restrict__ W2, const float* __restrict__ b2,
    const float* __restrict__ W3, const float* __restrict__ b3,
    float* __restrict__ out)
{
    int g = blockIdx.x, t = threadIdx.x;
    __shared__ float hrow[1024];
    __shared__ float h1s[128];
    __shared__ float h2s[64];
    __shared__ float o3[10];
    for (int j = t; j < 512; j += 128) {
        hrow[j] = acc1[(size_t)g * 512 + j];
        hrow[512 + j] = acc2[(size_t)g * 512 + j];
    }
    __syncthreads();
    float s = b1[t];
    for (int kx = 0; kx < 1024; ++kx) s += hrow[kx] * W1[(size_t)kx * 128 + t];
    h1s[t] = fmaxf(s, 0.f);
    __syncthreads();
    if (t < 64) {
        float s2 = b2[t];
        for (int kx = 0; kx < 128; ++kx) s2 += h1s[kx] * W2[kx * 64 + t];
        h2s[t] = fmaxf(s2, 0.f);
    }
    __syncthreads();
    if (t < 10) {
        float s3 = b3[t];
        for (int kx = 0; kx < 64; ++kx) s3 += h2s[kx] * W3[kx * 10 + t];
        o3[t] = s3;
    }
    __syncthreads();
    if (t < 10) {
        float m = o3[0];
        for (int j = 1; j < 10; ++j) m = fmaxf(m, o3[j]);
        float se = 0.f;
        for (int j = 0; j < 10; ++j) se += expf(o3[j] - m);
        out[g * 10 + t] = o3[t] - m - logf(se);
    }
}

// ---------------------------------------------------------------- launch
extern "C" void kernel_launch(void* const* d_in, const int* in_sizes, int n_in,
                              void* d_out, int out_size, void* d_ws, size_t ws_size,
                              hipStream_t stream) {
    (void)n_in; (void)out_size; (void)ws_size;
    const float* x0 = (const float*)d_in[0];
    const int* src = (const int*)d_in[1];
    const int* dst = src + N_EDGES;

    // dict order per harness doc; grouped-signature fallback kept for safety
    bool dictOrder = (in_sizes[7] == 64 * 768);
    const float *gatW[3], *gatAtt[3], *gatB[3], *gatRes[3];
    const float *gtWqkv[3], *gtBqkv[3], *gtWskip[3], *gtBskip[3];
    const float *gatPool, *gtPool;
    if (dictOrder) {
        for (int l = 0; l < 3; ++l) {
            int b = 3 + l * 8;
            gatW[l]    = (const float*)d_in[b + 0];
            gatAtt[l]  = (const float*)d_in[b + 1];
            gatB[l]    = (const float*)d_in[b + 2];
            gatRes[l]  = (const float*)d_in[b + 3];
            gtWqkv[l]  = (const float*)d_in[b + 4];
            gtBqkv[l]  = (const float*)d_in[b + 5];
            gtWskip[l] = (const float*)d_in[b + 6];
            gtBskip[l] = (const float*)d_in[b + 7];
        }
        gatPool = (const float*)d_in[27];
        gtPool  = (const float*)d_in[28];
    } else {
        for (int l = 0; l < 3; ++l) {
            int b = 3 + l * 4;
            gatW[l]   = (const float*)d_in[b + 0];
            gatAtt[l] = (const float*)d_in[b + 1];
            gatB[l]   = (const float*)d_in[b + 2];
            gatRes[l] = (const float*)d_in[b + 3];
            int c = 16 + l * 4;
            gtWqkv[l]  = (const float*)d_in[c + 0];
            gtBqkv[l]  = (const float*)d_in[c + 1];
            gtWskip[l] = (const float*)d_in[c + 2];
            gtBskip[l] = (const float*)d_in[c + 3];
        }
        gatPool = (const float*)d_in[15];
        gtPool  = (const float*)d_in[28];
    }
    const float* lin1W = (const float*)d_in[29];
    const float* lin1b = (const float*)d_in[30];
    const float* lin2W = (const float*)d_in[31];
    const float* lin2b = (const float*)d_in[32];
    const float* lin3W = (const float*)d_in[33];
    const float* lin3b = (const float*)d_in[34];

    char* wsp = (char*)d_ws;
    size_t off = 0;
    auto carve = [&](size_t bytes) -> void* {
        void* p = wsp + off;
        off += (bytes + 255) & ~(size_t)255;
        return p;
    };
    float* bufX   = (float*)carve((size_t)N_NODES * HDF * 4);   // 52.4 MB
    float* bufH   = (float*)carve((size_t)N_NODES * 768 * 4);   // 157.3 MB
    float* aS     = (float*)carve((size_t)N_NODES * 4 * 4);
    float* aD     = (float*)carve((size_t)N_NODES * 4 * 4);
    float* scoreB = (float*)carve((size_t)N_NODES * 4);
    int* nmask    = (int*)carve((size_t)N_NODES * 4);
    int* emask    = (int*)carve((size_t)N_EDGES * 4);
    int* deg      = (int*)carve((size_t)N_NODES * 4);
    int* rowStart = (int*)carve((size_t)(N_NODES + 1) * 4);
    int* cursor   = (int*)carve((size_t)N_NODES * 4);
    int* edgeIdx  = (int*)carve((size_t)N_EDGES * 4);
    float* acc1   = (float*)carve((size_t)N_GRAPHS * 512 * 4);
    float* acc2   = (float*)carve((size_t)N_GRAPHS * 512 * 4);
    float* ysec   = bufH + (size_t)N_NODES * HDF;   // spare 2/3 of bufH for GAT agg

    // zero-init via kernels (no hipMemsetAsync anywhere)
    set_int<<<N_NODES / 256, 256, 0, stream>>>(deg, 0, N_NODES);
    set_int<<<N_NODES / 256, 256, 0, stream>>>(cursor, 0, N_NODES);
    set_int<<<(N_GRAPHS * 512) / 256, 256, 0, stream>>>((int*)acc1, 0, N_GRAPHS * 512);
    set_int<<<(N_GRAPHS * 512) / 256, 256, 0, stream>>>((int*)acc2, 0, N_GRAPHS * 512);

    count_deg<<<N_EDGES / 256, 256, 0, stream>>>(dst, deg);
    scan_deg<<<1, 1024, 0, stream>>>(deg, rowStart);
    scatter_edges<<<N_EDGES / 256, 256, 0, stream>>>(dst, cursor, rowStart, edgeIdx);

    for (int br = 0; br < 2; ++br) {
        bool isGAT = (br == 0);
        float* acc = isGAT ? acc1 : acc2;
        const float* poolW = isGAT ? gatPool : gtPool;
        set_int<<<N_NODES / 256, 256, 0, stream>>>(nmask, 1, N_NODES);
        set_int<<<N_EDGES / 256, 256, 0, stream>>>(emask, 1, N_EDGES);
        const float* xcur = x0;
        int fi = 64;
        for (int l = 0; l < 3; ++l) {
            if (isGAT) {
                gemm_bias<<<dim3(HDF / 64, N_NODES / 64), 256, 0, stream>>>(
                    xcur, gatW[l], nullptr, bufH, fi, HDF);
                gat_att<<<N_NODES, 256, 0, stream>>>(bufH, gatAtt[l], aS, aD);
                gat_edge<<<N_NODES, 256, 0, stream>>>(bufH, aS, aD, rowStart, edgeIdx,
                                                      src, emask, nmask, ysec);
                fused_skip_gemm<<<N_NODES / 64, 256, 0, stream>>>(
                    xcur, gatRes[l], gatB[l], ysec, HDF, nmask, bufX, fi);
            } else {
                gemm_bias<<<dim3(768 / 64, N_NODES / 64), 256, 0, stream>>>(
                    xcur, gtWqkv[l], gtBqkv[l], bufH, fi, 768);
                gt_edge<<<N_NODES, 256, 0, stream>>>(bufH, rowStart, edgeIdx,
                                                     src, emask, nmask);
                fused_skip_gemm<<<N_NODES / 64, 256, 0, stream>>>(
                    xcur, gtWskip[l], gtBskip[l], bufH /*agg in q-slots*/, 768,
                    nmask, bufX, fi);
            }
            score_kernel<<<N_NODES / 4, 256, 0, stream>>>(bufX, poolW + l * HDF, scoreB);
            pool_kernel<<<N_GRAPHS, 128, 0, stream>>>(scoreB, nmask);
            emask_update<<<N_EDGES / 256, 256, 0, stream>>>(src, dst, nmask, emask);
            apply_pool<<<N_NODES, 256, 0, stream>>>(bufX, scoreB, nmask);
            readout_kernel<<<N_GRAPHS, 256, 0, stream>>>(bufX, nmask, acc);
            xcur = bufX;
            fi = HDF;
        }
    }
    mlp_kernel<<<N_GRAPHS, 128, 0, stream>>>(acc1, acc2, lin1W, lin1b, lin2W, lin2b,
                                             lin3W, lin3b, (float*)d_out);
}

// Round 3
// 2627.944 us; speedup vs baseline: 1.2810x; 1.2810x over previous
//
#include <hip/hip_runtime.h>
#include <hip/hip_bf16.h>
#include <math.h>

#define N_NODES 51200
#define N_GRAPHS 512
#define S_NODES 100
#define N_EDGES 512000
#define HDF 256          // H*D
#define NEGF (-1e30f)
#define MAXD 256

// ---------------------------------------------------------------- util
__global__ void set_int(int* __restrict__ p, int v, int n) {
    int i = blockIdx.x * 256 + threadIdx.x;
    if (i < n) p[i] = v;
}

// ---------------------------------------------------------------- GEMM fp32 128x128
// C[rows x NC] = A[rows x K] @ B[K x NC] (+ bias). grid = (NC/128, rows/128).
// 256 threads, 8x8 micro-tile per thread (rows tr*8..+7, cols tc*4 & tc*4+64).
__global__ __launch_bounds__(256) void gemm_bias(
    const float* __restrict__ A, const float* __restrict__ B,
    const float* __restrict__ bias, float* __restrict__ C,
    int K, int NC)
{
    __shared__ float As[16][136];   // k-major, 136*4B = 16B-aligned rows
    __shared__ float Bs[16][136];
    int row0 = blockIdx.y * 128, col0 = blockIdx.x * 128;
    int t = threadIdx.x;
    int tr = t >> 4, tc = t & 15;
    float4 acc0[8], acc1[8];
    #pragma unroll
    for (int i = 0; i < 8; ++i) {
        acc0[i] = make_float4(0.f, 0.f, 0.f, 0.f);
        acc1[i] = make_float4(0.f, 0.f, 0.f, 0.f);
    }
    int rA = t >> 1, kqA = (t & 1) * 8;     // A: 128 rows x 16 k
    int kB = t >> 4, cqB = (t & 15) * 8;    // B: 16 k x 128 cols
    for (int k0 = 0; k0 < K; k0 += 16) {
        float4 av0 = *(const float4*)(A + (size_t)(row0 + rA) * K + k0 + kqA);
        float4 av1 = *(const float4*)(A + (size_t)(row0 + rA) * K + k0 + kqA + 4);
        As[kqA + 0][rA] = av0.x; As[kqA + 1][rA] = av0.y;
        As[kqA + 2][rA] = av0.z; As[kqA + 3][rA] = av0.w;
        As[kqA + 4][rA] = av1.x; As[kqA + 5][rA] = av1.y;
        As[kqA + 6][rA] = av1.z; As[kqA + 7][rA] = av1.w;
        float4 bv0 = *(const float4*)(B + (size_t)(k0 + kB) * NC + col0 + cqB);
        float4 bv1 = *(const float4*)(B + (size_t)(k0 + kB) * NC + col0 + cqB + 4);
        *(float4*)&Bs[kB][cqB] = bv0;
        *(float4*)&Bs[kB][cqB + 4] = bv1;
        __syncthreads();
        #pragma unroll
        for (int kk = 0; kk < 16; ++kk) {
            float4 ra0 = *(const float4*)&As[kk][tr * 8];
            float4 ra1 = *(const float4*)&As[kk][tr * 8 + 4];
            float4 rb0 = *(const float4*)&Bs[kk][tc * 4];
            float4 rb1 = *(const float4*)&Bs[kk][tc * 4 + 64];
            float ra[8] = {ra0.x, ra0.y, ra0.z, ra0.w, ra1.x, ra1.y, ra1.z, ra1.w};
            #pragma unroll
            for (int i = 0; i < 8; ++i) {
                acc0[i].x += ra[i] * rb0.x;
                acc0[i].y += ra[i] * rb0.y;
                acc0[i].z += ra[i] * rb0.z;
                acc0[i].w += ra[i] * rb0.w;
                acc1[i].x += ra[i] * rb1.x;
                acc1[i].y += ra[i] * rb1.y;
                acc1[i].z += ra[i] * rb1.z;
                acc1[i].w += ra[i] * rb1.w;
            }
        }
        __syncthreads();
    }
    int c0 = col0 + tc * 4, c1 = c0 + 64;
    float4 bb0 = make_float4(0.f, 0.f, 0.f, 0.f), bb1 = bb0;
    if (bias) {
        bb0 = *(const float4*)&bias[c0];
        bb1 = *(const float4*)&bias[c1];
    }
    #pragma unroll
    for (int i = 0; i < 8; ++i) {
        int r = row0 + tr * 8 + i;
        float4 o0 = acc0[i], o1 = acc1[i];
        o0.x += bb0.x; o0.y += bb0.y; o0.z += bb0.z; o0.w += bb0.w;
        o1.x += bb1.x; o1.y += bb1.y; o1.z += bb1.z; o1.w += bb1.w;
        *(float4*)(C + (size_t)r * NC + c0) = o0;
        *(float4*)(C + (size_t)r * NC + c1) = o1;
    }
}

// ------------------------------------------------- fused skip-GEMM (in-place safe)
// out[r, 0:256] = relu(agg[r,c] + A[r,:]@B + bias[c]) * nmask[r]
// Block owns 64 rows x ALL 256 cols -> out may alias A.
__global__ __launch_bounds__(256) void fused_skip_gemm(
    const float* __restrict__ A, const float* __restrict__ B,
    const float* __restrict__ bias, const float* __restrict__ agg, int aggStride,
    const int* __restrict__ nmaskArr, float* __restrict__ out, int K)
{
    __shared__ float As[16][65];
    __shared__ float Bs[16][256];
    int row0 = blockIdx.x * 64;
    int t = threadIdx.x;
    int tr = t >> 4, tc = t & 15;
    float4 acc[4][4];
    #pragma unroll
    for (int i = 0; i < 4; ++i)
        #pragma unroll
        for (int u = 0; u < 4; ++u) acc[i][u] = make_float4(0.f, 0.f, 0.f, 0.f);
    int mA = t >> 2, kqA = (t & 3) << 2;
    for (int k0 = 0; k0 < K; k0 += 16) {
        float4 av = *(const float4*)(A + (size_t)(row0 + mA) * K + k0 + kqA);
        As[kqA + 0][mA] = av.x; As[kqA + 1][mA] = av.y;
        As[kqA + 2][mA] = av.z; As[kqA + 3][mA] = av.w;
        #pragma unroll
        for (int u = 0; u < 4; ++u) {
            int idx = t + u * 256;          // 0..1023
            int row = idx >> 6;             // 0..15
            int colq = (idx & 63) << 2;     // 0..252
            float4 bv = *(const float4*)(B + (size_t)(k0 + row) * 256 + colq);
            *(float4*)&Bs[row][colq] = bv;
        }
        __syncthreads();
        #pragma unroll
        for (int kk = 0; kk < 16; ++kk) {
            float ra[4];
            #pragma unroll
            for (int i = 0; i < 4; ++i) ra[i] = As[kk][tr * 4 + i];
            #pragma unroll
            for (int u = 0; u < 4; ++u) {
                float4 rb = *(const float4*)&Bs[kk][tc * 4 + u * 64];
                #pragma unroll
                for (int i = 0; i < 4; ++i) {
                    acc[i][u].x += ra[i] * rb.x;
                    acc[i][u].y += ra[i] * rb.y;
                    acc[i][u].z += ra[i] * rb.z;
                    acc[i][u].w += ra[i] * rb.w;
                }
            }
        }
        __syncthreads();
    }
    #pragma unroll
    for (int i = 0; i < 4; ++i) {
        int r = row0 + tr * 4 + i;
        float nm = nmaskArr[r] ? 1.f : 0.f;
        #pragma unroll
        for (int u = 0; u < 4; ++u) {
            int c = tc * 4 + u * 64;
            float4 v = acc[i][u];
            float4 bv = *(const float4*)&bias[c];
            float4 av = *(const float4*)(agg + (size_t)r * aggStride + c);
            v.x = fmaxf(v.x + av.x + bv.x, 0.f) * nm;
            v.y = fmaxf(v.y + av.y + bv.y, 0.f) * nm;
            v.z = fmaxf(v.z + av.z + bv.z, 0.f) * nm;
            v.w = fmaxf(v.w + av.w + bv.w, 0.f) * nm;
            *(float4*)(out + (size_t)r * HDF + c) = v;
        }
    }
}

// ---------------------------------------------------------------- CSR build
__global__ void count_deg(const int* __restrict__ dst, int* __restrict__ deg) {
    int e = blockIdx.x * 256 + threadIdx.x;
    atomicAdd(&deg[dst[e]], 1);
}

__global__ __launch_bounds__(1024) void scan_deg(const int* __restrict__ deg,
                                                 int* __restrict__ rowStart) {
    __shared__ int part[1024];
    int t = threadIdx.x;
    const int chunk = N_NODES / 1024;      // 50
    int s = t * chunk;
    int sum = 0;
    for (int i = 0; i < chunk; ++i) sum += deg[s + i];
    part[t] = sum;
    __syncthreads();
    for (int d = 1; d < 1024; d <<= 1) {
        int v = (t >= d) ? part[t - d] : 0;
        __syncthreads();
        part[t] += v;
        __syncthreads();
    }
    int excl = (t == 0) ? 0 : part[t - 1];
    for (int i = 0; i < chunk; ++i) { rowStart[s + i] = excl; excl += deg[s + i]; }
    if (t == 1023) rowStart[N_NODES] = part[1023];
}

__global__ void scatter_edges(const int* __restrict__ dst, int* __restrict__ cursor,
                              const int* __restrict__ rowStart, int* __restrict__ edgeIdx) {
    int e = blockIdx.x * 256 + threadIdx.x;
    int d = dst[e];
    int p = atomicAdd(&cursor[d], 1);
    edgeIdx[rowStart[d] + p] = e;
}

// ---------------------------------------------------------------- GAT pieces
__global__ __launch_bounds__(256) void gat_att(const float* __restrict__ hfeat,
                                               const float* __restrict__ att,
                                               float* __restrict__ aS, float* __restrict__ aD) {
    int i = blockIdx.x, t = threadIdx.x, hh = t >> 6, d = t & 63;
    float hv = hfeat[(size_t)i * HDF + t];
    float p0 = hv * att[hh * 64 + d];
    float p1 = hv * att[256 + hh * 64 + d];
    #pragma unroll
    for (int o = 32; o > 0; o >>= 1) { p0 += __shfl_down(p0, o, 64); p1 += __shfl_down(p1, o, 64); }
    if (d == 0) { aS[i * 4 + hh] = p0; aD[i * 4 + hh] = p1; }
}

// per-dst attention aggregation -> aggOut (stride 256). 4-wave-parallel gather.
__global__ __launch_bounds__(256) void gat_edge(
    const float* __restrict__ hfeat, const float* __restrict__ aS, const float* __restrict__ aD,
    const int* __restrict__ rowStart, const int* __restrict__ edgeIdx,
    const int* __restrict__ srcArr, const int* __restrict__ emask, const int* __restrict__ nmask,
    float* __restrict__ aggOut)
{
    int i = blockIdx.x, t = threadIdx.x;
    int w = t >> 6, l = t & 63;
    __shared__ int sSrc[MAXD + 1];
    __shared__ float sL[MAXD + 1][4];
    __shared__ float sAcc[3][256];
    if (!nmask[i]) {
        aggOut[(size_t)i * HDF + t] = 0.f;
        return;
    }
    int rs = rowStart[i], re = rowStart[i + 1];
    int deg = min(re - rs, MAXD);
    for (int j = t; j < deg; j += 256) {
        int e = edgeIdx[rs + j];
        int ok = emask[e];
        int s_ = srcArr[e];
        sSrc[j] = ok ? s_ : -1;
        #pragma unroll
        for (int h2 = 0; h2 < 4; ++h2) {
            float lg = aS[s_ * 4 + h2] + aD[i * 4 + h2];
            lg = (lg >= 0.f) ? lg : 0.2f * lg;
            sL[j][h2] = ok ? lg : NEGF;
        }
    }
    if (t == 0) {   // self loop (node alive here)
        sSrc[deg] = i;
        #pragma unroll
        for (int h2 = 0; h2 < 4; ++h2) {
            float lg = aS[i * 4 + h2] + aD[i * 4 + h2];
            sL[deg][h2] = (lg >= 0.f) ? lg : 0.2f * lg;
        }
    }
    __syncthreads();
    int tot = deg + 1;
    int hh4 = l >> 4;                     // head owning dims 4l..4l+3
    float m = NEGF;
    for (int j = 0; j < tot; ++j) if (sSrc[j] >= 0) m = fmaxf(m, sL[j][hh4]);
    float ssum = 0.f;
    for (int j = 0; j < tot; ++j) if (sSrc[j] >= 0) ssum += expf(sL[j][hh4] - m);
    float inv = 1.f / fmaxf(ssum, 1e-16f);
    float4 a4 = make_float4(0.f, 0.f, 0.f, 0.f);
    for (int j = w; j < tot; j += 4) {
        int s_ = sSrc[j];
        if (s_ < 0) continue;
        float a = expf(sL[j][hh4] - m) * inv;
        float4 v4 = *(const float4*)&hfeat[(size_t)s_ * HDF + l * 4];
        a4.x += a * v4.x; a4.y += a * v4.y; a4.z += a * v4.z; a4.w += a * v4.w;
    }
    if (w > 0) *(float4*)&sAcc[w - 1][l * 4] = a4;
    __syncthreads();
    if (w == 0) {
        float4 p0 = *(const float4*)&sAcc[0][l * 4];
        float4 p1 = *(const float4*)&sAcc[1][l * 4];
        float4 p2 = *(const float4*)&sAcc[2][l * 4];
        a4.x += p0.x + p1.x + p2.x;
        a4.y += p0.y + p1.y + p2.y;
        a4.z += p0.z + p1.z + p2.z;
        a4.w += p0.w + p1.w + p2.w;
        *(float4*)(aggOut + (size_t)i * HDF + l * 4) = a4;
    }
}

// ---------------------------------------------------------------- GT piece
// qkv row: [q(256) | k(256) | v(256)]. Writes agg over OWN q-slot (race-free:
// other blocks never read this row's q). 4-wave-parallel logits + gather.
__global__ __launch_bounds__(256) void gt_edge(
    float* __restrict__ qkv,
    const int* __restrict__ rowStart, const int* __restrict__ edgeIdx,
    const int* __restrict__ srcArr, const int* __restrict__ emask, const int* __restrict__ nmask)
{
    int i = blockIdx.x, t = threadIdx.x;
    int w = t >> 6, l = t & 63;
    __shared__ float sQ[256];
    __shared__ int sSrc[MAXD];
    __shared__ float sL[MAXD][4];
    __shared__ float sAcc[3][256];
    if (!nmask[i]) {
        qkv[(size_t)i * 768 + t] = 0.f;
        return;
    }
    int rs = rowStart[i], re = rowStart[i + 1];
    int deg = min(re - rs, MAXD);
    sQ[t] = qkv[(size_t)i * 768 + t];
    __syncthreads();
    // phase A: wave w handles edges j = w, w+4, ... ; lane l covers dims 4l..4l+3
    float4 q4 = *(const float4*)&sQ[l * 4];
    for (int j = w; j < deg; j += 4) {
        int e = edgeIdx[rs + j];
        int ok = emask[e];
        int s_ = srcArr[e];
        float4 k4 = *(const float4*)&qkv[(size_t)s_ * 768 + 256 + l * 4];
        float p = q4.x * k4.x + q4.y * k4.y + q4.z * k4.z + q4.w * k4.w;
        // reduce within 16-lane group (one head per group)
        p += __shfl_xor(p, 1, 64);
        p += __shfl_xor(p, 2, 64);
        p += __shfl_xor(p, 4, 64);
        p += __shfl_xor(p, 8, 64);
        if ((l & 15) == 0) sL[j][l >> 4] = ok ? p * 0.125f : NEGF;
        if (l == 0) sSrc[j] = ok ? s_ : -1;
    }
    __syncthreads();
    // phase B: per-thread softmax scalars for its head
    int hh4 = l >> 4;
    float m = NEGF;
    for (int j = 0; j < deg; ++j) if (sSrc[j] >= 0) m = fmaxf(m, sL[j][hh4]);
    float ssum = 0.f;
    for (int j = 0; j < deg; ++j) if (sSrc[j] >= 0) ssum += expf(sL[j][hh4] - m);
    float inv = 1.f / fmaxf(ssum, 1e-16f);
    // phase C: wave-parallel weighted V gather
    float4 a4 = make_float4(0.f, 0.f, 0.f, 0.f);
    for (int j = w; j < deg; j += 4) {
        int s_ = sSrc[j];
        if (s_ < 0) continue;
        float a = expf(sL[j][hh4] - m) * inv;
        float4 v4 = *(const float4*)&qkv[(size_t)s_ * 768 + 512 + l * 4];
        a4.x += a * v4.x; a4.y += a * v4.y; a4.z += a * v4.z; a4.w += a * v4.w;
    }
    if (w > 0) *(float4*)&sAcc[w - 1][l * 4] = a4;
    __syncthreads();
    if (w == 0) {
        float4 p0 = *(const float4*)&sAcc[0][l * 4];
        float4 p1 = *(const float4*)&sAcc[1][l * 4];
        float4 p2 = *(const float4*)&sAcc[2][l * 4];
        a4.x += p0.x + p1.x + p2.x;
        a4.y += p0.y + p1.y + p2.y;
        a4.z += p0.z + p1.z + p2.z;
        a4.w += p0.w + p1.w + p2.w;
        *(float4*)(qkv + (size_t)i * 768 + l * 4) = a4;
    }
}

// ---------------------------------------------------------------- pooling
__global__ __launch_bounds__(256) void score_kernel(const float* __restrict__ x,
                                                    const float* __restrict__ w,
                                                    float* __restrict__ score) {
    int wave = threadIdx.x >> 6, lane = threadIdx.x & 63;
    int node = blockIdx.x * 4 + wave;
    float dx = 0.f, dw = 0.f;
    #pragma unroll
    for (int c = 0; c < 4; ++c) {
        int cc = lane + c * 64;
        float wv = w[cc];
        dx += x[(size_t)node * HDF + cc] * wv;
        dw += wv * wv;
    }
    #pragma unroll
    for (int o = 32; o > 0; o >>= 1) { dx += __shfl_down(dx, o, 64); dw += __shfl_down(dw, o, 64); }
    if (lane == 0) score[node] = tanhf(dx / sqrtf(dw));
}

__global__ __launch_bounds__(128) void pool_kernel(const float* __restrict__ score,
                                                   int* __restrict__ nmask) {
    int g = blockIdx.x, t = threadIdx.x;
    __shared__ float kv[128];
    __shared__ int cnt_s;
    if (t == 0) cnt_s = 0;
    int alive = 0;
    float ck = -2.0f;
    int node = g * S_NODES + t;
    if (t < S_NODES) { alive = nmask[node]; ck = alive ? score[node] : -1.5f; }
    kv[t] = ck;
    __syncthreads();
    if (alive) atomicAdd(&cnt_s, 1);
    __syncthreads();
    int k = (int)ceilf(0.8f * (float)cnt_s);   // f32, matches jnp.ceil(RATIO*n)
    int rank = 0;
    for (int j = 0; j < S_NODES; ++j) {
        float o = kv[j];
        rank += (o > ck || (o == ck && j < t)) ? 1 : 0;  // stable desc
    }
    if (t < S_NODES) nmask[node] = (alive && rank < k) ? 1 : 0;
}

__global__ void emask_update(const int* __restrict__ srcArr, const int* __restrict__ dstArr,
                             const int* __restrict__ nmask, int* __restrict__ emask) {
    int e = blockIdx.x * 256 + threadIdx.x;
    emask[e] = (emask[e] && nmask[srcArr[e]] && nmask[dstArr[e]]) ? 1 : 0;
}

__global__ void apply_pool(float* __restrict__ x, const float* __restrict__ score,
                           const int* __restrict__ nmask) {
    size_t idx = (size_t)blockIdx.x * 256 + threadIdx.x;
    int node = (int)(idx >> 8);
    x[idx] = nmask[node] ? x[idx] * score[node] : 0.f;
}

__global__ __launch_bounds__(256) void readout_kernel(const float* __restrict__ x,
                                                      const int* __restrict__ nmask,
                                                      float* __restrict__ acc) {
    int g = blockIdx.x, c = threadIdx.x;
    float mx = NEGF, sm = 0.f, cnt = 0.f;
    int base = g * S_NODES;
    for (int o = 0; o < S_NODES; ++o) {
        if (nmask[base + o]) {
            float v = x[(size_t)(base + o) * HDF + c];
            mx = fmaxf(mx, v);
            sm += v;
            cnt += 1.f;
        }
    }
    acc[(size_t)g * 512 + c] += mx;
    acc[(size_t)g * 512 + 256 + c] += sm / fmaxf(cnt, 1.f);
}

// ---------------------------------------------------------------- MLP head
__global__ __launch_bounds__(128) void mlp_kernel(
    const float* __restrict__ acc1, const float* __restrict__ acc2,
    const float* __restrict__ W1, const float* __restrict__ b1,
    const float* __restrict__ W2, const float* __restrict__ b2,
    const float* __restrict__ W3, const float* __restrict__ b3,
    float* __restrict__ out)
{
    int g = blockIdx.x, t = threadIdx.x;
    __shared__ float hrow[1024];
    __shared__ float h1s[128];
    __shared__ float h2s[64];
    __shared__ float o3[10];
    for (int j = t; j < 512; j += 128) {
        hrow[j] = acc1[(size_t)g * 512 + j];
        hrow[512 + j] = acc2[(size_t)g * 512 + j];
    }
    __syncthreads();
    float s = b1[t];
    for (int kx = 0; kx < 1024; ++kx) s += hrow[kx] * W1[(size_t)kx * 128 + t];
    h1s[t] = fmaxf(s, 0.f);
    __syncthreads();
    if (t < 64) {
        float s2 = b2[t];
        for (int kx = 0; kx < 128; ++kx) s2 += h1s[kx] * W2[kx * 64 + t];
        h2s[t] = fmaxf(s2, 0.f);
    }
    __syncthreads();
    if (t < 10) {
        float s3 = b3[t];
        for (int kx = 0; kx < 64; ++kx) s3 += h2s[kx] * W3[kx * 10 + t];
        o3[t] = s3;
    }
    __syncthreads();
    if (t < 10) {
        float m = o3[0];
        for (int j = 1; j < 10; ++j) m = fmaxf(m, o3[j]);
        float se = 0.f;
        for (int j = 0; j < 10; ++j) se += expf(o3[j] - m);
        out[g * 10 + t] = o3[t] - m - logf(se);
    }
}

// ---------------------------------------------------------------- launch
extern "C" void kernel_launch(void* const* d_in, const int* in_sizes, int n_in,
                              void* d_out, int out_size, void* d_ws, size_t ws_size,
                              hipStream_t stream) {
    (void)n_in; (void)out_size; (void)ws_size;
    const float* x0 = (const float*)d_in[0];
    const int* src = (const int*)d_in[1];
    const int* dst = src + N_EDGES;

    bool dictOrder = (in_sizes[7] == 64 * 768);
    const float *gatW[3], *gatAtt[3], *gatB[3], *gatRes[3];
    const float *gtWqkv[3], *gtBqkv[3], *gtWskip[3], *gtBskip[3];
    const float *gatPool, *gtPool;
    if (dictOrder) {
        for (int l = 0; l < 3; ++l) {
            int b = 3 + l * 8;
            gatW[l]    = (const float*)d_in[b + 0];
            gatAtt[l]  = (const float*)d_in[b + 1];
            gatB[l]    = (const float*)d_in[b + 2];
            gatRes[l]  = (const float*)d_in[b + 3];
            gtWqkv[l]  = (const float*)d_in[b + 4];
            gtBqkv[l]  = (const float*)d_in[b + 5];
            gtWskip[l] = (const float*)d_in[b + 6];
            gtBskip[l] = (const float*)d_in[b + 7];
        }
        gatPool = (const float*)d_in[27];
        gtPool  = (const float*)d_in[28];
    } else {
        for (int l = 0; l < 3; ++l) {
            int b = 3 + l * 4;
            gatW[l]   = (const float*)d_in[b + 0];
            gatAtt[l] = (const float*)d_in[b + 1];
            gatB[l]   = (const float*)d_in[b + 2];
            gatRes[l] = (const float*)d_in[b + 3];
            int c = 16 + l * 4;
            gtWqkv[l]  = (const float*)d_in[c + 0];
            gtBqkv[l]  = (const float*)d_in[c + 1];
            gtWskip[l] = (const float*)d_in[c + 2];
            gtBskip[l] = (const float*)d_in[c + 3];
        }
        gatPool = (const float*)d_in[15];
        gtPool  = (const float*)d_in[28];
    }
    const float* lin1W = (const float*)d_in[29];
    const float* lin1b = (const float*)d_in[30];
    const float* lin2W = (const float*)d_in[31];
    const float* lin2b = (const float*)d_in[32];
    const float* lin3W = (const float*)d_in[33];
    const float* lin3b = (const float*)d_in[34];

    char* wsp = (char*)d_ws;
    size_t off = 0;
    auto carve = [&](size_t bytes) -> void* {
        void* p = wsp + off;
        off += (bytes + 255) & ~(size_t)255;
        return p;
    };
    float* bufX   = (float*)carve((size_t)N_NODES * HDF * 4);   // 52.4 MB
    float* bufH   = (float*)carve((size_t)N_NODES * 768 * 4);   // 157.3 MB
    float* aS     = (float*)carve((size_t)N_NODES * 4 * 4);
    float* aD     = (float*)carve((size_t)N_NODES * 4 * 4);
    float* scoreB = (float*)carve((size_t)N_NODES * 4);
    int* nmask    = (int*)carve((size_t)N_NODES * 4);
    int* emask    = (int*)carve((size_t)N_EDGES * 4);
    int* deg      = (int*)carve((size_t)N_NODES * 4);
    int* rowStart = (int*)carve((size_t)(N_NODES + 1) * 4);
    int* cursor   = (int*)carve((size_t)N_NODES * 4);
    int* edgeIdx  = (int*)carve((size_t)N_EDGES * 4);
    float* acc1   = (float*)carve((size_t)N_GRAPHS * 512 * 4);
    float* acc2   = (float*)carve((size_t)N_GRAPHS * 512 * 4);
    float* ysec   = bufH + (size_t)N_NODES * HDF;   // spare 2nd third of bufH (GAT agg)

    set_int<<<N_NODES / 256, 256, 0, stream>>>(deg, 0, N_NODES);
    set_int<<<N_NODES / 256, 256, 0, stream>>>(cursor, 0, N_NODES);
    set_int<<<(N_GRAPHS * 512) / 256, 256, 0, stream>>>((int*)acc1, 0, N_GRAPHS * 512);
    set_int<<<(N_GRAPHS * 512) / 256, 256, 0, stream>>>((int*)acc2, 0, N_GRAPHS * 512);

    count_deg<<<N_EDGES / 256, 256, 0, stream>>>(dst, deg);
    scan_deg<<<1, 1024, 0, stream>>>(deg, rowStart);
    scatter_edges<<<N_EDGES / 256, 256, 0, stream>>>(dst, cursor, rowStart, edgeIdx);

    for (int br = 0; br < 2; ++br) {
        bool isGAT = (br == 0);
        float* acc = isGAT ? acc1 : acc2;
        const float* poolW = isGAT ? gatPool : gtPool;
        set_int<<<N_NODES / 256, 256, 0, stream>>>(nmask, 1, N_NODES);
        set_int<<<N_EDGES / 256, 256, 0, stream>>>(emask, 1, N_EDGES);
        const float* xcur = x0;
        int fi = 64;
        for (int l = 0; l < 3; ++l) {
            if (isGAT) {
                gemm_bias<<<dim3(HDF / 128, N_NODES / 128), 256, 0, stream>>>(
                    xcur, gatW[l], nullptr, bufH, fi, HDF);
                gat_att<<<N_NODES, 256, 0, stream>>>(bufH, gatAtt[l], aS, aD);
                gat_edge<<<N_NODES, 256, 0, stream>>>(bufH, aS, aD, rowStart, edgeIdx,
                                                      src, emask, nmask, ysec);
                fused_skip_gemm<<<N_NODES / 64, 256, 0, stream>>>(
                    xcur, gatRes[l], gatB[l], ysec, HDF, nmask, bufX, fi);
            } else {
                gemm_bias<<<dim3(768 / 128, N_NODES / 128), 256, 0, stream>>>(
                    xcur, gtWqkv[l], gtBqkv[l], bufH, fi, 768);
                gt_edge<<<N_NODES, 256, 0, stream>>>(bufH, rowStart, edgeIdx,
                                                     src, emask, nmask);
                fused_skip_gemm<<<N_NODES / 64, 256, 0, stream>>>(
                    xcur, gtWskip[l], gtBskip[l], bufH /*agg in q-slots*/, 768,
                    nmask, bufX, fi);
            }
            score_kernel<<<N_NODES / 4, 256, 0, stream>>>(bufX, poolW + l * HDF, scoreB);
            pool_kernel<<<N_GRAPHS, 128, 0, stream>>>(scoreB, nmask);
            emask_update<<<N_EDGES / 256, 256, 0, stream>>>(src, dst, nmask, emask);
            apply_pool<<<N_NODES, 256, 0, stream>>>(bufX, scoreB, nmask);
            readout_kernel<<<N_GRAPHS, 256, 0, stream>>>(bufX, nmask, acc);
            xcur = bufX;
            fi = HDF;
        }
    }
    mlp_kernel<<<N_GRAPHS, 128, 0, stream>>>(acc1, acc2, lin1W, lin1b, lin2W, lin2b,
                                             lin3W, lin3b, (float*)d_out);
}

// Round 4
// 2035.583 us; speedup vs baseline: 1.6538x; 1.2910x over previous
//
#include <hip/hip_runtime.h>
#include <hip/hip_bf16.h>
#include <math.h>

#define N_NODES 51200
#define N_GRAPHS 512
#define S_NODES 100
#define N_EDGES 512000
#define HDF 256          // H*D
#define NEGF (-1e30f)
#define MAXD 256

typedef short bf16x8 __attribute__((ext_vector_type(8)));
typedef float f32x4 __attribute__((ext_vector_type(4)));

__device__ inline unsigned short f2b(float x) {   // fp32 -> bf16 RNE
    union { float f; unsigned u; } v; v.f = x;
    unsigned r = v.u + 0x7FFFu + ((v.u >> 16) & 1u);
    return (unsigned short)(r >> 16);
}
__device__ inline float b2f(unsigned short b) {
    union { float f; unsigned u; } v; v.u = ((unsigned)b) << 16; return v.f;
}

// ---------------------------------------------------------------- util
__global__ void set_int(int* __restrict__ p, int v, int n) {
    int i = blockIdx.x * 256 + threadIdx.x;
    if (i < n) p[i] = v;
}

// ------------------------------------------------- split-bf16 MFMA GEMM
// C[rows x NC] = A[rows x K] @ B[K x NC] (+bias) via 3-term bf16 split
// (hi*hi + hi*lo + lo*hi), fp32 MFMA accumulate. Tile 128x256, 512 thr,
// 8 waves (2x4), 64x64/wave. grid = (NC/256, rows/128).
// agg != null: fused epilogue out = relu(acc+agg+bias)*nmask, out stride 256,
// in-place safe (grid.x==1 -> block owns its rows; reads before last barrier).
__global__ __launch_bounds__(512) void mfma_gemm(
    const float* __restrict__ A, const float* __restrict__ B,
    const float* __restrict__ bias, float* __restrict__ C,
    int K, int NC,
    const float* __restrict__ agg, int aggStride,
    const int* __restrict__ nmaskArr)
{
    __shared__ unsigned short Ah[4 * 128 * 8];   // [kg][row][j]
    __shared__ unsigned short Al[4 * 128 * 8];
    __shared__ unsigned short Bh[4 * 256 * 8];   // [kg][col][j]
    __shared__ unsigned short Bl[4 * 256 * 8];
    int row0 = blockIdx.y * 128, col0 = blockIdx.x * 256;
    int t = threadIdx.x;
    int lane = t & 63, w = t >> 6;
    int wr = w >> 2, wc = w & 3;          // 2 x 4 wave grid
    int l15 = lane & 15, l4 = lane >> 4;
    f32x4 acc[4][4];
    #pragma unroll
    for (int m = 0; m < 4; ++m)
        #pragma unroll
        for (int n = 0; n < 4; ++n) acc[m][n] = (f32x4){0.f, 0.f, 0.f, 0.f};

    int arow = t & 127, akg = t >> 7;     // A staging: 1 task (row, kgroup)
    int bcol = t & 255, bhalf = t >> 8;   // B staging: 2 tasks (col, kgroup)

    for (int k0 = 0; k0 < K; k0 += 32) {
        // ---- stage A (fp32 -> hi/lo bf16)
        const float* ap = A + (size_t)(row0 + arow) * K + k0 + akg * 8;
        float4 a0 = *(const float4*)ap;
        float4 a1 = *(const float4*)(ap + 4);
        float av[8] = {a0.x, a0.y, a0.z, a0.w, a1.x, a1.y, a1.z, a1.w};
        int abase = (akg * 128 + arow) * 8;
        #pragma unroll
        for (int j = 0; j < 8; ++j) {
            unsigned short h = f2b(av[j]);
            Ah[abase + j] = h;
            Al[abase + j] = f2b(av[j] - b2f(h));
        }
        // ---- stage B
        #pragma unroll
        for (int q = 0; q < 2; ++q) {
            int kg = bhalf * 2 + q;
            int bbase = (kg * 256 + bcol) * 8;
            #pragma unroll
            for (int j = 0; j < 8; ++j) {
                float bvf = B[(size_t)(k0 + kg * 8 + j) * NC + col0 + bcol];
                unsigned short h = f2b(bvf);
                Bh[bbase + j] = h;
                Bl[bbase + j] = f2b(bvf - b2f(h));
            }
        }
        __syncthreads();
        // ---- fragments + MFMA
        bf16x8 bh[4], bl[4];
        #pragma unroll
        for (int n = 0; n < 4; ++n) {
            int idx = (l4 * 256 + wc * 64 + n * 16 + l15) * 8;
            bh[n] = *(bf16x8*)&Bh[idx];
            bl[n] = *(bf16x8*)&Bl[idx];
        }
        #pragma unroll
        for (int m = 0; m < 4; ++m) {
            int idx = (l4 * 128 + wr * 64 + m * 16 + l15) * 8;
            bf16x8 ah = *(bf16x8*)&Ah[idx];
            bf16x8 al = *(bf16x8*)&Al[idx];
            #pragma unroll
            for (int n = 0; n < 4; ++n) {
                acc[m][n] = __builtin_amdgcn_mfma_f32_16x16x32_bf16(ah, bh[n], acc[m][n], 0, 0, 0);
                acc[m][n] = __builtin_amdgcn_mfma_f32_16x16x32_bf16(ah, bl[n], acc[m][n], 0, 0, 0);
                acc[m][n] = __builtin_amdgcn_mfma_f32_16x16x32_bf16(al, bh[n], acc[m][n], 0, 0, 0);
            }
        }
        __syncthreads();
    }
    // ---- epilogue: D row = wr*64+m*16+l4*4+r, col = wc*64+n*16+l15
    bool fused = (agg != nullptr);
    #pragma unroll
    for (int m = 0; m < 4; ++m) {
        #pragma unroll
        for (int n = 0; n < 4; ++n) {
            int col = col0 + wc * 64 + n * 16 + l15;
            float bv = bias ? bias[col] : 0.f;
            #pragma unroll
            for (int r = 0; r < 4; ++r) {
                int row = row0 + wr * 64 + m * 16 + l4 * 4 + r;
                float v = acc[m][n][r] + bv;
                if (fused) {
                    v += agg[(size_t)row * aggStride + col];
                    float nm = nmaskArr[row] ? 1.f : 0.f;
                    C[(size_t)row * 256 + col] = fmaxf(v, 0.f) * nm;
                } else {
                    C[(size_t)row * NC + col] = v;
                }
            }
        }
    }
}

// ---------------------------------------------------------------- CSR build
__global__ void count_deg(const int* __restrict__ dst, int* __restrict__ deg) {
    int e = blockIdx.x * 256 + threadIdx.x;
    atomicAdd(&deg[dst[e]], 1);
}

__global__ __launch_bounds__(1024) void scan_deg(const int* __restrict__ deg,
                                                 int* __restrict__ rowStart) {
    __shared__ int part[1024];
    int t = threadIdx.x;
    const int chunk = N_NODES / 1024;      // 50
    int s = t * chunk;
    int sum = 0;
    for (int i = 0; i < chunk; ++i) sum += deg[s + i];
    part[t] = sum;
    __syncthreads();
    for (int d = 1; d < 1024; d <<= 1) {
        int v = (t >= d) ? part[t - d] : 0;
        __syncthreads();
        part[t] += v;
        __syncthreads();
    }
    int excl = (t == 0) ? 0 : part[t - 1];
    for (int i = 0; i < chunk; ++i) { rowStart[s + i] = excl; excl += deg[s + i]; }
    if (t == 1023) rowStart[N_NODES] = part[1023];
}

__global__ void scatter_edges(const int* __restrict__ dst, int* __restrict__ cursor,
                              const int* __restrict__ rowStart, int* __restrict__ edgeIdx) {
    int e = blockIdx.x * 256 + threadIdx.x;
    int d = dst[e];
    int p = atomicAdd(&cursor[d], 1);
    edgeIdx[rowStart[d] + p] = e;
}

// ---------------------------------------------------------------- GAT pieces
__global__ __launch_bounds__(256) void gat_att(const float* __restrict__ hfeat,
                                               const float* __restrict__ att,
                                               float* __restrict__ aS, float* __restrict__ aD) {
    int i = blockIdx.x, t = threadIdx.x, hh = t >> 6, d = t & 63;
    float hv = hfeat[(size_t)i * HDF + t];
    float p0 = hv * att[hh * 64 + d];
    float p1 = hv * att[256 + hh * 64 + d];
    #pragma unroll
    for (int o = 32; o > 0; o >>= 1) { p0 += __shfl_down(p0, o, 64); p1 += __shfl_down(p1, o, 64); }
    if (d == 0) { aS[i * 4 + hh] = p0; aD[i * 4 + hh] = p1; }
}

// per-dst attention aggregation -> aggOut (stride 256). 4-wave-parallel gather.
__global__ __launch_bounds__(256) void gat_edge(
    const float* __restrict__ hfeat, const float* __restrict__ aS, const float* __restrict__ aD,
    const int* __restrict__ rowStart, const int* __restrict__ edgeIdx,
    const int* __restrict__ srcArr, const int* __restrict__ emask, const int* __restrict__ nmask,
    float* __restrict__ aggOut)
{
    int i = blockIdx.x, t = threadIdx.x;
    int w = t >> 6, l = t & 63;
    __shared__ int sSrc[MAXD + 1];
    __shared__ float sL[MAXD + 1][4];
    __shared__ float sAcc[3][256];
    if (!nmask[i]) {
        aggOut[(size_t)i * HDF + t] = 0.f;
        return;
    }
    int rs = rowStart[i], re = rowStart[i + 1];
    int deg = min(re - rs, MAXD);
    for (int j = t; j < deg; j += 256) {
        int e = edgeIdx[rs + j];
        int ok = emask[e];
        int s_ = srcArr[e];
        sSrc[j] = ok ? s_ : -1;
        #pragma unroll
        for (int h2 = 0; h2 < 4; ++h2) {
            float lg = aS[s_ * 4 + h2] + aD[i * 4 + h2];
            lg = (lg >= 0.f) ? lg : 0.2f * lg;
            sL[j][h2] = ok ? lg : NEGF;
        }
    }
    if (t == 0) {   // self loop (node alive here)
        sSrc[deg] = i;
        #pragma unroll
        for (int h2 = 0; h2 < 4; ++h2) {
            float lg = aS[i * 4 + h2] + aD[i * 4 + h2];
            sL[deg][h2] = (lg >= 0.f) ? lg : 0.2f * lg;
        }
    }
    __syncthreads();
    int tot = deg + 1;
    int hh4 = l >> 4;                     // head owning dims 4l..4l+3
    float m = NEGF;
    for (int j = 0; j < tot; ++j) if (sSrc[j] >= 0) m = fmaxf(m, sL[j][hh4]);
    float ssum = 0.f;
    for (int j = 0; j < tot; ++j) if (sSrc[j] >= 0) ssum += expf(sL[j][hh4] - m);
    float inv = 1.f / fmaxf(ssum, 1e-16f);
    float4 a4 = make_float4(0.f, 0.f, 0.f, 0.f);
    for (int j = w; j < tot; j += 4) {
        int s_ = sSrc[j];
        if (s_ < 0) continue;
        float a = expf(sL[j][hh4] - m) * inv;
        float4 v4 = *(const float4*)&hfeat[(size_t)s_ * HDF + l * 4];
        a4.x += a * v4.x; a4.y += a * v4.y; a4.z += a * v4.z; a4.w += a * v4.w;
    }
    if (w > 0) *(float4*)&sAcc[w - 1][l * 4] = a4;
    __syncthreads();
    if (w == 0) {
        float4 p0 = *(const float4*)&sAcc[0][l * 4];
        float4 p1 = *(const float4*)&sAcc[1][l * 4];
        float4 p2 = *(const float4*)&sAcc[2][l * 4];
        a4.x += p0.x + p1.x + p2.x;
        a4.y += p0.y + p1.y + p2.y;
        a4.z += p0.z + p1.z + p2.z;
        a4.w += p0.w + p1.w + p2.w;
        *(float4*)(aggOut + (size_t)i * HDF + l * 4) = a4;
    }
}

// ---------------------------------------------------------------- GT piece
// qkv row: [q(256) | k(256) | v(256)]. Writes agg over OWN q-slot (race-free:
// other blocks never read this row's q). 4-wave-parallel logits + gather.
__global__ __launch_bounds__(256) void gt_edge(
    float* __restrict__ qkv,
    const int* __restrict__ rowStart, const int* __restrict__ edgeIdx,
    const int* __restrict__ srcArr, const int* __restrict__ emask, const int* __restrict__ nmask)
{
    int i = blockIdx.x, t = threadIdx.x;
    int w = t >> 6, l = t & 63;
    __shared__ float sQ[256];
    __shared__ int sSrc[MAXD];
    __shared__ float sL[MAXD][4];
    __shared__ float sAcc[3][256];
    if (!nmask[i]) {
        qkv[(size_t)i * 768 + t] = 0.f;
        return;
    }
    int rs = rowStart[i], re = rowStart[i + 1];
    int deg = min(re - rs, MAXD);
    sQ[t] = qkv[(size_t)i * 768 + t];
    __syncthreads();
    float4 q4 = *(const float4*)&sQ[l * 4];
    for (int j = w; j < deg; j += 4) {
        int e = edgeIdx[rs + j];
        int ok = emask[e];
        int s_ = srcArr[e];
        float4 k4 = *(const float4*)&qkv[(size_t)s_ * 768 + 256 + l * 4];
        float p = q4.x * k4.x + q4.y * k4.y + q4.z * k4.z + q4.w * k4.w;
        p += __shfl_xor(p, 1, 64);
        p += __shfl_xor(p, 2, 64);
        p += __shfl_xor(p, 4, 64);
        p += __shfl_xor(p, 8, 64);
        if ((l & 15) == 0) sL[j][l >> 4] = ok ? p * 0.125f : NEGF;
        if (l == 0) sSrc[j] = ok ? s_ : -1;
    }
    __syncthreads();
    int hh4 = l >> 4;
    float m = NEGF;
    for (int j = 0; j < deg; ++j) if (sSrc[j] >= 0) m = fmaxf(m, sL[j][hh4]);
    float ssum = 0.f;
    for (int j = 0; j < deg; ++j) if (sSrc[j] >= 0) ssum += expf(sL[j][hh4] - m);
    float inv = 1.f / fmaxf(ssum, 1e-16f);
    float4 a4 = make_float4(0.f, 0.f, 0.f, 0.f);
    for (int j = w; j < deg; j += 4) {
        int s_ = sSrc[j];
        if (s_ < 0) continue;
        float a = expf(sL[j][hh4] - m) * inv;
        float4 v4 = *(const float4*)&qkv[(size_t)s_ * 768 + 512 + l * 4];
        a4.x += a * v4.x; a4.y += a * v4.y; a4.z += a * v4.z; a4.w += a * v4.w;
    }
    if (w > 0) *(float4*)&sAcc[w - 1][l * 4] = a4;
    __syncthreads();
    if (w == 0) {
        float4 p0 = *(const float4*)&sAcc[0][l * 4];
        float4 p1 = *(const float4*)&sAcc[1][l * 4];
        float4 p2 = *(const float4*)&sAcc[2][l * 4];
        a4.x += p0.x + p1.x + p2.x;
        a4.y += p0.y + p1.y + p2.y;
        a4.z += p0.z + p1.z + p2.z;
        a4.w += p0.w + p1.w + p2.w;
        *(float4*)(qkv + (size_t)i * 768 + l * 4) = a4;
    }
}

// ---------------------------------------------------------------- pooling
__global__ __launch_bounds__(256) void score_kernel(const float* __restrict__ x,
                                                    const float* __restrict__ w,
                                                    float* __restrict__ score) {
    int wave = threadIdx.x >> 6, lane = threadIdx.x & 63;
    int node = blockIdx.x * 4 + wave;
    float dx = 0.f, dw = 0.f;
    #pragma unroll
    for (int c = 0; c < 4; ++c) {
        int cc = lane + c * 64;
        float wv = w[cc];
        dx += x[(size_t)node * HDF + cc] * wv;
        dw += wv * wv;
    }
    #pragma unroll
    for (int o = 32; o > 0; o >>= 1) { dx += __shfl_down(dx, o, 64); dw += __shfl_down(dw, o, 64); }
    if (lane == 0) score[node] = tanhf(dx / sqrtf(dw));
}

__global__ __launch_bounds__(128) void pool_kernel(const float* __restrict__ score,
                                                   int* __restrict__ nmask) {
    int g = blockIdx.x, t = threadIdx.x;
    __shared__ float kv[128];
    __shared__ int cnt_s;
    if (t == 0) cnt_s = 0;
    int alive = 0;
    float ck = -2.0f;
    int node = g * S_NODES + t;
    if (t < S_NODES) { alive = nmask[node]; ck = alive ? score[node] : -1.5f; }
    kv[t] = ck;
    __syncthreads();
    if (alive) atomicAdd(&cnt_s, 1);
    __syncthreads();
    int k = (int)ceilf(0.8f * (float)cnt_s);   // f32, matches jnp.ceil(RATIO*n)
    int rank = 0;
    for (int j = 0; j < S_NODES; ++j) {
        float o = kv[j];
        rank += (o > ck || (o == ck && j < t)) ? 1 : 0;  // stable desc
    }
    if (t < S_NODES) nmask[node] = (alive && rank < k) ? 1 : 0;
}

__global__ void emask_update(const int* __restrict__ srcArr, const int* __restrict__ dstArr,
                             const int* __restrict__ nmask, int* __restrict__ emask) {
    int e = blockIdx.x * 256 + threadIdx.x;
    emask[e] = (emask[e] && nmask[srcArr[e]] && nmask[dstArr[e]]) ? 1 : 0;
}

__global__ void apply_pool(float* __restrict__ x, const float* __restrict__ score,
                           const int* __restrict__ nmask) {
    size_t idx = (size_t)blockIdx.x * 256 + threadIdx.x;
    int node = (int)(idx >> 8);
    x[idx] = nmask[node] ? x[idx] * score[node] : 0.f;
}

__global__ __launch_bounds__(256) void readout_kernel(const float* __restrict__ x,
                                                      const int* __restrict__ nmask,
                                                      float* __restrict__ acc) {
    int g = blockIdx.x, c = threadIdx.x;
    float mx = NEGF, sm = 0.f, cnt = 0.f;
    int base = g * S_NODES;
    for (int o = 0; o < S_NODES; ++o) {
        if (nmask[base + o]) {
            float v = x[(size_t)(base + o) * HDF + c];
            mx = fmaxf(mx, v);
            sm += v;
            cnt += 1.f;
        }
    }
    acc[(size_t)g * 512 + c] += mx;
    acc[(size_t)g * 512 + 256 + c] += sm / fmaxf(cnt, 1.f);
}

// ---------------------------------------------------------------- MLP head
__global__ __launch_bounds__(128) void mlp_kernel(
    const float* __restrict__ acc1, const float* __restrict__ acc2,
    const float* __restrict__ W1, const float* __restrict__ b1,
    const float* __restrict__ W2, const float* __restrict__ b2,
    const float* __restrict__ W3, const float* __restrict__ b3,
    float* __restrict__ out)
{
    int g = blockIdx.x, t = threadIdx.x;
    __shared__ float hrow[1024];
    __shared__ float h1s[128];
    __shared__ float h2s[64];
    __shared__ float o3[10];
    for (int j = t; j < 512; j += 128) {
        hrow[j] = acc1[(size_t)g * 512 + j];
        hrow[512 + j] = acc2[(size_t)g * 512 + j];
    }
    __syncthreads();
    float s = b1[t];
    for (int kx = 0; kx < 1024; ++kx) s += hrow[kx] * W1[(size_t)kx * 128 + t];
    h1s[t] = fmaxf(s, 0.f);
    __syncthreads();
    if (t < 64) {
        float s2 = b2[t];
        for (int kx = 0; kx < 128; ++kx) s2 += h1s[kx] * W2[kx * 64 + t];
        h2s[t] = fmaxf(s2, 0.f);
    }
    __syncthreads();
    if (t < 10) {
        float s3 = b3[t];
        for (int kx = 0; kx < 64; ++kx) s3 += h2s[kx] * W3[kx * 10 + t];
        o3[t] = s3;
    }
    __syncthreads();
    if (t < 10) {
        float m = o3[0];
        for (int j = 1; j < 10; ++j) m = fmaxf(m, o3[j]);
        float se = 0.f;
        for (int j = 0; j < 10; ++j) se += expf(o3[j] - m);
        out[g * 10 + t] = o3[t] - m - logf(se);
    }
}

// ---------------------------------------------------------------- launch
extern "C" void kernel_launch(void* const* d_in, const int* in_sizes, int n_in,
                              void* d_out, int out_size, void* d_ws, size_t ws_size,
                              hipStream_t stream) {
    (void)n_in; (void)out_size; (void)ws_size;
    const float* x0 = (const float*)d_in[0];
    const int* src = (const int*)d_in[1];
    const int* dst = src + N_EDGES;

    bool dictOrder = (in_sizes[7] == 64 * 768);
    const float *gatW[3], *gatAtt[3], *gatB[3], *gatRes[3];
    const float *gtWqkv[3], *gtBqkv[3], *gtWskip[3], *gtBskip[3];
    const float *gatPool, *gtPool;
    if (dictOrder) {
        for (int l = 0; l < 3; ++l) {
            int b = 3 + l * 8;
            gatW[l]    = (const float*)d_in[b + 0];
            gatAtt[l]  = (const float*)d_in[b + 1];
            gatB[l]    = (const float*)d_in[b + 2];
            gatRes[l]  = (const float*)d_in[b + 3];
            gtWqkv[l]  = (const float*)d_in[b + 4];
            gtBqkv[l]  = (const float*)d_in[b + 5];
            gtWskip[l] = (const float*)d_in[b + 6];
            gtBskip[l] = (const float*)d_in[b + 7];
        }
        gatPool = (const float*)d_in[27];
        gtPool  = (const float*)d_in[28];
    } else {
        for (int l = 0; l < 3; ++l) {
            int b = 3 + l * 4;
            gatW[l]   = (const float*)d_in[b + 0];
            gatAtt[l] = (const float*)d_in[b + 1];
            gatB[l]   = (const float*)d_in[b + 2];
            gatRes[l] = (const float*)d_in[b + 3];
            int c = 16 + l * 4;
            gtWqkv[l]  = (const float*)d_in[c + 0];
            gtBqkv[l]  = (const float*)d_in[c + 1];
            gtWskip[l] = (const float*)d_in[c + 2];
            gtBskip[l] = (const float*)d_in[c + 3];
        }
        gatPool = (const float*)d_in[15];
        gtPool  = (const float*)d_in[28];
    }
    const float* lin1W = (const float*)d_in[29];
    const float* lin1b = (const float*)d_in[30];
    const float* lin2W = (const float*)d_in[31];
    const float* lin2b = (const float*)d_in[32];
    const float* lin3W = (const float*)d_in[33];
    const float* lin3b = (const float*)d_in[34];

    char* wsp = (char*)d_ws;
    size_t off = 0;
    auto carve = [&](size_t bytes) -> void* {
        void* p = wsp + off;
        off += (bytes + 255) & ~(size_t)255;
        return p;
    };
    float* bufX   = (float*)carve((size_t)N_NODES * HDF * 4);   // 52.4 MB
    float* bufH   = (float*)carve((size_t)N_NODES * 768 * 4);   // 157.3 MB
    float* aS     = (float*)carve((size_t)N_NODES * 4 * 4);
    float* aD     = (float*)carve((size_t)N_NODES * 4 * 4);
    float* scoreB = (float*)carve((size_t)N_NODES * 4);
    int* nmask    = (int*)carve((size_t)N_NODES * 4);
    int* emask    = (int*)carve((size_t)N_EDGES * 4);
    int* deg      = (int*)carve((size_t)N_NODES * 4);
    int* rowStart = (int*)carve((size_t)(N_NODES + 1) * 4);
    int* cursor   = (int*)carve((size_t)N_NODES * 4);
    int* edgeIdx  = (int*)carve((size_t)N_EDGES * 4);
    float* acc1   = (float*)carve((size_t)N_GRAPHS * 512 * 4);
    float* acc2   = (float*)carve((size_t)N_GRAPHS * 512 * 4);
    float* ysec   = bufH + (size_t)N_NODES * HDF;   // spare 2nd third of bufH (GAT agg)

    set_int<<<N_NODES / 256, 256, 0, stream>>>(deg, 0, N_NODES);
    set_int<<<N_NODES / 256, 256, 0, stream>>>(cursor, 0, N_NODES);
    set_int<<<(N_GRAPHS * 512) / 256, 256, 0, stream>>>((int*)acc1, 0, N_GRAPHS * 512);
    set_int<<<(N_GRAPHS * 512) / 256, 256, 0, stream>>>((int*)acc2, 0, N_GRAPHS * 512);

    count_deg<<<N_EDGES / 256, 256, 0, stream>>>(dst, deg);
    scan_deg<<<1, 1024, 0, stream>>>(deg, rowStart);
    scatter_edges<<<N_EDGES / 256, 256, 0, stream>>>(dst, cursor, rowStart, edgeIdx);

    for (int br = 0; br < 2; ++br) {
        bool isGAT = (br == 0);
        float* acc = isGAT ? acc1 : acc2;
        const float* poolW = isGAT ? gatPool : gtPool;
        set_int<<<N_NODES / 256, 256, 0, stream>>>(nmask, 1, N_NODES);
        set_int<<<N_EDGES / 256, 256, 0, stream>>>(emask, 1, N_EDGES);
        const float* xcur = x0;
        int fi = 64;
        for (int l = 0; l < 3; ++l) {
            if (isGAT) {
                mfma_gemm<<<dim3(1, N_NODES / 128), 512, 0, stream>>>(
                    xcur, gatW[l], nullptr, bufH, fi, 256, nullptr, 0, nullptr);
                gat_att<<<N_NODES, 256, 0, stream>>>(bufH, gatAtt[l], aS, aD);
                gat_edge<<<N_NODES, 256, 0, stream>>>(bufH, aS, aD, rowStart, edgeIdx,
                                                      src, emask, nmask, ysec);
                mfma_gemm<<<dim3(1, N_NODES / 128), 512, 0, stream>>>(
                    xcur, gatRes[l], gatB[l], bufX, fi, 256, ysec, HDF, nmask);
            } else {
                mfma_gemm<<<dim3(3, N_NODES / 128), 512, 0, stream>>>(
                    xcur, gtWqkv[l], gtBqkv[l], bufH, fi, 768, nullptr, 0, nullptr);
                gt_edge<<<N_NODES, 256, 0, stream>>>(bufH, rowStart, edgeIdx,
                                                     src, emask, nmask);
                mfma_gemm<<<dim3(1, N_NODES / 128), 512, 0, stream>>>(
                    xcur, gtWskip[l], gtBskip[l], bufX, fi, 256, bufH /*agg q-slots*/, 768, nmask);
            }
            score_kernel<<<N_NODES / 4, 256, 0, stream>>>(bufX, poolW + l * HDF, scoreB);
            pool_kernel<<<N_GRAPHS, 128, 0, stream>>>(scoreB, nmask);
            emask_update<<<N_EDGES / 256, 256, 0, stream>>>(src, dst, nmask, emask);
            apply_pool<<<N_NODES, 256, 0, stream>>>(bufX, scoreB, nmask);
            readout_kernel<<<N_GRAPHS, 256, 0, stream>>>(bufX, nmask, acc);
            xcur = bufX;
            fi = HDF;
        }
    }
    mlp_kernel<<<N_GRAPHS, 128, 0, stream>>>(acc1, acc2, lin1W, lin1b, lin2W, lin2b,
                                             lin3W, lin3b, (float*)d_out);
}

// Round 5
// 1856.643 us; speedup vs baseline: 1.8132x; 1.0964x over previous
//
#include <hip/hip_runtime.h>
#include <hip/hip_bf16.h>
#include <math.h>

#define N_NODES 51200
#define N_GRAPHS 512
#define S_NODES 100
#define N_EDGES 512000
#define HDF 256          // H*D
#define NEGF (-1e30f)
#define MAXD 256

typedef short bf16x8 __attribute__((ext_vector_type(8)));
typedef float f32x4 __attribute__((ext_vector_type(4)));

__device__ inline unsigned short f2b(float x) {   // fp32 -> bf16 RNE
    union { float f; unsigned u; } v; v.f = x;
    unsigned r = v.u + 0x7FFFu + ((v.u >> 16) & 1u);
    return (unsigned short)(r >> 16);
}
__device__ inline float b2f(unsigned short b) {
    union { float f; unsigned u; } v; v.u = ((unsigned)b) << 16; return v.f;
}

// ---------------------------------------------------------------- util
__global__ void set_int(int* __restrict__ p, int v, int n) {
    int i = blockIdx.x * 256 + threadIdx.x;
    if (i < n) p[i] = v;
}

// ------------------------------------------------- split-bf16 MFMA GEMM
// C[rows x NC] = (rowScale.*A)[rows x K] @ B[K x NC] (+bias), 3-term bf16
// split (hi*hi + hi*lo + lo*hi), fp32 MFMA acc. Tile 128x256, 512 thr,
// 8 waves (2x4), 64x64/wave. grid = (NC/256, rows/128).
// rowScale!=null: A row r scaled by (rsMask[r]? rowScale[r] : 0)  (top-k fold)
// agg != null: fused epilogue out = relu(acc+agg+bias)*nmask, out stride 256.
__global__ __launch_bounds__(512) void mfma_gemm(
    const float* __restrict__ A, const float* __restrict__ B,
    const float* __restrict__ bias, float* __restrict__ C,
    int K, int NC,
    const float* __restrict__ agg, int aggStride,
    const int* __restrict__ nmaskArr,
    const float* __restrict__ rowScale, const int* __restrict__ rsMask)
{
    __shared__ unsigned short Ah[4 * 128 * 8];   // [kg][row][j]
    __shared__ unsigned short Al[4 * 128 * 8];
    __shared__ unsigned short Bh[4 * 256 * 8];   // [kg][col][j]
    __shared__ unsigned short Bl[4 * 256 * 8];
    int row0 = blockIdx.y * 128, col0 = blockIdx.x * 256;
    int t = threadIdx.x;
    int lane = t & 63, w = t >> 6;
    int wr = w >> 2, wc = w & 3;          // 2 x 4 wave grid
    int l15 = lane & 15, l4 = lane >> 4;
    f32x4 acc[4][4];
    #pragma unroll
    for (int m = 0; m < 4; ++m)
        #pragma unroll
        for (int n = 0; n < 4; ++n) acc[m][n] = (f32x4){0.f, 0.f, 0.f, 0.f};

    int arow = t & 127, akg = t >> 7;     // A staging: 1 task (row, kgroup)
    int bcol = t & 255, bhalf = t >> 8;   // B staging: 2 tasks (col, kgroup)
    float ascale = 1.f;
    if (rowScale) ascale = rsMask[row0 + arow] ? rowScale[row0 + arow] : 0.f;

    for (int k0 = 0; k0 < K; k0 += 32) {
        // ---- stage A (fp32 -> hi/lo bf16), with folded top-k row scale
        const float* ap = A + (size_t)(row0 + arow) * K + k0 + akg * 8;
        float4 a0 = *(const float4*)ap;
        float4 a1 = *(const float4*)(ap + 4);
        float av[8] = {a0.x, a0.y, a0.z, a0.w, a1.x, a1.y, a1.z, a1.w};
        int abase = (akg * 128 + arow) * 8;
        #pragma unroll
        for (int j = 0; j < 8; ++j) {
            float s = av[j] * ascale;
            unsigned short h = f2b(s);
            Ah[abase + j] = h;
            Al[abase + j] = f2b(s - b2f(h));
        }
        // ---- stage B
        #pragma unroll
        for (int q = 0; q < 2; ++q) {
            int kg = bhalf * 2 + q;
            int bbase = (kg * 256 + bcol) * 8;
            #pragma unroll
            for (int j = 0; j < 8; ++j) {
                float bvf = B[(size_t)(k0 + kg * 8 + j) * NC + col0 + bcol];
                unsigned short h = f2b(bvf);
                Bh[bbase + j] = h;
                Bl[bbase + j] = f2b(bvf - b2f(h));
            }
        }
        __syncthreads();
        // ---- fragments + MFMA
        bf16x8 bh[4], bl[4];
        #pragma unroll
        for (int n = 0; n < 4; ++n) {
            int idx = (l4 * 256 + wc * 64 + n * 16 + l15) * 8;
            bh[n] = *(bf16x8*)&Bh[idx];
            bl[n] = *(bf16x8*)&Bl[idx];
        }
        #pragma unroll
        for (int m = 0; m < 4; ++m) {
            int idx = (l4 * 128 + wr * 64 + m * 16 + l15) * 8;
            bf16x8 ah = *(bf16x8*)&Ah[idx];
            bf16x8 al = *(bf16x8*)&Al[idx];
            #pragma unroll
            for (int n = 0; n < 4; ++n) {
                acc[m][n] = __builtin_amdgcn_mfma_f32_16x16x32_bf16(ah, bh[n], acc[m][n], 0, 0, 0);
                acc[m][n] = __builtin_amdgcn_mfma_f32_16x16x32_bf16(ah, bl[n], acc[m][n], 0, 0, 0);
                acc[m][n] = __builtin_amdgcn_mfma_f32_16x16x32_bf16(al, bh[n], acc[m][n], 0, 0, 0);
            }
        }
        __syncthreads();
    }
    // ---- epilogue: D row = wr*64+m*16+l4*4+r, col = wc*64+n*16+l15
    bool fused = (agg != nullptr);
    #pragma unroll
    for (int m = 0; m < 4; ++m) {
        #pragma unroll
        for (int n = 0; n < 4; ++n) {
            int col = col0 + wc * 64 + n * 16 + l15;
            float bv = bias ? bias[col] : 0.f;
            #pragma unroll
            for (int r = 0; r < 4; ++r) {
                int row = row0 + wr * 64 + m * 16 + l4 * 4 + r;
                float v = acc[m][n][r] + bv;
                if (fused) {
                    v += agg[(size_t)row * aggStride + col];
                    float nm = nmaskArr[row] ? 1.f : 0.f;
                    C[(size_t)row * 256 + col] = fmaxf(v, 0.f) * nm;
                } else {
                    C[(size_t)row * NC + col] = v;
                }
            }
        }
    }
}

// ---------------------------------------------------------------- CSR build
__global__ void count_deg(const int* __restrict__ dst, int* __restrict__ deg) {
    int e = blockIdx.x * 256 + threadIdx.x;
    atomicAdd(&deg[dst[e]], 1);
}

__global__ __launch_bounds__(1024) void scan_deg(const int* __restrict__ deg,
                                                 int* __restrict__ rowStart) {
    __shared__ int part[1024];
    int t = threadIdx.x;
    const int chunk = N_NODES / 1024;      // 50
    int s = t * chunk;
    int sum = 0;
    for (int i = 0; i < chunk; ++i) sum += deg[s + i];
    part[t] = sum;
    __syncthreads();
    for (int d = 1; d < 1024; d <<= 1) {
        int v = (t >= d) ? part[t - d] : 0;
        __syncthreads();
        part[t] += v;
        __syncthreads();
    }
    int excl = (t == 0) ? 0 : part[t - 1];
    for (int i = 0; i < chunk; ++i) { rowStart[s + i] = excl; excl += deg[s + i]; }
    if (t == 1023) rowStart[N_NODES] = part[1023];
}

__global__ void scatter_edges(const int* __restrict__ dst, int* __restrict__ cursor,
                              const int* __restrict__ rowStart, int* __restrict__ edgeIdx) {
    int e = blockIdx.x * 256 + threadIdx.x;
    int d = dst[e];
    int p = atomicAdd(&cursor[d], 1);
    edgeIdx[rowStart[d] + p] = e;
}

// ---------------------------------------------------------------- GAT pieces
__global__ __launch_bounds__(256) void gat_att(const float* __restrict__ hfeat,
                                               const float* __restrict__ att,
                                               float* __restrict__ aS, float* __restrict__ aD) {
    int i = blockIdx.x, t = threadIdx.x, hh = t >> 6, d = t & 63;
    float hv = hfeat[(size_t)i * HDF + t];
    float p0 = hv * att[hh * 64 + d];
    float p1 = hv * att[256 + hh * 64 + d];
    #pragma unroll
    for (int o = 32; o > 0; o >>= 1) { p0 += __shfl_down(p0, o, 64); p1 += __shfl_down(p1, o, 64); }
    if (d == 0) { aS[i * 4 + hh] = p0; aD[i * 4 + hh] = p1; }
}

// per-dst attention aggregation -> aggOut (stride 256).
// edge mask == nmask[src] (see launch comment); wave-parallel softmax.
__global__ __launch_bounds__(256) void gat_edge(
    const float* __restrict__ hfeat, const float* __restrict__ aS, const float* __restrict__ aD,
    const int* __restrict__ rowStart, const int* __restrict__ edgeIdx,
    const int* __restrict__ srcArr, const int* __restrict__ nmask,
    float* __restrict__ aggOut)
{
    int bid = blockIdx.x;
    int i = (bid & 7) * (N_NODES / 8) + (bid >> 3);   // XCD-swizzle: graph->one XCD
    int t = threadIdx.x;
    int w = t >> 6, l = t & 63;
    __shared__ int sSrc[MAXD + 1];
    __shared__ float sL[MAXD + 1][4];
    __shared__ float sAcc[3][256];
    if (!nmask[i]) {
        aggOut[i * HDF + t] = 0.f;
        return;
    }
    int rs = rowStart[i], re = rowStart[i + 1];
    int deg = min(re - rs, MAXD);
    float ad0 = aD[i * 4 + 0], ad1 = aD[i * 4 + 1];
    float ad2 = aD[i * 4 + 2], ad3 = aD[i * 4 + 3];
    for (int j = t; j < deg; j += 256) {
        int e = edgeIdx[rs + j];
        int s_ = srcArr[e];
        int ok = nmask[s_];
        sSrc[j] = ok ? s_ : -1;
        float adv[4] = {ad0, ad1, ad2, ad3};
        #pragma unroll
        for (int h2 = 0; h2 < 4; ++h2) {
            float lg = aS[s_ * 4 + h2] + adv[h2];
            lg = (lg >= 0.f) ? lg : 0.2f * lg;
            sL[j][h2] = ok ? lg : NEGF;
        }
    }
    if (t == 0) {   // self loop (node alive here)
        sSrc[deg] = i;
        float adv[4] = {ad0, ad1, ad2, ad3};
        #pragma unroll
        for (int h2 = 0; h2 < 4; ++h2) {
            float lg = aS[i * 4 + h2] + adv[h2];
            sL[deg][h2] = (lg >= 0.f) ? lg : 0.2f * lg;
        }
    }
    __syncthreads();
    int tot = deg + 1;
    // wave-parallel softmax: wave w = head w, lane l = edge l (+64-folds)
    {
        float m = NEGF;
        for (int j = l; j < tot; j += 64) if (sSrc[j] >= 0) m = fmaxf(m, sL[j][w]);
        #pragma unroll
        for (int o = 32; o > 0; o >>= 1) m = fmaxf(m, __shfl_xor(m, o, 64));
        float part = 0.f;
        for (int j = l; j < tot; j += 64) {
            float e = (sSrc[j] >= 0) ? __expf(sL[j][w] - m) : 0.f;
            sL[j][w] = e;
            part += e;
        }
        #pragma unroll
        for (int o = 32; o > 0; o >>= 1) part += __shfl_xor(part, o, 64);
        float inv = 1.f / fmaxf(part, 1e-16f);
        for (int j = l; j < tot; j += 64) sL[j][w] *= inv;
    }
    __syncthreads();
    int hh4 = l >> 4;                     // head owning dims 4l..4l+3
    float4 a4 = make_float4(0.f, 0.f, 0.f, 0.f);
    for (int j = w; j < tot; j += 4) {
        int s_ = sSrc[j];
        if (s_ < 0) continue;
        float a = sL[j][hh4];
        float4 v4 = *(const float4*)&hfeat[s_ * HDF + l * 4];
        a4.x += a * v4.x; a4.y += a * v4.y; a4.z += a * v4.z; a4.w += a * v4.w;
    }
    if (w > 0) *(float4*)&sAcc[w - 1][l * 4] = a4;
    __syncthreads();
    if (w == 0) {
        float4 p0 = *(const float4*)&sAcc[0][l * 4];
        float4 p1 = *(const float4*)&sAcc[1][l * 4];
        float4 p2 = *(const float4*)&sAcc[2][l * 4];
        a4.x += p0.x + p1.x + p2.x;
        a4.y += p0.y + p1.y + p2.y;
        a4.z += p0.z + p1.z + p2.z;
        a4.w += p0.w + p1.w + p2.w;
        *(float4*)(aggOut + i * HDF + l * 4) = a4;
    }
}

// ---------------------------------------------------------------- GT piece
// qkv row: [q(256) | k(256) | v(256)]. Writes agg over OWN q-slot (race-free).
// edge mask == nmask[src]; wave-parallel logits + softmax + gather.
__global__ __launch_bounds__(256) void gt_edge(
    float* __restrict__ qkv,
    const int* __restrict__ rowStart, const int* __restrict__ edgeIdx,
    const int* __restrict__ srcArr, const int* __restrict__ nmask)
{
    int bid = blockIdx.x;
    int i = (bid & 7) * (N_NODES / 8) + (bid >> 3);   // XCD-swizzle
    int t = threadIdx.x;
    int w = t >> 6, l = t & 63;
    __shared__ float sQ[256];
    __shared__ int sSrc[MAXD];
    __shared__ float sL[MAXD][4];
    __shared__ float sAcc[3][256];
    if (!nmask[i]) {
        qkv[i * 768 + t] = 0.f;
        return;
    }
    int rs = rowStart[i], re = rowStart[i + 1];
    int deg = min(re - rs, MAXD);
    sQ[t] = qkv[i * 768 + t];
    __syncthreads();
    // phase A: wave w handles edges j = w mod 4; lane l covers dims 4l..4l+3
    float4 q4 = *(const float4*)&sQ[l * 4];
    for (int j = w; j < deg; j += 4) {
        int e = edgeIdx[rs + j];
        int s_ = srcArr[e];
        int ok = nmask[s_];
        float4 k4 = *(const float4*)&qkv[s_ * 768 + 256 + l * 4];
        float p = q4.x * k4.x + q4.y * k4.y + q4.z * k4.z + q4.w * k4.w;
        p += __shfl_xor(p, 1, 64);
        p += __shfl_xor(p, 2, 64);
        p += __shfl_xor(p, 4, 64);
        p += __shfl_xor(p, 8, 64);
        if ((l & 15) == 0) sL[j][l >> 4] = ok ? p * 0.125f : NEGF;
        if (l == 0) sSrc[j] = ok ? s_ : -1;
    }
    __syncthreads();
    // phase B: wave-parallel softmax (wave w = head w, lane l = edge l)
    {
        float m = NEGF;
        for (int j = l; j < deg; j += 64) if (sSrc[j] >= 0) m = fmaxf(m, sL[j][w]);
        #pragma unroll
        for (int o = 32; o > 0; o >>= 1) m = fmaxf(m, __shfl_xor(m, o, 64));
        float part = 0.f;
        for (int j = l; j < deg; j += 64) {
            float e = (sSrc[j] >= 0) ? __expf(sL[j][w] - m) : 0.f;
            sL[j][w] = e;
            part += e;
        }
        #pragma unroll
        for (int o = 32; o > 0; o >>= 1) part += __shfl_xor(part, o, 64);
        float inv = 1.f / fmaxf(part, 1e-16f);
        for (int j = l; j < deg; j += 64) sL[j][w] *= inv;
    }
    __syncthreads();
    // phase C: wave-parallel weighted V gather with precomputed alpha
    int hh4 = l >> 4;
    float4 a4 = make_float4(0.f, 0.f, 0.f, 0.f);
    for (int j = w; j < deg; j += 4) {
        int s_ = sSrc[j];
        if (s_ < 0) continue;
        float a = sL[j][hh4];
        float4 v4 = *(const float4*)&qkv[s_ * 768 + 512 + l * 4];
        a4.x += a * v4.x; a4.y += a * v4.y; a4.z += a * v4.z; a4.w += a * v4.w;
    }
    if (w > 0) *(float4*)&sAcc[w - 1][l * 4] = a4;
    __syncthreads();
    if (w == 0) {
        float4 p0 = *(const float4*)&sAcc[0][l * 4];
        float4 p1 = *(const float4*)&sAcc[1][l * 4];
        float4 p2 = *(const float4*)&sAcc[2][l * 4];
        a4.x += p0.x + p1.x + p2.x;
        a4.y += p0.y + p1.y + p2.y;
        a4.z += p0.z + p1.z + p2.z;
        a4.w += p0.w + p1.w + p2.w;
        *(float4*)(qkv + i * 768 + l * 4) = a4;
    }
}

// ---------------------------------------------------------------- pooling
__global__ __launch_bounds__(256) void score_kernel(const float* __restrict__ x,
                                                    const float* __restrict__ w,
                                                    float* __restrict__ score) {
    int wave = threadIdx.x >> 6, lane = threadIdx.x & 63;
    int node = blockIdx.x * 4 + wave;
    float dx = 0.f, dw = 0.f;
    #pragma unroll
    for (int c = 0; c < 4; ++c) {
        int cc = lane + c * 64;
        float wv = w[cc];
        dx += x[(size_t)node * HDF + cc] * wv;
        dw += wv * wv;
    }
    #pragma unroll
    for (int o = 32; o > 0; o >>= 1) { dx += __shfl_down(dx, o, 64); dw += __shfl_down(dw, o, 64); }
    if (lane == 0) score[node] = tanhf(dx / sqrtf(dw));
}

__global__ __launch_bounds__(128) void pool_kernel(const float* __restrict__ score,
                                                   int* __restrict__ nmask) {
    int g = blockIdx.x, t = threadIdx.x;
    __shared__ float kv[128];
    __shared__ int cnt_s;
    if (t == 0) cnt_s = 0;
    int alive = 0;
    float ck = -2.0f;
    int node = g * S_NODES + t;
    if (t < S_NODES) { alive = nmask[node]; ck = alive ? score[node] : -1.5f; }
    kv[t] = ck;
    __syncthreads();
    if (alive) atomicAdd(&cnt_s, 1);
    __syncthreads();
    int k = (int)ceilf(0.8f * (float)cnt_s);   // f32, matches jnp.ceil(RATIO*n)
    int rank = 0;
    for (int j = 0; j < S_NODES; ++j) {
        float o = kv[j];
        rank += (o > ck || (o == ck && j < t)) ? 1 : 0;  // stable desc
    }
    if (t < S_NODES) nmask[node] = (alive && rank < k) ? 1 : 0;
}

// readout with folded top-k scaling: v = x[node]*score[node] for alive nodes
__global__ __launch_bounds__(256) void readout_kernel(const float* __restrict__ x,
                                                      const float* __restrict__ score,
                                                      const int* __restrict__ nmask,
                                                      float* __restrict__ acc) {
    int g = blockIdx.x, c = threadIdx.x;
    float mx = NEGF, sm = 0.f, cnt = 0.f;
    int base = g * S_NODES;
    for (int o = 0; o < S_NODES; ++o) {
        if (nmask[base + o]) {
            float v = x[(size_t)(base + o) * HDF + c] * score[base + o];
            mx = fmaxf(mx, v);
            sm += v;
            cnt += 1.f;
        }
    }
    acc[(size_t)g * 512 + c] += mx;
    acc[(size_t)g * 512 + 256 + c] += sm / fmaxf(cnt, 1.f);
}

// ---------------------------------------------------------------- MLP head
__global__ __launch_bounds__(128) void mlp_kernel(
    const float* __restrict__ acc1, const float* __restrict__ acc2,
    const float* __restrict__ W1, const float* __restrict__ b1,
    const float* __restrict__ W2, const float* __restrict__ b2,
    const float* __restrict__ W3, const float* __restrict__ b3,
    float* __restrict__ out)
{
    int g = blockIdx.x, t = threadIdx.x;
    __shared__ float hrow[1024];
    __shared__ float h1s[128];
    __shared__ float h2s[64];
    __shared__ float o3[10];
    for (int j = t; j < 512; j += 128) {
        hrow[j] = acc1[(size_t)g * 512 + j];
        hrow[512 + j] = acc2[(size_t)g * 512 + j];
    }
    __syncthreads();
    float s = b1[t];
    for (int kx = 0; kx < 1024; ++kx) s += hrow[kx] * W1[(size_t)kx * 128 + t];
    h1s[t] = fmaxf(s, 0.f);
    __syncthreads();
    if (t < 64) {
        float s2 = b2[t];
        for (int kx = 0; kx < 128; ++kx) s2 += h1s[kx] * W2[kx * 64 + t];
        h2s[t] = fmaxf(s2, 0.f);
    }
    __syncthreads();
    if (t < 10) {
        float s3 = b3[t];
        for (int kx = 0; kx < 64; ++kx) s3 += h2s[kx] * W3[kx * 10 + t];
        o3[t] = s3;
    }
    __syncthreads();
    if (t < 10) {
        float m = o3[0];
        for (int j = 1; j < 10; ++j) m = fmaxf(m, o3[j]);
        float se = 0.f;
        for (int j = 0; j < 10; ++j) se += expf(o3[j] - m);
        out[g * 10 + t] = o3[t] - m - logf(se);
    }
}

// ---------------------------------------------------------------- launch
extern "C" void kernel_launch(void* const* d_in, const int* in_sizes, int n_in,
                              void* d_out, int out_size, void* d_ws, size_t ws_size,
                              hipStream_t stream) {
    (void)n_in; (void)out_size; (void)ws_size;
    const float* x0 = (const float*)d_in[0];
    const int* src = (const int*)d_in[1];
    const int* dst = src + N_EDGES;

    bool dictOrder = (in_sizes[7] == 64 * 768);
    const float *gatW[3], *gatAtt[3], *gatB[3], *gatRes[3];
    const float *gtWqkv[3], *gtBqkv[3], *gtWskip[3], *gtBskip[3];
    const float *gatPool, *gtPool;
    if (dictOrder) {
        for (int l = 0; l < 3; ++l) {
            int b = 3 + l * 8;
            gatW[l]    = (const float*)d_in[b + 0];
            gatAtt[l]  = (const float*)d_in[b + 1];
            gatB[l]    = (const float*)d_in[b + 2];
            gatRes[l]  = (const float*)d_in[b + 3];
            gtWqkv[l]  = (const float*)d_in[b + 4];
            gtBqkv[l]  = (const float*)d_in[b + 5];
            gtWskip[l] = (const float*)d_in[b + 6];
            gtBskip[l] = (const float*)d_in[b + 7];
        }
        gatPool = (const float*)d_in[27];
        gtPool  = (const float*)d_in[28];
    } else {
        for (int l = 0; l < 3; ++l) {
            int b = 3 + l * 4;
            gatW[l]   = (const float*)d_in[b + 0];
            gatAtt[l] = (const float*)d_in[b + 1];
            gatB[l]   = (const float*)d_in[b + 2];
            gatRes[l] = (const float*)d_in[b + 3];
            int c = 16 + l * 4;
            gtWqkv[l]  = (const float*)d_in[c + 0];
            gtBqkv[l]  = (const float*)d_in[c + 1];
            gtWskip[l] = (const float*)d_in[c + 2];
            gtBskip[l] = (const float*)d_in[c + 3];
        }
        gatPool = (const float*)d_in[15];
        gtPool  = (const float*)d_in[28];
    }
    const float* lin1W = (const float*)d_in[29];
    const float* lin1b = (const float*)d_in[30];
    const float* lin2W = (const float*)d_in[31];
    const float* lin2b = (const float*)d_in[32];
    const float* lin3W = (const float*)d_in[33];
    const float* lin3b = (const float*)d_in[34];

    char* wsp = (char*)d_ws;
    size_t off = 0;
    auto carve = [&](size_t bytes) -> void* {
        void* p = wsp + off;
        off += (bytes + 255) & ~(size_t)255;
        return p;
    };
    float* bufX   = (float*)carve((size_t)N_NODES * HDF * 4);   // 52.4 MB
    float* bufH   = (float*)carve((size_t)N_NODES * 768 * 4);   // 157.3 MB
    float* aS     = (float*)carve((size_t)N_NODES * 4 * 4);
    float* aD     = (float*)carve((size_t)N_NODES * 4 * 4);
    float* scoreB = (float*)carve((size_t)N_NODES * 4);
    int* nmask    = (int*)carve((size_t)N_NODES * 4);
    int* deg      = (int*)carve((size_t)N_NODES * 4);
    int* rowStart = (int*)carve((size_t)(N_NODES + 1) * 4);
    int* cursor   = (int*)carve((size_t)N_NODES * 4);
    int* edgeIdx  = (int*)carve((size_t)N_EDGES * 4);
    float* acc1   = (float*)carve((size_t)N_GRAPHS * 512 * 4);
    float* acc2   = (float*)carve((size_t)N_GRAPHS * 512 * 4);
    float* ysec   = bufH + (size_t)N_NODES * HDF;   // spare 2nd third of bufH (GAT agg)

    set_int<<<N_NODES / 256, 256, 0, stream>>>(deg, 0, N_NODES);
    set_int<<<N_NODES / 256, 256, 0, stream>>>(cursor, 0, N_NODES);
    set_int<<<(N_GRAPHS * 512) / 256, 256, 0, stream>>>((int*)acc1, 0, N_GRAPHS * 512);
    set_int<<<(N_GRAPHS * 512) / 256, 256, 0, stream>>>((int*)acc2, 0, N_GRAPHS * 512);

    count_deg<<<N_EDGES / 256, 256, 0, stream>>>(dst, deg);
    scan_deg<<<1, 1024, 0, stream>>>(deg, rowStart);
    scatter_edges<<<N_EDGES / 256, 256, 0, stream>>>(dst, cursor, rowStart, edgeIdx);

    for (int br = 0; br < 2; ++br) {
        bool isGAT = (br == 0);
        float* acc = isGAT ? acc1 : acc2;
        const float* poolW = isGAT ? gatPool : gtPool;
        set_int<<<N_NODES / 256, 256, 0, stream>>>(nmask, 1, N_NODES);
        const float* xcur = x0;
        int fi = 64;
        for (int l = 0; l < 3; ++l) {
            // x_new = x*score*keep folded into GEMM A-staging (l>0)
            const float* rs = (l == 0) ? nullptr : scoreB;
            const int* rsm = (l == 0) ? nullptr : nmask;
            if (isGAT) {
                mfma_gemm<<<dim3(1, N_NODES / 128), 512, 0, stream>>>(
                    xcur, gatW[l], nullptr, bufH, fi, 256, nullptr, 0, nullptr, rs, rsm);
                gat_att<<<N_NODES, 256, 0, stream>>>(bufH, gatAtt[l], aS, aD);
                gat_edge<<<N_NODES, 256, 0, stream>>>(bufH, aS, aD, rowStart, edgeIdx,
                                                      src, nmask, ysec);
                mfma_gemm<<<dim3(1, N_NODES / 128), 512, 0, stream>>>(
                    xcur, gatRes[l], gatB[l], bufX, fi, 256, ysec, HDF, nmask, rs, rsm);
            } else {
                mfma_gemm<<<dim3(3, N_NODES / 128), 512, 0, stream>>>(
                    xcur, gtWqkv[l], gtBqkv[l], bufH, fi, 768, nullptr, 0, nullptr, rs, rsm);
                gt_edge<<<N_NODES, 256, 0, stream>>>(bufH, rowStart, edgeIdx, src, nmask);
                mfma_gemm<<<dim3(1, N_NODES / 128), 512, 0, stream>>>(
                    xcur, gtWskip[l], gtBskip[l], bufX, fi, 256, bufH /*agg q-slots*/, 768,
                    nmask, rs, rsm);
            }
            score_kernel<<<N_NODES / 4, 256, 0, stream>>>(bufX, poolW + l * HDF, scoreB);
            pool_kernel<<<N_GRAPHS, 128, 0, stream>>>(scoreB, nmask);
            readout_kernel<<<N_GRAPHS, 256, 0, stream>>>(bufX, scoreB, nmask, acc);
            xcur = bufX;
            fi = HDF;
        }
    }
    mlp_kernel<<<N_GRAPHS, 128, 0, stream>>>(acc1, acc2, lin1W, lin1b, lin2W, lin2b,
                                             lin3W, lin3b, (float*)d_out);
}

// Round 6
// 1749.626 us; speedup vs baseline: 1.9241x; 1.0612x over previous
//
#include <hip/hip_runtime.h>
#include <hip/hip_bf16.h>
#include <math.h>

#define N_NODES 51200
#define N_GRAPHS 512
#define S_NODES 100
#define N_EDGES 512000
#define HDF 256          // H*D
#define NEGF (-1e30f)
#define MAXD 256

typedef short bf16x8 __attribute__((ext_vector_type(8)));
typedef float f32x4 __attribute__((ext_vector_type(4)));

__device__ inline unsigned short f2b(float x) {   // fp32 -> bf16 RNE
    union { float f; unsigned u; } v; v.f = x;
    unsigned r = v.u + 0x7FFFu + ((v.u >> 16) & 1u);
    return (unsigned short)(r >> 16);
}
__device__ inline float b2f(unsigned short b) {
    union { float f; unsigned u; } v; v.u = ((unsigned)b) << 16; return v.f;
}

// ---------------------------------------------------------------- util
__global__ void set_int(int* __restrict__ p, int v, int n) {
    int i = blockIdx.x * 256 + threadIdx.x;
    if (i < n) p[i] = v;
}

// pre-split weights: fp32 W[K x NC] -> bf16 hi/lo in MFMA fragment layout
// element (k,c) -> [(k>>3)*NC + c]*8 + (k&7)
__global__ void wsplit(const float* __restrict__ W, unsigned short* __restrict__ Wh,
                       unsigned short* __restrict__ Wl, int K, int NC) {
    int idx = blockIdx.x * 256 + threadIdx.x;
    if (idx >= K * NC) return;
    int k = idx / NC, c = idx - k * NC;
    float v = W[idx];
    unsigned short h = f2b(v);
    int o = ((k >> 3) * NC + c) * 8 + (k & 7);
    Wh[o] = h;
    Wl[o] = f2b(v - b2f(h));
}

// ------------------------------------------------- split-bf16 MFMA GEMM
// C[rows x NC] = (rowScale.*A)[rows x K] @ B[K x NC] (+bias), 3-term bf16
// split (hi*hi + hi*lo + lo*hi), fp32 MFMA acc. Tile 128x256, 512 thr,
// 8 waves (2x4), 64x64/wave. grid = (NC/256, rows/128).
// B passed pre-split in fragment layout (Bh_g/Bl_g from wsplit).
// rowScale!=null: A row r scaled by (rsMask[r]? rowScale[r] : 0)  (top-k fold)
// agg != null: fused epilogue out = relu(acc+agg+bias)*nmask, out stride 256.
__global__ __launch_bounds__(512) void mfma_gemm(
    const float* __restrict__ A,
    const unsigned short* __restrict__ Bh_g, const unsigned short* __restrict__ Bl_g,
    const float* __restrict__ bias, float* __restrict__ C,
    int K, int NC,
    const float* __restrict__ agg, int aggStride,
    const int* __restrict__ nmaskArr,
    const float* __restrict__ rowScale, const int* __restrict__ rsMask)
{
    __shared__ unsigned short Ah[4 * 128 * 8];   // [kg][row][j]
    __shared__ unsigned short Al[4 * 128 * 8];
    __shared__ unsigned short Bh[4 * 256 * 8];   // [kg][col][j]
    __shared__ unsigned short Bl[4 * 256 * 8];
    int row0 = blockIdx.y * 128, col0 = blockIdx.x * 256;
    int t = threadIdx.x;
    int lane = t & 63, w = t >> 6;
    int wr = w >> 2, wc = w & 3;          // 2 x 4 wave grid
    int l15 = lane & 15, l4 = lane >> 4;
    f32x4 acc[4][4];
    #pragma unroll
    for (int m = 0; m < 4; ++m)
        #pragma unroll
        for (int n = 0; n < 4; ++n) acc[m][n] = (f32x4){0.f, 0.f, 0.f, 0.f};

    int arow = t & 127, akg = t >> 7;     // A staging: 1 task (row, kgroup)
    int bcol = t & 255, bhalf = t >> 8;   // B staging: 2 tasks (col, kgroup)
    float ascale = 1.f;
    if (rowScale) ascale = rsMask[row0 + arow] ? rowScale[row0 + arow] : 0.f;

    for (int k0 = 0; k0 < K; k0 += 32) {
        // ---- stage A (fp32 -> hi/lo bf16), with folded top-k row scale
        const float* ap = A + (size_t)(row0 + arow) * K + k0 + akg * 8;
        float4 a0 = *(const float4*)ap;
        float4 a1 = *(const float4*)(ap + 4);
        float av[8] = {a0.x, a0.y, a0.z, a0.w, a1.x, a1.y, a1.z, a1.w};
        int abase = (akg * 128 + arow) * 8;
        #pragma unroll
        for (int j = 0; j < 8; ++j) {
            float s = av[j] * ascale;
            unsigned short h = f2b(s);
            Ah[abase + j] = h;
            Al[abase + j] = f2b(s - b2f(h));
        }
        // ---- stage B (pre-split, fragment layout: straight 16B copies)
        #pragma unroll
        for (int q = 0; q < 2; ++q) {
            int kg = bhalf * 2 + q;
            size_t gb = ((size_t)((k0 >> 3) + kg) * NC + col0 + bcol) * 8;
            int bbase = (kg * 256 + bcol) * 8;
            *(bf16x8*)&Bh[bbase] = *(const bf16x8*)&Bh_g[gb];
            *(bf16x8*)&Bl[bbase] = *(const bf16x8*)&Bl_g[gb];
        }
        __syncthreads();
        // ---- fragments + MFMA
        bf16x8 bh[4], bl[4];
        #pragma unroll
        for (int n = 0; n < 4; ++n) {
            int idx = (l4 * 256 + wc * 64 + n * 16 + l15) * 8;
            bh[n] = *(bf16x8*)&Bh[idx];
            bl[n] = *(bf16x8*)&Bl[idx];
        }
        #pragma unroll
        for (int m = 0; m < 4; ++m) {
            int idx = (l4 * 128 + wr * 64 + m * 16 + l15) * 8;
            bf16x8 ah = *(bf16x8*)&Ah[idx];
            bf16x8 al = *(bf16x8*)&Al[idx];
            #pragma unroll
            for (int n = 0; n < 4; ++n) {
                acc[m][n] = __builtin_amdgcn_mfma_f32_16x16x32_bf16(ah, bh[n], acc[m][n], 0, 0, 0);
                acc[m][n] = __builtin_amdgcn_mfma_f32_16x16x32_bf16(ah, bl[n], acc[m][n], 0, 0, 0);
                acc[m][n] = __builtin_amdgcn_mfma_f32_16x16x32_bf16(al, bh[n], acc[m][n], 0, 0, 0);
            }
        }
        __syncthreads();
    }
    // ---- epilogue: D row = wr*64+m*16+l4*4+r, col = wc*64+n*16+l15
    bool fused = (agg != nullptr);
    #pragma unroll
    for (int m = 0; m < 4; ++m) {
        #pragma unroll
        for (int n = 0; n < 4; ++n) {
            int col = col0 + wc * 64 + n * 16 + l15;
            float bv = bias ? bias[col] : 0.f;
            #pragma unroll
            for (int r = 0; r < 4; ++r) {
                int row = row0 + wr * 64 + m * 16 + l4 * 4 + r;
                float v = acc[m][n][r] + bv;
                if (fused) {
                    v += agg[(size_t)row * aggStride + col];
                    float nm = nmaskArr[row] ? 1.f : 0.f;
                    C[(size_t)row * 256 + col] = fmaxf(v, 0.f) * nm;
                } else {
                    C[(size_t)row * NC + col] = v;
                }
            }
        }
    }
}

// ---------------------------------------------------------------- CSR build
__global__ void count_deg(const int* __restrict__ dst, int* __restrict__ deg) {
    int e = blockIdx.x * 256 + threadIdx.x;
    atomicAdd(&deg[dst[e]], 1);
}

__global__ __launch_bounds__(1024) void scan_deg(const int* __restrict__ deg,
                                                 int* __restrict__ rowStart) {
    __shared__ int part[1024];
    int t = threadIdx.x;
    const int chunk = N_NODES / 1024;      // 50
    int s = t * chunk;
    int sum = 0;
    for (int i = 0; i < chunk; ++i) sum += deg[s + i];
    part[t] = sum;
    __syncthreads();
    for (int d = 1; d < 1024; d <<= 1) {
        int v = (t >= d) ? part[t - d] : 0;
        __syncthreads();
        part[t] += v;
        __syncthreads();
    }
    int excl = (t == 0) ? 0 : part[t - 1];
    for (int i = 0; i < chunk; ++i) { rowStart[s + i] = excl; excl += deg[s + i]; }
    if (t == 1023) rowStart[N_NODES] = part[1023];
}

// store SRC ids directly in CSR order (kills edgeIdx indirection)
__global__ void scatter_edges(const int* __restrict__ src, const int* __restrict__ dst,
                              int* __restrict__ cursor, const int* __restrict__ rowStart,
                              int* __restrict__ csrSrc) {
    int e = blockIdx.x * 256 + threadIdx.x;
    int d = dst[e];
    int p = atomicAdd(&cursor[d], 1);
    csrSrc[rowStart[d] + p] = src[e];
}

// ---------------------------------------------------------------- GAT pieces
__global__ __launch_bounds__(256) void gat_att(const float* __restrict__ hfeat,
                                               const float* __restrict__ att,
                                               float* __restrict__ aS, float* __restrict__ aD) {
    int i = blockIdx.x, t = threadIdx.x, hh = t >> 6, d = t & 63;
    float hv = hfeat[(size_t)i * HDF + t];
    float p0 = hv * att[hh * 64 + d];
    float p1 = hv * att[256 + hh * 64 + d];
    #pragma unroll
    for (int o = 32; o > 0; o >>= 1) { p0 += __shfl_down(p0, o, 64); p1 += __shfl_down(p1, o, 64); }
    if (d == 0) { aS[i * 4 + hh] = p0; aD[i * 4 + hh] = p1; }
}

// per-dst attention aggregation -> aggOut (stride 256).
// edge mask == nmask[src]; wave-parallel softmax; transposed sL (bank-safe).
__global__ __launch_bounds__(256) void gat_edge(
    const float* __restrict__ hfeat, const float* __restrict__ aS, const float* __restrict__ aD,
    const int* __restrict__ rowStart, const int* __restrict__ csrSrc,
    const int* __restrict__ nmask,
    float* __restrict__ aggOut)
{
    int bid = blockIdx.x;
    int i = (bid & 7) * (N_NODES / 8) + (bid >> 3);   // XCD-swizzle
    int t = threadIdx.x;
    int w = t >> 6, l = t & 63;
    __shared__ int sSrc[MAXD + 1];
    __shared__ float sL[4][MAXD + 4];
    __shared__ float sAcc[3][256];
    if (!nmask[i]) {
        aggOut[i * HDF + t] = 0.f;
        return;
    }
    int rs = rowStart[i], re = rowStart[i + 1];
    int deg = min(re - rs, MAXD);
    float4 ad4 = *(const float4*)&aD[i * 4];
    for (int j = t; j < deg; j += 256) {
        int s_ = csrSrc[rs + j];
        int ok = nmask[s_];
        sSrc[j] = ok ? s_ : -1;
        float4 as4 = *(const float4*)&aS[s_ * 4];
        float lg0 = as4.x + ad4.x, lg1 = as4.y + ad4.y;
        float lg2 = as4.z + ad4.z, lg3 = as4.w + ad4.w;
        lg0 = (lg0 >= 0.f) ? lg0 : 0.2f * lg0;
        lg1 = (lg1 >= 0.f) ? lg1 : 0.2f * lg1;
        lg2 = (lg2 >= 0.f) ? lg2 : 0.2f * lg2;
        lg3 = (lg3 >= 0.f) ? lg3 : 0.2f * lg3;
        sL[0][j] = ok ? lg0 : NEGF;
        sL[1][j] = ok ? lg1 : NEGF;
        sL[2][j] = ok ? lg2 : NEGF;
        sL[3][j] = ok ? lg3 : NEGF;
    }
    if (t == 0) {   // self loop (node alive here)
        sSrc[deg] = i;
        float4 as4 = *(const float4*)&aS[i * 4];
        float lg0 = as4.x + ad4.x, lg1 = as4.y + ad4.y;
        float lg2 = as4.z + ad4.z, lg3 = as4.w + ad4.w;
        sL[0][deg] = (lg0 >= 0.f) ? lg0 : 0.2f * lg0;
        sL[1][deg] = (lg1 >= 0.f) ? lg1 : 0.2f * lg1;
        sL[2][deg] = (lg2 >= 0.f) ? lg2 : 0.2f * lg2;
        sL[3][deg] = (lg3 >= 0.f) ? lg3 : 0.2f * lg3;
    }
    __syncthreads();
    int tot = deg + 1;
    // wave-parallel softmax: wave w = head w, lane l = edge l (+64-folds)
    {
        float m = NEGF;
        for (int j = l; j < tot; j += 64) if (sSrc[j] >= 0) m = fmaxf(m, sL[w][j]);
        #pragma unroll
        for (int o = 32; o > 0; o >>= 1) m = fmaxf(m, __shfl_xor(m, o, 64));
        float part = 0.f;
        for (int j = l; j < tot; j += 64) {
            float e = (sSrc[j] >= 0) ? __expf(sL[w][j] - m) : 0.f;
            sL[w][j] = e;
            part += e;
        }
        #pragma unroll
        for (int o = 32; o > 0; o >>= 1) part += __shfl_xor(part, o, 64);
        float inv = 1.f / fmaxf(part, 1e-16f);
        for (int j = l; j < tot; j += 64) sL[w][j] *= inv;
    }
    __syncthreads();
    int hh4 = l >> 4;                     // head owning dims 4l..4l+3
    float4 a4 = make_float4(0.f, 0.f, 0.f, 0.f);
    for (int j = w; j < tot; j += 4) {
        int s_ = sSrc[j];
        if (s_ < 0) continue;
        float a = sL[hh4][j];
        float4 v4 = *(const float4*)&hfeat[s_ * HDF + l * 4];
        a4.x += a * v4.x; a4.y += a * v4.y; a4.z += a * v4.z; a4.w += a * v4.w;
    }
    if (w > 0) *(float4*)&sAcc[w - 1][l * 4] = a4;
    __syncthreads();
    if (w == 0) {
        float4 p0 = *(const float4*)&sAcc[0][l * 4];
        float4 p1 = *(const float4*)&sAcc[1][l * 4];
        float4 p2 = *(const float4*)&sAcc[2][l * 4];
        a4.x += p0.x + p1.x + p2.x;
        a4.y += p0.y + p1.y + p2.y;
        a4.z += p0.z + p1.z + p2.z;
        a4.w += p0.w + p1.w + p2.w;
        *(float4*)(aggOut + i * HDF + l * 4) = a4;
    }
}

// ---------------------------------------------------------------- GT piece
// qkv row: [q(256) | k(256) | v(256)]. Writes agg over OWN q-slot (race-free).
// edge mask == nmask[src]; wave-parallel logits + softmax + gather.
__global__ __launch_bounds__(256) void gt_edge(
    float* __restrict__ qkv,
    const int* __restrict__ rowStart, const int* __restrict__ csrSrc,
    const int* __restrict__ nmask)
{
    int bid = blockIdx.x;
    int i = (bid & 7) * (N_NODES / 8) + (bid >> 3);   // XCD-swizzle
    int t = threadIdx.x;
    int w = t >> 6, l = t & 63;
    __shared__ float sQ[256];
    __shared__ int sSrc[MAXD];
    __shared__ float sL[4][MAXD + 4];
    __shared__ float sAcc[3][256];
    if (!nmask[i]) {
        qkv[i * 768 + t] = 0.f;
        return;
    }
    int rs = rowStart[i], re = rowStart[i + 1];
    int deg = min(re - rs, MAXD);
    sQ[t] = qkv[i * 768 + t];
    for (int j = t; j < deg; j += 256) {      // preload src ids (+nmask fold)
        int s_ = csrSrc[rs + j];
        sSrc[j] = nmask[s_] ? s_ : -1;
    }
    __syncthreads();
    // phase A: wave w handles edges j = w mod 4; lane l covers dims 4l..4l+3
    float4 q4 = *(const float4*)&sQ[l * 4];
    for (int j = w; j < deg; j += 4) {
        int s_ = sSrc[j];                      // wave-uniform
        float p = 0.f;
        if (s_ >= 0) {
            float4 k4 = *(const float4*)&qkv[s_ * 768 + 256 + l * 4];
            p = q4.x * k4.x + q4.y * k4.y + q4.z * k4.z + q4.w * k4.w;
        }
        p += __shfl_xor(p, 1, 64);
        p += __shfl_xor(p, 2, 64);
        p += __shfl_xor(p, 4, 64);
        p += __shfl_xor(p, 8, 64);
        if ((l & 15) == 0) sL[l >> 4][j] = (s_ >= 0) ? p * 0.125f : NEGF;
    }
    __syncthreads();
    // phase B: wave-parallel softmax (wave w = head w, lane l = edge l)
    {
        float m = NEGF;
        for (int j = l; j < deg; j += 64) if (sSrc[j] >= 0) m = fmaxf(m, sL[w][j]);
        #pragma unroll
        for (int o = 32; o > 0; o >>= 1) m = fmaxf(m, __shfl_xor(m, o, 64));
        float part = 0.f;
        for (int j = l; j < deg; j += 64) {
            float e = (sSrc[j] >= 0) ? __expf(sL[w][j] - m) : 0.f;
            sL[w][j] = e;
            part += e;
        }
        #pragma unroll
        for (int o = 32; o > 0; o >>= 1) part += __shfl_xor(part, o, 64);
        float inv = 1.f / fmaxf(part, 1e-16f);
        for (int j = l; j < deg; j += 64) sL[w][j] *= inv;
    }
    __syncthreads();
    // phase C: wave-parallel weighted V gather with precomputed alpha
    int hh4 = l >> 4;
    float4 a4 = make_float4(0.f, 0.f, 0.f, 0.f);
    for (int j = w; j < deg; j += 4) {
        int s_ = sSrc[j];
        if (s_ < 0) continue;
        float a = sL[hh4][j];
        float4 v4 = *(const float4*)&qkv[s_ * 768 + 512 + l * 4];
        a4.x += a * v4.x; a4.y += a * v4.y; a4.z += a * v4.z; a4.w += a * v4.w;
    }
    if (w > 0) *(float4*)&sAcc[w - 1][l * 4] = a4;
    __syncthreads();
    if (w == 0) {
        float4 p0 = *(const float4*)&sAcc[0][l * 4];
        float4 p1 = *(const float4*)&sAcc[1][l * 4];
        float4 p2 = *(const float4*)&sAcc[2][l * 4];
        a4.x += p0.x + p1.x + p2.x;
        a4.y += p0.y + p1.y + p2.y;
        a4.z += p0.z + p1.z + p2.z;
        a4.w += p0.w + p1.w + p2.w;
        *(float4*)(qkv + i * 768 + l * 4) = a4;
    }
}

// ---------------------------------------------------------------- pooling
__global__ __launch_bounds__(256) void score_kernel(const float* __restrict__ x,
                                                    const float* __restrict__ w,
                                                    float* __restrict__ score) {
    int wave = threadIdx.x >> 6, lane = threadIdx.x & 63;
    int node = blockIdx.x * 4 + wave;
    float dx = 0.f, dw = 0.f;
    #pragma unroll
    for (int c = 0; c < 4; ++c) {
        int cc = lane + c * 64;
        float wv = w[cc];
        dx += x[(size_t)node * HDF + cc] * wv;
        dw += wv * wv;
    }
    #pragma unroll
    for (int o = 32; o > 0; o >>= 1) { dx += __shfl_down(dx, o, 64); dw += __shfl_down(dw, o, 64); }
    if (lane == 0) score[node] = tanhf(dx / sqrtf(dw));
}

__global__ __launch_bounds__(128) void pool_kernel(const float* __restrict__ score,
                                                   int* __restrict__ nmask) {
    int g = blockIdx.x, t = threadIdx.x;
    __shared__ float kv[128];
    __shared__ int cnt_s;
    if (t == 0) cnt_s = 0;
    int alive = 0;
    float ck = -2.0f;
    int node = g * S_NODES + t;
    if (t < S_NODES) { alive = nmask[node]; ck = alive ? score[node] : -1.5f; }
    kv[t] = ck;
    __syncthreads();
    if (alive) atomicAdd(&cnt_s, 1);
    __syncthreads();
    int k = (int)ceilf(0.8f * (float)cnt_s);   // f32, matches jnp.ceil(RATIO*n)
    int rank = 0;
    for (int j = 0; j < S_NODES; ++j) {
        float o = kv[j];
        rank += (o > ck || (o == ck && j < t)) ? 1 : 0;  // stable desc
    }
    if (t < S_NODES) nmask[node] = (alive && rank < k) ? 1 : 0;
}

// readout with folded top-k scaling: v = x[node]*score[node] for alive nodes
__global__ __launch_bounds__(256) void readout_kernel(const float* __restrict__ x,
                                                      const float* __restrict__ score,
                                                      const int* __restrict__ nmask,
                                                      float* __restrict__ acc) {
    int g = blockIdx.x, c = threadIdx.x;
    float mx = NEGF, sm = 0.f, cnt = 0.f;
    int base = g * S_NODES;
    for (int o = 0; o < S_NODES; ++o) {
        if (nmask[base + o]) {
            float v = x[(size_t)(base + o) * HDF + c] * score[base + o];
            mx = fmaxf(mx, v);
            sm += v;
            cnt += 1.f;
        }
    }
    acc[(size_t)g * 512 + c] += mx;
    acc[(size_t)g * 512 + 256 + c] += sm / fmaxf(cnt, 1.f);
}

// ---------------------------------------------------------------- MLP head
__global__ __launch_bounds__(128) void mlp_kernel(
    const float* __restrict__ acc1, const float* __restrict__ acc2,
    const float* __restrict__ W1, const float* __restrict__ b1,
    const float* __restrict__ W2, const float* __restrict__ b2,
    const float* __restrict__ W3, const float* __restrict__ b3,
    float* __restrict__ out)
{
    int g = blockIdx.x, t = threadIdx.x;
    __shared__ float hrow[1024];
    __shared__ float h1s[128];
    __shared__ float h2s[64];
    __shared__ float o3[10];
    for (int j = t; j < 512; j += 128) {
        hrow[j] = acc1[(size_t)g * 512 + j];
        hrow[512 + j] = acc2[(size_t)g * 512 + j];
    }
    __syncthreads();
    float s = b1[t];
    for (int kx = 0; kx < 1024; ++kx) s += hrow[kx] * W1[(size_t)kx * 128 + t];
    h1s[t] = fmaxf(s, 0.f);
    __syncthreads();
    if (t < 64) {
        float s2 = b2[t];
        for (int kx = 0; kx < 128; ++kx) s2 += h1s[kx] * W2[kx * 64 + t];
        h2s[t] = fmaxf(s2, 0.f);
    }
    __syncthreads();
    if (t < 10) {
        float s3 = b3[t];
        for (int kx = 0; kx < 64; ++kx) s3 += h2s[kx] * W3[kx * 10 + t];
        o3[t] = s3;
    }
    __syncthreads();
    if (t < 10) {
        float m = o3[0];
        for (int j = 1; j < 10; ++j) m = fmaxf(m, o3[j]);
        float se = 0.f;
        for (int j = 0; j < 10; ++j) se += expf(o3[j] - m);
        out[g * 10 + t] = o3[t] - m - logf(se);
    }
}

// ---------------------------------------------------------------- launch
extern "C" void kernel_launch(void* const* d_in, const int* in_sizes, int n_in,
                              void* d_out, int out_size, void* d_ws, size_t ws_size,
                              hipStream_t stream) {
    (void)n_in; (void)out_size; (void)ws_size;
    const float* x0 = (const float*)d_in[0];
    const int* src = (const int*)d_in[1];
    const int* dst = src + N_EDGES;

    bool dictOrder = (in_sizes[7] == 64 * 768);
    const float *gatW[3], *gatAtt[3], *gatB[3], *gatRes[3];
    const float *gtWqkv[3], *gtBqkv[3], *gtWskip[3], *gtBskip[3];
    const float *gatPool, *gtPool;
    if (dictOrder) {
        for (int l = 0; l < 3; ++l) {
            int b = 3 + l * 8;
            gatW[l]    = (const float*)d_in[b + 0];
            gatAtt[l]  = (const float*)d_in[b + 1];
            gatB[l]    = (const float*)d_in[b + 2];
            gatRes[l]  = (const float*)d_in[b + 3];
            gtWqkv[l]  = (const float*)d_in[b + 4];
            gtBqkv[l]  = (const float*)d_in[b + 5];
            gtWskip[l] = (const float*)d_in[b + 6];
            gtBskip[l] = (const float*)d_in[b + 7];
        }
        gatPool = (const float*)d_in[27];
        gtPool  = (const float*)d_in[28];
    } else {
        for (int l = 0; l < 3; ++l) {
            int b = 3 + l * 4;
            gatW[l]   = (const float*)d_in[b + 0];
            gatAtt[l] = (const float*)d_in[b + 1];
            gatB[l]   = (const float*)d_in[b + 2];
            gatRes[l] = (const float*)d_in[b + 3];
            int c = 16 + l * 4;
            gtWqkv[l]  = (const float*)d_in[c + 0];
            gtBqkv[l]  = (const float*)d_in[c + 1];
            gtWskip[l] = (const float*)d_in[c + 2];
            gtBskip[l] = (const float*)d_in[c + 3];
        }
        gatPool = (const float*)d_in[15];
        gtPool  = (const float*)d_in[28];
    }
    const float* lin1W = (const float*)d_in[29];
    const float* lin1b = (const float*)d_in[30];
    const float* lin2W = (const float*)d_in[31];
    const float* lin2b = (const float*)d_in[32];
    const float* lin3W = (const float*)d_in[33];
    const float* lin3b = (const float*)d_in[34];

    char* wsp = (char*)d_ws;
    size_t off = 0;
    auto carve = [&](size_t bytes) -> void* {
        void* p = wsp + off;
        off += (bytes + 255) & ~(size_t)255;
        return p;
    };
    float* bufX   = (float*)carve((size_t)N_NODES * HDF * 4);   // 52.4 MB
    float* bufH   = (float*)carve((size_t)N_NODES * 768 * 4);   // 157.3 MB
    float* aS     = (float*)carve((size_t)N_NODES * 4 * 4);
    float* aD     = (float*)carve((size_t)N_NODES * 4 * 4);
    float* scoreB = (float*)carve((size_t)N_NODES * 4);
    int* nmask    = (int*)carve((size_t)N_NODES * 4);
    int* deg      = (int*)carve((size_t)N_NODES * 4);
    int* rowStart = (int*)carve((size_t)(N_NODES + 1) * 4);
    int* cursor   = (int*)carve((size_t)N_NODES * 4);
    int* csrSrc   = (int*)carve((size_t)N_EDGES * 4);
    float* acc1   = (float*)carve((size_t)N_GRAPHS * 512 * 4);
    float* acc2   = (float*)carve((size_t)N_GRAPHS * 512 * 4);
    // pre-split weights (hi/lo, fragment layout). 884736 elems total.
    const int wElems = 884736;
    unsigned short* whBase = (unsigned short*)carve((size_t)wElems * 2);
    unsigned short* wlBase = (unsigned short*)carve((size_t)wElems * 2);
    float* ysec   = bufH + (size_t)N_NODES * HDF;   // spare 2nd third of bufH (GAT agg)

    // per-matrix split offsets: order per layer [gatW, gatRes, gtWqkv, gtWskip]
    unsigned short *WH[12], *WL[12];
    {
        int o = 0;
        for (int l = 0; l < 3; ++l) {
            int fi = (l == 0) ? 64 : 256;
            int sz[4] = {fi * 256, fi * 256, fi * 768, fi * 256};
            const float* Wp[4] = {gatW[l], gatRes[l], gtWqkv[l], gtWskip[l]};
            int NCs[4] = {256, 256, 768, 256};
            for (int q = 0; q < 4; ++q) {
                int idx = l * 4 + q;
                WH[idx] = whBase + o;
                WL[idx] = wlBase + o;
                wsplit<<<(sz[q] + 255) / 256, 256, 0, stream>>>(
                    Wp[q], WH[idx], WL[idx], fi, NCs[q]);
                o += sz[q];
            }
        }
    }

    set_int<<<N_NODES / 256, 256, 0, stream>>>(deg, 0, N_NODES);
    set_int<<<N_NODES / 256, 256, 0, stream>>>(cursor, 0, N_NODES);
    set_int<<<(N_GRAPHS * 512) / 256, 256, 0, stream>>>((int*)acc1, 0, N_GRAPHS * 512);
    set_int<<<(N_GRAPHS * 512) / 256, 256, 0, stream>>>((int*)acc2, 0, N_GRAPHS * 512);

    count_deg<<<N_EDGES / 256, 256, 0, stream>>>(dst, deg);
    scan_deg<<<1, 1024, 0, stream>>>(deg, rowStart);
    scatter_edges<<<N_EDGES / 256, 256, 0, stream>>>(src, dst, cursor, rowStart, csrSrc);

    for (int br = 0; br < 2; ++br) {
        bool isGAT = (br == 0);
        float* acc = isGAT ? acc1 : acc2;
        const float* poolW = isGAT ? gatPool : gtPool;
        set_int<<<N_NODES / 256, 256, 0, stream>>>(nmask, 1, N_NODES);
        const float* xcur = x0;
        int fi = 64;
        for (int l = 0; l < 3; ++l) {
            const float* rs = (l == 0) ? nullptr : scoreB;
            const int* rsm = (l == 0) ? nullptr : nmask;
            if (isGAT) {
                mfma_gemm<<<dim3(1, N_NODES / 128), 512, 0, stream>>>(
                    xcur, WH[l * 4 + 0], WL[l * 4 + 0], nullptr, bufH, fi, 256,
                    nullptr, 0, nullptr, rs, rsm);
                gat_att<<<N_NODES, 256, 0, stream>>>(bufH, gatAtt[l], aS, aD);
                gat_edge<<<N_NODES, 256, 0, stream>>>(bufH, aS, aD, rowStart, csrSrc,
                                                      nmask, ysec);
                mfma_gemm<<<dim3(1, N_NODES / 128), 512, 0, stream>>>(
                    xcur, WH[l * 4 + 1], WL[l * 4 + 1], gatB[l], bufX, fi, 256,
                    ysec, HDF, nmask, rs, rsm);
            } else {
                mfma_gemm<<<dim3(3, N_NODES / 128), 512, 0, stream>>>(
                    xcur, WH[l * 4 + 2], WL[l * 4 + 2], gtBqkv[l], bufH, fi, 768,
                    nullptr, 0, nullptr, rs, rsm);
                gt_edge<<<N_NODES, 256, 0, stream>>>(bufH, rowStart, csrSrc, nmask);
                mfma_gemm<<<dim3(1, N_NODES / 128), 512, 0, stream>>>(
                    xcur, WH[l * 4 + 3], WL[l * 4 + 3], gtBskip[l], bufX, fi, 256,
                    bufH /*agg q-slots*/, 768, nmask, rs, rsm);
            }
            score_kernel<<<N_NODES / 4, 256, 0, stream>>>(bufX, poolW + l * HDF, scoreB);
            pool_kernel<<<N_GRAPHS, 128, 0, stream>>>(scoreB, nmask);
            readout_kernel<<<N_GRAPHS, 256, 0, stream>>>(bufX, scoreB, nmask, acc);
            xcur = bufX;
            fi = HDF;
        }
    }
    mlp_kernel<<<N_GRAPHS, 128, 0, stream>>>(acc1, acc2, lin1W, lin1b, lin2W, lin2b,
                                             lin3W, lin3b, (float*)d_out);
}

// Round 7
// 1659.395 us; speedup vs baseline: 2.0287x; 1.0544x over previous
//
#include <hip/hip_runtime.h>
#include <hip/hip_bf16.h>
#include <math.h>

#define N_NODES 51200
#define N_GRAPHS 512
#define S_NODES 100
#define N_EDGES 512000
#define HDF 256          // H*D
#define NEGF (-1e30f)
#define MAXD 256

typedef short bf16x8 __attribute__((ext_vector_type(8)));
typedef float f32x4 __attribute__((ext_vector_type(4)));

__device__ inline unsigned short f2b(float x) {   // fp32 -> bf16 RNE
    union { float f; unsigned u; } v; v.f = x;
    unsigned r = v.u + 0x7FFFu + ((v.u >> 16) & 1u);
    return (unsigned short)(r >> 16);
}
__device__ inline float b2f(unsigned short b) {
    union { float f; unsigned u; } v; v.u = ((unsigned)b) << 16; return v.f;
}

// ---------------------------------------------------------------- util
__global__ void set_int(int* __restrict__ p, int v, int n) {
    int i = blockIdx.x * 256 + threadIdx.x;
    if (i < n) p[i] = v;
}

// zero deg, cursor (N_NODES) and acc1, acc2 (N_GRAPHS*512) in one launch
__global__ void init_zero(int* __restrict__ deg, int* __restrict__ cursor,
                          float* __restrict__ acc1, float* __restrict__ acc2) {
    int i = blockIdx.x * 256 + threadIdx.x;   // grid covers 262144
    if (i < N_NODES) { deg[i] = 0; cursor[i] = 0; }
    acc1[i] = 0.f;
    acc2[i] = 0.f;
}

// pre-split weights: fp32 W[K x NC] -> bf16 hi/lo in MFMA fragment layout
// element (k,c) -> [(k>>3)*NC + c]*8 + (k&7).  One launch for all 12 matrices.
struct WSplitDesc { const float* W; unsigned short* Wh; unsigned short* Wl; int K, NC; };
struct WSplitPack { WSplitDesc d[12]; };
__global__ void wsplit_all(WSplitPack p) {
    WSplitDesc d = p.d[blockIdx.y];
    int idx = blockIdx.x * 256 + threadIdx.x;
    if (idx >= d.K * d.NC) return;
    int k = idx / d.NC, c = idx - k * d.NC;
    float v = d.W[idx];
    unsigned short h = f2b(v);
    int o = ((k >> 3) * d.NC + c) * 8 + (k & 7);
    d.Wh[o] = h;
    d.Wl[o] = f2b(v - b2f(h));
}

// ------------------------------------------------- split-bf16 MFMA GEMM
// C[rows x NC] = (rowScale.*A)[rows x K] @ B[K x NC] (+bias), 3-term bf16
// split (hi*hi + hi*lo + lo*hi), fp32 MFMA acc. Tile 128x256, 512 thr,
// 8 waves (2x4), 64x64/wave. grid = (NC/256, rows/128).
// B pre-split in fragment layout. rowScale: top-k fold on A rows.
// agg != null: fused epilogue out = relu(acc+agg+bias)*nmask, out stride 256.
__global__ __launch_bounds__(512) void mfma_gemm(
    const float* __restrict__ A,
    const unsigned short* __restrict__ Bh_g, const unsigned short* __restrict__ Bl_g,
    const float* __restrict__ bias, float* __restrict__ C,
    int K, int NC,
    const float* __restrict__ agg, int aggStride,
    const int* __restrict__ nmaskArr,
    const float* __restrict__ rowScale, const int* __restrict__ rsMask)
{
    __shared__ unsigned short Ah[4 * 128 * 8];   // [kg][row][j]
    __shared__ unsigned short Al[4 * 128 * 8];
    __shared__ unsigned short Bh[4 * 256 * 8];   // [kg][col][j]
    __shared__ unsigned short Bl[4 * 256 * 8];
    int row0 = blockIdx.y * 128, col0 = blockIdx.x * 256;
    int t = threadIdx.x;
    int lane = t & 63, w = t >> 6;
    int wr = w >> 2, wc = w & 3;          // 2 x 4 wave grid
    int l15 = lane & 15, l4 = lane >> 4;
    f32x4 acc[4][4];
    #pragma unroll
    for (int m = 0; m < 4; ++m)
        #pragma unroll
        for (int n = 0; n < 4; ++n) acc[m][n] = (f32x4){0.f, 0.f, 0.f, 0.f};

    int arow = t & 127, akg = t >> 7;     // A staging: 1 task (row, kgroup)
    int bcol = t & 255, bhalf = t >> 8;   // B staging: 2 tasks (col, kgroup)
    float ascale = 1.f;
    if (rowScale) ascale = rsMask[row0 + arow] ? rowScale[row0 + arow] : 0.f;

    for (int k0 = 0; k0 < K; k0 += 32) {
        // ---- stage A (fp32 -> hi/lo bf16), with folded top-k row scale
        const float* ap = A + (size_t)(row0 + arow) * K + k0 + akg * 8;
        float4 a0 = *(const float4*)ap;
        float4 a1 = *(const float4*)(ap + 4);
        float av[8] = {a0.x, a0.y, a0.z, a0.w, a1.x, a1.y, a1.z, a1.w};
        int abase = (akg * 128 + arow) * 8;
        #pragma unroll
        for (int j = 0; j < 8; ++j) {
            float s = av[j] * ascale;
            unsigned short h = f2b(s);
            Ah[abase + j] = h;
            Al[abase + j] = f2b(s - b2f(h));
        }
        // ---- stage B (pre-split, fragment layout: straight 16B copies)
        #pragma unroll
        for (int q = 0; q < 2; ++q) {
            int kg = bhalf * 2 + q;
            size_t gb = ((size_t)((k0 >> 3) + kg) * NC + col0 + bcol) * 8;
            int bbase = (kg * 256 + bcol) * 8;
            *(bf16x8*)&Bh[bbase] = *(const bf16x8*)&Bh_g[gb];
            *(bf16x8*)&Bl[bbase] = *(const bf16x8*)&Bl_g[gb];
        }
        __syncthreads();
        // ---- fragments + MFMA
        bf16x8 bh[4], bl[4];
        #pragma unroll
        for (int n = 0; n < 4; ++n) {
            int idx = (l4 * 256 + wc * 64 + n * 16 + l15) * 8;
            bh[n] = *(bf16x8*)&Bh[idx];
            bl[n] = *(bf16x8*)&Bl[idx];
        }
        #pragma unroll
        for (int m = 0; m < 4; ++m) {
            int idx = (l4 * 128 + wr * 64 + m * 16 + l15) * 8;
            bf16x8 ah = *(bf16x8*)&Ah[idx];
            bf16x8 al = *(bf16x8*)&Al[idx];
            #pragma unroll
            for (int n = 0; n < 4; ++n) {
                acc[m][n] = __builtin_amdgcn_mfma_f32_16x16x32_bf16(ah, bh[n], acc[m][n], 0, 0, 0);
                acc[m][n] = __builtin_amdgcn_mfma_f32_16x16x32_bf16(ah, bl[n], acc[m][n], 0, 0, 0);
                acc[m][n] = __builtin_amdgcn_mfma_f32_16x16x32_bf16(al, bh[n], acc[m][n], 0, 0, 0);
            }
        }
        __syncthreads();
    }
    // ---- epilogue: D row = wr*64+m*16+l4*4+r, col = wc*64+n*16+l15
    bool fused = (agg != nullptr);
    #pragma unroll
    for (int m = 0; m < 4; ++m) {
        #pragma unroll
        for (int n = 0; n < 4; ++n) {
            int col = col0 + wc * 64 + n * 16 + l15;
            float bv = bias ? bias[col] : 0.f;
            #pragma unroll
            for (int r = 0; r < 4; ++r) {
                int row = row0 + wr * 64 + m * 16 + l4 * 4 + r;
                float v = acc[m][n][r] + bv;
                if (fused) {
                    v += agg[(size_t)row * aggStride + col];
                    float nm = nmaskArr[row] ? 1.f : 0.f;
                    C[(size_t)row * 256 + col] = fmaxf(v, 0.f) * nm;
                } else {
                    C[(size_t)row * NC + col] = v;
                }
            }
        }
    }
}

// ---------------------------------------------------------------- CSR build
__global__ void count_deg(const int* __restrict__ dst, int* __restrict__ deg) {
    int e = blockIdx.x * 256 + threadIdx.x;
    atomicAdd(&deg[dst[e]], 1);
}

__global__ __launch_bounds__(1024) void scan_deg(const int* __restrict__ deg,
                                                 int* __restrict__ rowStart) {
    __shared__ int part[1024];
    int t = threadIdx.x;
    const int chunk = N_NODES / 1024;      // 50
    int s = t * chunk;
    int sum = 0;
    for (int i = 0; i < chunk; ++i) sum += deg[s + i];
    part[t] = sum;
    __syncthreads();
    for (int d = 1; d < 1024; d <<= 1) {
        int v = (t >= d) ? part[t - d] : 0;
        __syncthreads();
        part[t] += v;
        __syncthreads();
    }
    int excl = (t == 0) ? 0 : part[t - 1];
    for (int i = 0; i < chunk; ++i) { rowStart[s + i] = excl; excl += deg[s + i]; }
    if (t == 1023) rowStart[N_NODES] = part[1023];
}

// store SRC ids directly in CSR order
__global__ void scatter_edges(const int* __restrict__ src, const int* __restrict__ dst,
                              int* __restrict__ cursor, const int* __restrict__ rowStart,
                              int* __restrict__ csrSrc) {
    int e = blockIdx.x * 256 + threadIdx.x;
    int d = dst[e];
    int p = atomicAdd(&cursor[d], 1);
    csrSrc[rowStart[d] + p] = src[e];
}

// ---------------------------------------------------------------- GAT pieces
__global__ __launch_bounds__(256) void gat_att(const float* __restrict__ hfeat,
                                               const float* __restrict__ att,
                                               float* __restrict__ aS, float* __restrict__ aD) {
    int i = blockIdx.x, t = threadIdx.x, hh = t >> 6, d = t & 63;
    float hv = hfeat[(size_t)i * HDF + t];
    float p0 = hv * att[hh * 64 + d];
    float p1 = hv * att[256 + hh * 64 + d];
    #pragma unroll
    for (int o = 32; o > 0; o >>= 1) { p0 += __shfl_down(p0, o, 64); p1 += __shfl_down(p1, o, 64); }
    if (d == 0) { aS[i * 4 + hh] = p0; aD[i * 4 + hh] = p1; }
}

// per-dst attention aggregation -> aggOut (stride 256).
// edge mask == nmask[src]; wave-parallel softmax; transposed sL; 2x-unrolled gather.
__global__ __launch_bounds__(256) void gat_edge(
    const float* __restrict__ hfeat, const float* __restrict__ aS, const float* __restrict__ aD,
    const int* __restrict__ rowStart, const int* __restrict__ csrSrc,
    const int* __restrict__ nmask,
    float* __restrict__ aggOut)
{
    int bid = blockIdx.x;
    int i = (bid & 7) * (N_NODES / 8) + (bid >> 3);   // XCD-swizzle
    int t = threadIdx.x;
    int w = t >> 6, l = t & 63;
    __shared__ int sSrc[MAXD + 1];
    __shared__ float sL[4][MAXD + 4];
    __shared__ float sAcc[3][256];
    if (!nmask[i]) {
        aggOut[i * HDF + t] = 0.f;
        return;
    }
    int rs = rowStart[i], re = rowStart[i + 1];
    int deg = min(re - rs, MAXD);
    float4 ad4 = *(const float4*)&aD[i * 4];
    for (int j = t; j < deg; j += 256) {
        int s_ = csrSrc[rs + j];
        int ok = nmask[s_];
        sSrc[j] = ok ? s_ : -1;
        float4 as4 = *(const float4*)&aS[s_ * 4];
        float lg0 = as4.x + ad4.x, lg1 = as4.y + ad4.y;
        float lg2 = as4.z + ad4.z, lg3 = as4.w + ad4.w;
        lg0 = (lg0 >= 0.f) ? lg0 : 0.2f * lg0;
        lg1 = (lg1 >= 0.f) ? lg1 : 0.2f * lg1;
        lg2 = (lg2 >= 0.f) ? lg2 : 0.2f * lg2;
        lg3 = (lg3 >= 0.f) ? lg3 : 0.2f * lg3;
        sL[0][j] = ok ? lg0 : NEGF;
        sL[1][j] = ok ? lg1 : NEGF;
        sL[2][j] = ok ? lg2 : NEGF;
        sL[3][j] = ok ? lg3 : NEGF;
    }
    if (t == 0) {   // self loop (node alive here)
        sSrc[deg] = i;
        float4 as4 = *(const float4*)&aS[i * 4];
        float lg0 = as4.x + ad4.x, lg1 = as4.y + ad4.y;
        float lg2 = as4.z + ad4.z, lg3 = as4.w + ad4.w;
        sL[0][deg] = (lg0 >= 0.f) ? lg0 : 0.2f * lg0;
        sL[1][deg] = (lg1 >= 0.f) ? lg1 : 0.2f * lg1;
        sL[2][deg] = (lg2 >= 0.f) ? lg2 : 0.2f * lg2;
        sL[3][deg] = (lg3 >= 0.f) ? lg3 : 0.2f * lg3;
    }
    __syncthreads();
    int tot = deg + 1;
    // wave-parallel softmax: wave w = head w, lane l = edge l (+64-folds)
    {
        float m = NEGF;
        for (int j = l; j < tot; j += 64) if (sSrc[j] >= 0) m = fmaxf(m, sL[w][j]);
        #pragma unroll
        for (int o = 32; o > 0; o >>= 1) m = fmaxf(m, __shfl_xor(m, o, 64));
        float part = 0.f;
        for (int j = l; j < tot; j += 64) {
            float e = (sSrc[j] >= 0) ? __expf(sL[w][j] - m) : 0.f;
            sL[w][j] = e;
            part += e;
        }
        #pragma unroll
        for (int o = 32; o > 0; o >>= 1) part += __shfl_xor(part, o, 64);
        float inv = 1.f / fmaxf(part, 1e-16f);
        for (int j = l; j < tot; j += 64) sL[w][j] *= inv;
    }
    __syncthreads();
    int hh4 = l >> 4;                     // head owning dims 4l..4l+3
    float4 a4 = make_float4(0.f, 0.f, 0.f, 0.f);
    int j = w;
    for (; j + 4 < tot; j += 8) {         // 2x unroll: independent gathers
        int s0 = sSrc[j], s1 = sSrc[j + 4];
        float a0 = 0.f, a1 = 0.f;
        float4 v0 = make_float4(0.f, 0.f, 0.f, 0.f), v1 = v0;
        if (s0 >= 0) { a0 = sL[hh4][j];     v0 = *(const float4*)&hfeat[s0 * HDF + l * 4]; }
        if (s1 >= 0) { a1 = sL[hh4][j + 4]; v1 = *(const float4*)&hfeat[s1 * HDF + l * 4]; }
        a4.x += a0 * v0.x; a4.y += a0 * v0.y; a4.z += a0 * v0.z; a4.w += a0 * v0.w;
        a4.x += a1 * v1.x; a4.y += a1 * v1.y; a4.z += a1 * v1.z; a4.w += a1 * v1.w;
    }
    for (; j < tot; j += 4) {
        int s_ = sSrc[j];
        if (s_ < 0) continue;
        float a = sL[hh4][j];
        float4 v4 = *(const float4*)&hfeat[s_ * HDF + l * 4];
        a4.x += a * v4.x; a4.y += a * v4.y; a4.z += a * v4.z; a4.w += a * v4.w;
    }
    if (w > 0) *(float4*)&sAcc[w - 1][l * 4] = a4;
    __syncthreads();
    if (w == 0) {
        float4 p0 = *(const float4*)&sAcc[0][l * 4];
        float4 p1 = *(const float4*)&sAcc[1][l * 4];
        float4 p2 = *(const float4*)&sAcc[2][l * 4];
        a4.x += p0.x + p1.x + p2.x;
        a4.y += p0.y + p1.y + p2.y;
        a4.z += p0.z + p1.z + p2.z;
        a4.w += p0.w + p1.w + p2.w;
        *(float4*)(aggOut + i * HDF + l * 4) = a4;
    }
}

// ---------------------------------------------------------------- GT piece
// qkv row: [q(256) | k(256) | v(256)]. Writes agg over OWN q-slot (race-free).
// edge mask == nmask[src]; 2x-unrolled logits + gather (pipelined shfl chains).
__global__ __launch_bounds__(256) void gt_edge(
    float* __restrict__ qkv,
    const int* __restrict__ rowStart, const int* __restrict__ csrSrc,
    const int* __restrict__ nmask)
{
    int bid = blockIdx.x;
    int i = (bid & 7) * (N_NODES / 8) + (bid >> 3);   // XCD-swizzle
    int t = threadIdx.x;
    int w = t >> 6, l = t & 63;
    __shared__ float sQ[256];
    __shared__ int sSrc[MAXD];
    __shared__ float sL[4][MAXD + 4];
    __shared__ float sAcc[3][256];
    if (!nmask[i]) {
        qkv[i * 768 + t] = 0.f;
        return;
    }
    int rs = rowStart[i], re = rowStart[i + 1];
    int deg = min(re - rs, MAXD);
    sQ[t] = qkv[i * 768 + t];
    for (int j = t; j < deg; j += 256) {      // preload src ids (+nmask fold)
        int s_ = csrSrc[rs + j];
        sSrc[j] = nmask[s_] ? s_ : -1;
    }
    __syncthreads();
    // phase A: wave w handles edges j = w mod 4; 2x unroll pipelines the
    // dependent shfl chains and overlaps the two K-row gathers.
    float4 q4 = *(const float4*)&sQ[l * 4];
    int hh = l >> 4;
    {
        int j = w;
        for (; j + 4 < deg; j += 8) {
            int s0 = sSrc[j], s1 = sSrc[j + 4];
            float p0 = 0.f, p1 = 0.f;
            if (s0 >= 0) {
                float4 k4 = *(const float4*)&qkv[s0 * 768 + 256 + l * 4];
                p0 = q4.x * k4.x + q4.y * k4.y + q4.z * k4.z + q4.w * k4.w;
            }
            if (s1 >= 0) {
                float4 k4 = *(const float4*)&qkv[s1 * 768 + 256 + l * 4];
                p1 = q4.x * k4.x + q4.y * k4.y + q4.z * k4.z + q4.w * k4.w;
            }
            p0 += __shfl_xor(p0, 1, 64);  p1 += __shfl_xor(p1, 1, 64);
            p0 += __shfl_xor(p0, 2, 64);  p1 += __shfl_xor(p1, 2, 64);
            p0 += __shfl_xor(p0, 4, 64);  p1 += __shfl_xor(p1, 4, 64);
            p0 += __shfl_xor(p0, 8, 64);  p1 += __shfl_xor(p1, 8, 64);
            if ((l & 15) == 0) {
                sL[hh][j]     = (s0 >= 0) ? p0 * 0.125f : NEGF;
                sL[hh][j + 4] = (s1 >= 0) ? p1 * 0.125f : NEGF;
            }
        }
        for (; j < deg; j += 4) {
            int s_ = sSrc[j];
            float p = 0.f;
            if (s_ >= 0) {
                float4 k4 = *(const float4*)&qkv[s_ * 768 + 256 + l * 4];
                p = q4.x * k4.x + q4.y * k4.y + q4.z * k4.z + q4.w * k4.w;
            }
            p += __shfl_xor(p, 1, 64);
            p += __shfl_xor(p, 2, 64);
            p += __shfl_xor(p, 4, 64);
            p += __shfl_xor(p, 8, 64);
            if ((l & 15) == 0) sL[hh][j] = (s_ >= 0) ? p * 0.125f : NEGF;
        }
    }
    __syncthreads();
    // phase B: wave-parallel softmax (wave w = head w, lane l = edge l)
    {
        float m = NEGF;
        for (int j = l; j < deg; j += 64) if (sSrc[j] >= 0) m = fmaxf(m, sL[w][j]);
        #pragma unroll
        for (int o = 32; o > 0; o >>= 1) m = fmaxf(m, __shfl_xor(m, o, 64));
        float part = 0.f;
        for (int j = l; j < deg; j += 64) {
            float e = (sSrc[j] >= 0) ? __expf(sL[w][j] - m) : 0.f;
            sL[w][j] = e;
            part += e;
        }
        #pragma unroll
        for (int o = 32; o > 0; o >>= 1) part += __shfl_xor(part, o, 64);
        float inv = 1.f / fmaxf(part, 1e-16f);
        for (int j = l; j < deg; j += 64) sL[w][j] *= inv;
    }
    __syncthreads();
    // phase C: 2x-unrolled weighted V gather
    int hh4 = l >> 4;
    float4 a4 = make_float4(0.f, 0.f, 0.f, 0.f);
    int j = w;
    for (; j + 4 < deg; j += 8) {
        int s0 = sSrc[j], s1 = sSrc[j + 4];
        float a0 = 0.f, a1 = 0.f;
        float4 v0 = make_float4(0.f, 0.f, 0.f, 0.f), v1 = v0;
        if (s0 >= 0) { a0 = sL[hh4][j];     v0 = *(const float4*)&qkv[s0 * 768 + 512 + l * 4]; }
        if (s1 >= 0) { a1 = sL[hh4][j + 4]; v1 = *(const float4*)&qkv[s1 * 768 + 512 + l * 4]; }
        a4.x += a0 * v0.x; a4.y += a0 * v0.y; a4.z += a0 * v0.z; a4.w += a0 * v0.w;
        a4.x += a1 * v1.x; a4.y += a1 * v1.y; a4.z += a1 * v1.z; a4.w += a1 * v1.w;
    }
    for (; j < deg; j += 4) {
        int s_ = sSrc[j];
        if (s_ < 0) continue;
        float a = sL[hh4][j];
        float4 v4 = *(const float4*)&qkv[s_ * 768 + 512 + l * 4];
        a4.x += a * v4.x; a4.y += a * v4.y; a4.z += a * v4.z; a4.w += a * v4.w;
    }
    if (w > 0) *(float4*)&sAcc[w - 1][l * 4] = a4;
    __syncthreads();
    if (w == 0) {
        float4 p0 = *(const float4*)&sAcc[0][l * 4];
        float4 p1 = *(const float4*)&sAcc[1][l * 4];
        float4 p2 = *(const float4*)&sAcc[2][l * 4];
        a4.x += p0.x + p1.x + p2.x;
        a4.y += p0.y + p1.y + p2.y;
        a4.z += p0.z + p1.z + p2.z;
        a4.w += p0.w + p1.w + p2.w;
        *(float4*)(qkv + i * 768 + l * 4) = a4;
    }
}

// ---------------------------------------------------- fused score+pool+readout
// One block per graph. Replicates the exact reduction orders of the previous
// score_kernel / pool_kernel / readout_kernel (bit-identical results).
__global__ __launch_bounds__(256) void spr_kernel(
    const float* __restrict__ x, const float* __restrict__ w,
    float* __restrict__ score, int* __restrict__ nmask, float* __restrict__ acc)
{
    int g = blockIdx.x, t = threadIdx.x;
    int wv = t >> 6, l = t & 63;
    __shared__ float sW[256];
    __shared__ float sRaw[104];     // raw dot x.w per node
    __shared__ float sFin[104];     // final score
    __shared__ int   sKeep[104];
    __shared__ float swn;
    __shared__ int cnt_s;
    if (t == 0) cnt_s = 0;
    sW[t] = w[t];
    __syncthreads();
    // ||w||: same per-lane order as score_kernel (c-strided + shfl_down)
    if (wv == 0) {
        float dw = 0.f;
        #pragma unroll
        for (int c = 0; c < 4; ++c) { float v = sW[l + c * 64]; dw += v * v; }
        #pragma unroll
        for (int o = 32; o > 0; o >>= 1) dw += __shfl_down(dw, o, 64);
        if (l == 0) swn = sqrtf(dw);
    }
    // scores: wave wv owns nodes wv*25 .. wv*25+24 (same dot order as before)
    int base = g * S_NODES;
    for (int u = 0; u < 25; ++u) {
        int nl = wv * 25 + u;
        float dx = 0.f;
        #pragma unroll
        for (int c = 0; c < 4; ++c) {
            int cc = l + c * 64;
            dx += x[(size_t)(base + nl) * HDF + cc] * sW[cc];
        }
        #pragma unroll
        for (int o = 32; o > 0; o >>= 1) dx += __shfl_down(dx, o, 64);
        if (l == 0) sRaw[nl] = dx;
    }
    __syncthreads();
    // finalize scores + alive count (pool semantics identical to pool_kernel)
    int alive = 0;
    float ck = -2.0f;
    if (t < S_NODES) {
        float sc = tanhf(sRaw[t] / swn);
        sFin[t] = sc;
        score[base + t] = sc;
        alive = nmask[base + t];
        ck = alive ? sc : -1.5f;
        sRaw[t] = ck;               // reuse as sort key
        if (alive) atomicAdd(&cnt_s, 1);
    }
    __syncthreads();
    int k = (int)ceilf(0.8f * (float)cnt_s);
    if (t < S_NODES) {
        int rank = 0;
        for (int jj = 0; jj < S_NODES; ++jj) {
            float o = sRaw[jj];
            rank += (o > ck || (o == ck && jj < t)) ? 1 : 0;  // stable desc
        }
        int kp = (alive && rank < k) ? 1 : 0;
        sKeep[t] = kp;
        nmask[base + t] = kp;
    }
    __syncthreads();
    // readout (same o-ascending order; 4x prefetch of independent loads)
    float mx = NEGF, sm = 0.f, cnt = 0.f;
    for (int o = 0; o < S_NODES; o += 4) {
        float v0 = x[(size_t)(base + o + 0) * HDF + t];
        float v1 = x[(size_t)(base + o + 1) * HDF + t];
        float v2 = x[(size_t)(base + o + 2) * HDF + t];
        float v3 = x[(size_t)(base + o + 3) * HDF + t];
        if (sKeep[o + 0]) { float v = v0 * sFin[o + 0]; mx = fmaxf(mx, v); sm += v; cnt += 1.f; }
        if (sKeep[o + 1]) { float v = v1 * sFin[o + 1]; mx = fmaxf(mx, v); sm += v; cnt += 1.f; }
        if (sKeep[o + 2]) { float v = v2 * sFin[o + 2]; mx = fmaxf(mx, v); sm += v; cnt += 1.f; }
        if (sKeep[o + 3]) { float v = v3 * sFin[o + 3]; mx = fmaxf(mx, v); sm += v; cnt += 1.f; }
    }
    acc[(size_t)g * 512 + t] += mx;
    acc[(size_t)g * 512 + 256 + t] += sm / fmaxf(cnt, 1.f);
}

// ---------------------------------------------------------------- MLP head
__global__ __launch_bounds__(128) void mlp_kernel(
    const float* __restrict__ acc1, const float* __restrict__ acc2,
    const float* __restrict__ W1, const float* __restrict__ b1,
    const float* __restrict__ W2, const float* __restrict__ b2,
    const float* __restrict__ W3, const float* __restrict__ b3,
    float* __restrict__ out)
{
    int g = blockIdx.x, t = threadIdx.x;
    __shared__ float hrow[1024];
    __shared__ float h1s[128];
    __shared__ float h2s[64];
    __shared__ float o3[10];
    for (int j = t; j < 512; j += 128) {
        hrow[j] = acc1[(size_t)g * 512 + j];
        hrow[512 + j] = acc2[(size_t)g * 512 + j];
    }
    __syncthreads();
    float s = b1[t];
    for (int kx = 0; kx < 1024; ++kx) s += hrow[kx] * W1[(size_t)kx * 128 + t];
    h1s[t] = fmaxf(s, 0.f);
    __syncthreads();
    if (t < 64) {
        float s2 = b2[t];
        for (int kx = 0; kx < 128; ++kx) s2 += h1s[kx] * W2[kx * 64 + t];
        h2s[t] = fmaxf(s2, 0.f);
    }
    __syncthreads();
    if (t < 10) {
        float s3 = b3[t];
        for (int kx = 0; kx < 64; ++kx) s3 += h2s[kx] * W3[kx * 10 + t];
        o3[t] = s3;
    }
    __syncthreads();
    if (t < 10) {
        float m = o3[0];
        for (int j = 1; j < 10; ++j) m = fmaxf(m, o3[j]);
        float se = 0.f;
        for (int j = 0; j < 10; ++j) se += expf(o3[j] - m);
        out[g * 10 + t] = o3[t] - m - logf(se);
    }
}

// ---------------------------------------------------------------- launch
extern "C" void kernel_launch(void* const* d_in, const int* in_sizes, int n_in,
                              void* d_out, int out_size, void* d_ws, size_t ws_size,
                              hipStream_t stream) {
    (void)n_in; (void)out_size; (void)ws_size;
    const float* x0 = (const float*)d_in[0];
    const int* src = (const int*)d_in[1];
    const int* dst = src + N_EDGES;

    bool dictOrder = (in_sizes[7] == 64 * 768);
    const float *gatW[3], *gatAtt[3], *gatB[3], *gatRes[3];
    const float *gtWqkv[3], *gtBqkv[3], *gtWskip[3], *gtBskip[3];
    const float *gatPool, *gtPool;
    if (dictOrder) {
        for (int l = 0; l < 3; ++l) {
            int b = 3 + l * 8;
            gatW[l]    = (const float*)d_in[b + 0];
            gatAtt[l]  = (const float*)d_in[b + 1];
            gatB[l]    = (const float*)d_in[b + 2];
            gatRes[l]  = (const float*)d_in[b + 3];
            gtWqkv[l]  = (const float*)d_in[b + 4];
            gtBqkv[l]  = (const float*)d_in[b + 5];
            gtWskip[l] = (const float*)d_in[b + 6];
            gtBskip[l] = (const float*)d_in[b + 7];
        }
        gatPool = (const float*)d_in[27];
        gtPool  = (const float*)d_in[28];
    } else {
        for (int l = 0; l < 3; ++l) {
            int b = 3 + l * 4;
            gatW[l]   = (const float*)d_in[b + 0];
            gatAtt[l] = (const float*)d_in[b + 1];
            gatB[l]   = (const float*)d_in[b + 2];
            gatRes[l] = (const float*)d_in[b + 3];
            int c = 16 + l * 4;
            gtWqkv[l]  = (const float*)d_in[c + 0];
            gtBqkv[l]  = (const float*)d_in[c + 1];
            gtWskip[l] = (const float*)d_in[c + 2];
            gtBskip[l] = (const float*)d_in[c + 3];
        }
        gatPool = (const float*)d_in[15];
        gtPool  = (const float*)d_in[28];
    }
    const float* lin1W = (const float*)d_in[29];
    const float* lin1b = (const float*)d_in[30];
    const float* lin2W = (const float*)d_in[31];
    const float* lin2b = (const float*)d_in[32];
    const float* lin3W = (const float*)d_in[33];
    const float* lin3b = (const float*)d_in[34];

    char* wsp = (char*)d_ws;
    size_t off = 0;
    auto carve = [&](size_t bytes) -> void* {
        void* p = wsp + off;
        off += (bytes + 255) & ~(size_t)255;
        return p;
    };
    float* bufX   = (float*)carve((size_t)N_NODES * HDF * 4);   // 52.4 MB
    float* bufH   = (float*)carve((size_t)N_NODES * 768 * 4);   // 157.3 MB
    float* aS     = (float*)carve((size_t)N_NODES * 4 * 4);
    float* aD     = (float*)carve((size_t)N_NODES * 4 * 4);
    float* scoreB = (float*)carve((size_t)N_NODES * 4);
    int* nmask    = (int*)carve((size_t)N_NODES * 4);
    int* deg      = (int*)carve((size_t)N_NODES * 4);
    int* rowStart = (int*)carve((size_t)(N_NODES + 1) * 4);
    int* cursor   = (int*)carve((size_t)N_NODES * 4);
    int* csrSrc   = (int*)carve((size_t)N_EDGES * 4);
    float* acc1   = (float*)carve((size_t)N_GRAPHS * 512 * 4);
    float* acc2   = (float*)carve((size_t)N_GRAPHS * 512 * 4);
    const int wElems = 884736;
    unsigned short* whBase = (unsigned short*)carve((size_t)wElems * 2);
    unsigned short* wlBase = (unsigned short*)carve((size_t)wElems * 2);
    float* ysec   = bufH + (size_t)N_NODES * HDF;   // spare 2nd third of bufH (GAT agg)

    // single packed weight-split launch
    unsigned short *WH[12], *WL[12];
    {
        WSplitPack pack;
        int o = 0, maxSz = 0;
        for (int l = 0; l < 3; ++l) {
            int fi = (l == 0) ? 64 : 256;
            int sz[4] = {fi * 256, fi * 256, fi * 768, fi * 256};
            const float* Wp[4] = {gatW[l], gatRes[l], gtWqkv[l], gtWskip[l]};
            int NCs[4] = {256, 256, 768, 256};
            for (int q = 0; q < 4; ++q) {
                int idx = l * 4 + q;
                WH[idx] = whBase + o;
                WL[idx] = wlBase + o;
                pack.d[idx] = {Wp[q], WH[idx], WL[idx], fi, NCs[q]};
                if (sz[q] > maxSz) maxSz = sz[q];
                o += sz[q];
            }
        }
        wsplit_all<<<dim3((maxSz + 255) / 256, 12), 256, 0, stream>>>(pack);
    }

    init_zero<<<(N_GRAPHS * 512) / 256, 256, 0, stream>>>(deg, cursor, acc1, acc2);
    count_deg<<<N_EDGES / 256, 256, 0, stream>>>(dst, deg);
    scan_deg<<<1, 1024, 0, stream>>>(deg, rowStart);
    scatter_edges<<<N_EDGES / 256, 256, 0, stream>>>(src, dst, cursor, rowStart, csrSrc);

    for (int br = 0; br < 2; ++br) {
        bool isGAT = (br == 0);
        float* acc = isGAT ? acc1 : acc2;
        const float* poolW = isGAT ? gatPool : gtPool;
        set_int<<<N_NODES / 256, 256, 0, stream>>>(nmask, 1, N_NODES);
        const float* xcur = x0;
        int fi = 64;
        for (int l = 0; l < 3; ++l) {
            const float* rs = (l == 0) ? nullptr : scoreB;
            const int* rsm = (l == 0) ? nullptr : nmask;
            if (isGAT) {
                mfma_gemm<<<dim3(1, N_NODES / 128), 512, 0, stream>>>(
                    xcur, WH[l * 4 + 0], WL[l * 4 + 0], nullptr, bufH, fi, 256,
                    nullptr, 0, nullptr, rs, rsm);
                gat_att<<<N_NODES, 256, 0, stream>>>(bufH, gatAtt[l], aS, aD);
                gat_edge<<<N_NODES, 256, 0, stream>>>(bufH, aS, aD, rowStart, csrSrc,
                                                      nmask, ysec);
                mfma_gemm<<<dim3(1, N_NODES / 128), 512, 0, stream>>>(
                    xcur, WH[l * 4 + 1], WL[l * 4 + 1], gatB[l], bufX, fi, 256,
                    ysec, HDF, nmask, rs, rsm);
            } else {
                mfma_gemm<<<dim3(3, N_NODES / 128), 512, 0, stream>>>(
                    xcur, WH[l * 4 + 2], WL[l * 4 + 2], gtBqkv[l], bufH, fi, 768,
                    nullptr, 0, nullptr, rs, rsm);
                gt_edge<<<N_NODES, 256, 0, stream>>>(bufH, rowStart, csrSrc, nmask);
                mfma_gemm<<<dim3(1, N_NODES / 128), 512, 0, stream>>>(
                    xcur, WH[l * 4 + 3], WL[l * 4 + 3], gtBskip[l], bufX, fi, 256,
                    bufH /*agg q-slots*/, 768, nmask, rs, rsm);
            }
            spr_kernel<<<N_GRAPHS, 256, 0, stream>>>(bufX, poolW + l * HDF,
                                                     scoreB, nmask, acc);
            xcur = bufX;
            fi = HDF;
        }
    }
    mlp_kernel<<<N_GRAPHS, 128, 0, stream>>>(acc1, acc2, lin1W, lin1b, lin2W, lin2b,
                                             lin3W, lin3b, (float*)d_out);
}

// Round 8
// 1502.157 us; speedup vs baseline: 2.2410x; 1.1047x over previous
//
#include <hip/hip_runtime.h>
#include <hip/hip_bf16.h>
#include <math.h>

#define N_NODES 51200
#define N_GRAPHS 512
#define S_NODES 100
#define N_EDGES 512000
#define HDF 256          // H*D
#define NEGF (-1e30f)
#define DCAP 128         // per-node degree cap (P[Poisson(10)>128] ~ 0)

typedef short bf16x8 __attribute__((ext_vector_type(8)));
typedef float f32x4 __attribute__((ext_vector_type(4)));

__device__ inline unsigned short f2b(float x) {   // fp32 -> bf16 RNE
    union { float f; unsigned u; } v; v.f = x;
    unsigned r = v.u + 0x7FFFu + ((v.u >> 16) & 1u);
    return (unsigned short)(r >> 16);
}
__device__ inline float b2f(unsigned short b) {
    union { float f; unsigned u; } v; v.u = ((unsigned)b) << 16; return v.f;
}

// ---------------------------------------------------------------- util
__global__ void set_int(int* __restrict__ p, int v, int n) {
    int i = blockIdx.x * 256 + threadIdx.x;
    if (i < n) p[i] = v;
}

__global__ void init_zero(int* __restrict__ deg, int* __restrict__ cursor,
                          float* __restrict__ acc1, float* __restrict__ acc2) {
    int i = blockIdx.x * 256 + threadIdx.x;   // grid covers 262144
    if (i < N_NODES) { deg[i] = 0; cursor[i] = 0; }
    acc1[i] = 0.f;
    acc2[i] = 0.f;
}

// pre-split weights: fp32 W[K x NC] -> bf16 hi/lo in MFMA fragment layout
// element (k,c) -> [(k>>3)*NC + c]*8 + (k&7)
struct WSplitDesc { const float* W; unsigned short* Wh; unsigned short* Wl; int K, NC; };
struct WSplitPack { WSplitDesc d[12]; };
__global__ void wsplit_all(WSplitPack p) {
    WSplitDesc d = p.d[blockIdx.y];
    int idx = blockIdx.x * 256 + threadIdx.x;
    if (idx >= d.K * d.NC) return;
    int k = idx / d.NC, c = idx - k * d.NC;
    float v = d.W[idx];
    unsigned short h = f2b(v);
    int o = ((k >> 3) * d.NC + c) * 8 + (k & 7);
    d.Wh[o] = h;
    d.Wl[o] = f2b(v - b2f(h));
}

// ------------------------------------------------- split-bf16 MFMA GEMM
// B fragments are read DIRECTLY from the pre-split global fragment layout
// (contiguous 16B per lane) -> no B LDS, 16 KB LDS/block, ~10 blocks/CU.
__global__ __launch_bounds__(512) void mfma_gemm(
    const float* __restrict__ A,
    const unsigned short* __restrict__ Bh_g, const unsigned short* __restrict__ Bl_g,
    const float* __restrict__ bias, float* __restrict__ C,
    int K, int NC,
    const float* __restrict__ agg, int aggStride,
    const int* __restrict__ nmaskArr,
    const float* __restrict__ rowScale, const int* __restrict__ rsMask)
{
    __shared__ unsigned short Ah[4 * 128 * 8];   // [kg][row][j]
    __shared__ unsigned short Al[4 * 128 * 8];
    int row0 = blockIdx.y * 128, col0 = blockIdx.x * 256;
    int t = threadIdx.x;
    int lane = t & 63, w = t >> 6;
    int wr = w >> 2, wc = w & 3;          // 2 x 4 wave grid
    int l15 = lane & 15, l4 = lane >> 4;
    f32x4 acc[4][4];
    #pragma unroll
    for (int m = 0; m < 4; ++m)
        #pragma unroll
        for (int n = 0; n < 4; ++n) acc[m][n] = (f32x4){0.f, 0.f, 0.f, 0.f};

    int arow = t & 127, akg = t >> 7;     // A staging task (row, kgroup)
    float ascale = 1.f;
    if (rowScale) ascale = rsMask[row0 + arow] ? rowScale[row0 + arow] : 0.f;

    for (int k0 = 0; k0 < K; k0 += 32) {
        // ---- stage A (fp32 -> hi/lo bf16), folded top-k row scale
        const float* ap = A + (size_t)(row0 + arow) * K + k0 + akg * 8;
        float4 a0 = *(const float4*)ap;
        float4 a1 = *(const float4*)(ap + 4);
        float av[8] = {a0.x, a0.y, a0.z, a0.w, a1.x, a1.y, a1.z, a1.w};
        int abase = (akg * 128 + arow) * 8;
        #pragma unroll
        for (int j = 0; j < 8; ++j) {
            float s = av[j] * ascale;
            unsigned short h = f2b(s);
            Ah[abase + j] = h;
            Al[abase + j] = f2b(s - b2f(h));
        }
        __syncthreads();
        // ---- B fragments direct from global (pre-split fragment layout)
        bf16x8 bh[4], bl[4];
        size_t brow = (size_t)((k0 >> 3) + l4) * NC;
        #pragma unroll
        for (int n = 0; n < 4; ++n) {
            size_t gb = (brow + col0 + wc * 64 + n * 16 + l15) * 8;
            bh[n] = *(const bf16x8*)&Bh_g[gb];
            bl[n] = *(const bf16x8*)&Bl_g[gb];
        }
        #pragma unroll
        for (int m = 0; m < 4; ++m) {
            int idx = (l4 * 128 + wr * 64 + m * 16 + l15) * 8;
            bf16x8 ah = *(bf16x8*)&Ah[idx];
            bf16x8 al = *(bf16x8*)&Al[idx];
            #pragma unroll
            for (int n = 0; n < 4; ++n) {
                acc[m][n] = __builtin_amdgcn_mfma_f32_16x16x32_bf16(ah, bh[n], acc[m][n], 0, 0, 0);
                acc[m][n] = __builtin_amdgcn_mfma_f32_16x16x32_bf16(ah, bl[n], acc[m][n], 0, 0, 0);
                acc[m][n] = __builtin_amdgcn_mfma_f32_16x16x32_bf16(al, bh[n], acc[m][n], 0, 0, 0);
            }
        }
        __syncthreads();
    }
    // ---- epilogue: D row = wr*64+m*16+l4*4+r, col = wc*64+n*16+l15
    bool fused = (agg != nullptr);
    #pragma unroll
    for (int m = 0; m < 4; ++m) {
        #pragma unroll
        for (int n = 0; n < 4; ++n) {
            int col = col0 + wc * 64 + n * 16 + l15;
            float bv = bias ? bias[col] : 0.f;
            #pragma unroll
            for (int r = 0; r < 4; ++r) {
                int row = row0 + wr * 64 + m * 16 + l4 * 4 + r;
                float v = acc[m][n][r] + bv;
                if (fused) {
                    v += agg[(size_t)row * aggStride + col];
                    float nm = nmaskArr[row] ? 1.f : 0.f;
                    C[(size_t)row * 256 + col] = fmaxf(v, 0.f) * nm;
                } else {
                    C[(size_t)row * NC + col] = v;
                }
            }
        }
    }
}

// ---------------------------------------------------------------- CSR build
__global__ void count_deg(const int* __restrict__ dst, int* __restrict__ deg) {
    int e = blockIdx.x * 256 + threadIdx.x;
    atomicAdd(&deg[dst[e]], 1);
}

__global__ __launch_bounds__(1024) void scan_deg(const int* __restrict__ deg,
                                                 int* __restrict__ rowStart) {
    __shared__ int part[1024];
    int t = threadIdx.x;
    const int chunk = N_NODES / 1024;      // 50
    int s = t * chunk;
    int sum = 0;
    for (int i = 0; i < chunk; ++i) sum += deg[s + i];
    part[t] = sum;
    __syncthreads();
    for (int d = 1; d < 1024; d <<= 1) {
        int v = (t >= d) ? part[t - d] : 0;
        __syncthreads();
        part[t] += v;
        __syncthreads();
    }
    int excl = (t == 0) ? 0 : part[t - 1];
    for (int i = 0; i < chunk; ++i) { rowStart[s + i] = excl; excl += deg[s + i]; }
    if (t == 1023) rowStart[N_NODES] = part[1023];
}

__global__ void scatter_edges(const int* __restrict__ src, const int* __restrict__ dst,
                              int* __restrict__ cursor, const int* __restrict__ rowStart,
                              int* __restrict__ csrSrc) {
    int e = blockIdx.x * 256 + threadIdx.x;
    int d = dst[e];
    int p = atomicAdd(&cursor[d], 1);
    csrSrc[rowStart[d] + p] = src[e];
}

// ---------------------------------------------------------------- GAT pieces
// one wave per node, 4 nodes per block (amortized prologue)
__global__ __launch_bounds__(256) void gat_att_pw(const float* __restrict__ hfeat,
                                                  const float* __restrict__ att,
                                                  float* __restrict__ aS,
                                                  float* __restrict__ aD) {
    int t = threadIdx.x, w = t >> 6, l = t & 63;
    int i = blockIdx.x * 4 + w;
    int h = l >> 4, g16 = l & 15;
    float4 hv = *(const float4*)&hfeat[i * HDF + l * 4];
    float4 a0 = *(const float4*)&att[l * 4];
    float4 a1 = *(const float4*)&att[256 + l * 4];
    float p0 = hv.x * a0.x + hv.y * a0.y + hv.z * a0.z + hv.w * a0.w;
    float p1 = hv.x * a1.x + hv.y * a1.y + hv.z * a1.z + hv.w * a1.w;
    p0 += __shfl_xor(p0, 1, 64);  p1 += __shfl_xor(p1, 1, 64);
    p0 += __shfl_xor(p0, 2, 64);  p1 += __shfl_xor(p1, 2, 64);
    p0 += __shfl_xor(p0, 4, 64);  p1 += __shfl_xor(p1, 4, 64);
    p0 += __shfl_xor(p0, 8, 64);  p1 += __shfl_xor(p1, 8, 64);
    if (g16 == 0) { aS[i * 4 + h] = p0; aD[i * 4 + h] = p1; }
}

// per-graph-quarter GAT aggregation: 2048 blocks (4/graph), 1 wave per node,
// ~6 nodes/wave serial. edge mask == nmask[src]; self-loop appended.
__global__ __launch_bounds__(256) void gat_edge_pg(
    const float* __restrict__ hfeat, const float* __restrict__ aS, const float* __restrict__ aD,
    const int* __restrict__ rowStart, const int* __restrict__ csrSrc,
    const int* __restrict__ nmask,
    float* __restrict__ aggOut)
{
    int bid = blockIdx.x;
    int xcd = bid & 7, idx = bid >> 3;
    int g = xcd * 64 + (idx >> 2);       // graph -> one XCD
    int qtr = idx & 3;
    int t = threadIdx.x, w = t >> 6, l = t & 63;
    int h = l >> 4, g16 = l & 15;
    __shared__ float sL[4][4][DCAP + 8];
    __shared__ int   sS[4][DCAP + 8];
    int nodeBase = g * S_NODES + qtr * 25;
    for (int u = w; u < 25; u += 4) {
        int i = nodeBase + u;
        if (!nmask[i]) {
            *(float4*)&aggOut[i * HDF + l * 4] = make_float4(0.f, 0.f, 0.f, 0.f);
            continue;
        }
        int rs = rowStart[i];
        int deg = min(rowStart[i + 1] - rs, DCAP);
        float adh = aD[i * 4 + h];
        for (int j = 0; j < deg; ++j) {
            int s_ = csrSrc[rs + j];
            int ok = nmask[s_];
            float lg = aS[s_ * 4 + h] + adh;
            lg = (lg >= 0.f) ? lg : 0.2f * lg;
            if (g16 == 0) sL[w][h][j] = ok ? lg : NEGF;
            if (l == 0) sS[w][j] = ok ? s_ : -1;
        }
        {   // self loop (node alive here)
            float lg = aS[i * 4 + h] + adh;
            lg = (lg >= 0.f) ? lg : 0.2f * lg;
            if (g16 == 0) sL[w][h][deg] = lg;
            if (l == 0) sS[w][deg] = i;
        }
        int tot = deg + 1;
        // wave-local softmax per head (16-lane group)
        float m = NEGF;
        for (int j = g16; j < tot; j += 16) m = fmaxf(m, sL[w][h][j]);
        m = fmaxf(m, __shfl_xor(m, 1, 64));
        m = fmaxf(m, __shfl_xor(m, 2, 64));
        m = fmaxf(m, __shfl_xor(m, 4, 64));
        m = fmaxf(m, __shfl_xor(m, 8, 64));
        float sum = 0.f;
        for (int j = g16; j < tot; j += 16) {
            float lv = sL[w][h][j];
            float e = (lv > -1e29f) ? __expf(lv - m) : 0.f;
            sL[w][h][j] = e;
            sum += e;
        }
        sum += __shfl_xor(sum, 1, 64);
        sum += __shfl_xor(sum, 2, 64);
        sum += __shfl_xor(sum, 4, 64);
        sum += __shfl_xor(sum, 8, 64);
        float inv = 1.f / fmaxf(sum, 1e-16f);
        // gather
        float4 a4 = make_float4(0.f, 0.f, 0.f, 0.f);
        for (int j = 0; j < tot; ++j) {
            int s_ = sS[w][j];
            if (s_ < 0) continue;
            float a = sL[w][h][j] * inv;
            float4 v4 = *(const float4*)&hfeat[s_ * HDF + l * 4];
            a4.x += a * v4.x; a4.y += a * v4.y; a4.z += a * v4.z; a4.w += a * v4.w;
        }
        *(float4*)&aggOut[i * HDF + l * 4] = a4;
    }
}

// per-graph-quarter GT attention: 2048 blocks, 1 wave per node.
// qkv row: [q|k|v]; agg overwrites OWN q-slot (race-free: only this wave
// ever reads/writes q[i]).
__global__ __launch_bounds__(256) void gt_edge_pg(
    float* __restrict__ qkv,
    const int* __restrict__ rowStart, const int* __restrict__ csrSrc,
    const int* __restrict__ nmask)
{
    int bid = blockIdx.x;
    int xcd = bid & 7, idx = bid >> 3;
    int g = xcd * 64 + (idx >> 2);
    int qtr = idx & 3;
    int t = threadIdx.x, w = t >> 6, l = t & 63;
    int h = l >> 4, g16 = l & 15;
    __shared__ float sL[4][4][DCAP + 8];
    __shared__ int   sS[4][DCAP + 8];
    int nodeBase = g * S_NODES + qtr * 25;
    for (int u = w; u < 25; u += 4) {
        int i = nodeBase + u;
        if (!nmask[i]) {
            *(float4*)&qkv[i * 768 + l * 4] = make_float4(0.f, 0.f, 0.f, 0.f);
            continue;
        }
        int rs = rowStart[i];
        int deg = min(rowStart[i + 1] - rs, DCAP);
        float4 q4 = *(const float4*)&qkv[i * 768 + l * 4];
        // logits
        for (int j = 0; j < deg; ++j) {
            int s_ = csrSrc[rs + j];
            int ok = nmask[s_];
            float4 k4 = *(const float4*)&qkv[s_ * 768 + 256 + l * 4];
            float p = q4.x * k4.x + q4.y * k4.y + q4.z * k4.z + q4.w * k4.w;
            p += __shfl_xor(p, 1, 64);
            p += __shfl_xor(p, 2, 64);
            p += __shfl_xor(p, 4, 64);
            p += __shfl_xor(p, 8, 64);
            if (g16 == 0) sL[w][h][j] = ok ? p * 0.125f : NEGF;
            if (l == 0) sS[w][j] = ok ? s_ : -1;
        }
        // wave-local softmax per head
        float m = NEGF;
        for (int j = g16; j < deg; j += 16) m = fmaxf(m, sL[w][h][j]);
        m = fmaxf(m, __shfl_xor(m, 1, 64));
        m = fmaxf(m, __shfl_xor(m, 2, 64));
        m = fmaxf(m, __shfl_xor(m, 4, 64));
        m = fmaxf(m, __shfl_xor(m, 8, 64));
        float sum = 0.f;
        for (int j = g16; j < deg; j += 16) {
            float lv = sL[w][h][j];
            float e = (lv > -1e29f) ? __expf(lv - m) : 0.f;
            sL[w][h][j] = e;
            sum += e;
        }
        sum += __shfl_xor(sum, 1, 64);
        sum += __shfl_xor(sum, 2, 64);
        sum += __shfl_xor(sum, 4, 64);
        sum += __shfl_xor(sum, 8, 64);
        float inv = 1.f / fmaxf(sum, 1e-16f);
        // V gather
        float4 a4 = make_float4(0.f, 0.f, 0.f, 0.f);
        for (int j = 0; j < deg; ++j) {
            int s_ = sS[w][j];
            if (s_ < 0) continue;
            float a = sL[w][h][j] * inv;
            float4 v4 = *(const float4*)&qkv[s_ * 768 + 512 + l * 4];
            a4.x += a * v4.x; a4.y += a * v4.y; a4.z += a * v4.z; a4.w += a * v4.w;
        }
        *(float4*)&qkv[i * 768 + l * 4] = a4;
    }
}

// ---------------------------------------------------- fused score+pool+readout
__global__ __launch_bounds__(256) void spr_kernel(
    const float* __restrict__ x, const float* __restrict__ w,
    float* __restrict__ score, int* __restrict__ nmask, float* __restrict__ acc)
{
    int g = blockIdx.x, t = threadIdx.x;
    int wv = t >> 6, l = t & 63;
    __shared__ float sW[256];
    __shared__ float sRaw[104];
    __shared__ float sFin[104];
    __shared__ int   sKeep[104];
    __shared__ float swn;
    __shared__ int cnt_s;
    if (t == 0) cnt_s = 0;
    sW[t] = w[t];
    __syncthreads();
    if (wv == 0) {
        float dw = 0.f;
        #pragma unroll
        for (int c = 0; c < 4; ++c) { float v = sW[l + c * 64]; dw += v * v; }
        #pragma unroll
        for (int o = 32; o > 0; o >>= 1) dw += __shfl_down(dw, o, 64);
        if (l == 0) swn = sqrtf(dw);
    }
    int base = g * S_NODES;
    for (int u = 0; u < 25; ++u) {
        int nl = wv * 25 + u;
        float dx = 0.f;
        #pragma unroll
        for (int c = 0; c < 4; ++c) {
            int cc = l + c * 64;
            dx += x[(size_t)(base + nl) * HDF + cc] * sW[cc];
        }
        #pragma unroll
        for (int o = 32; o > 0; o >>= 1) dx += __shfl_down(dx, o, 64);
        if (l == 0) sRaw[nl] = dx;
    }
    __syncthreads();
    int alive = 0;
    float ck = -2.0f;
    if (t < S_NODES) {
        float sc = tanhf(sRaw[t] / swn);
        sFin[t] = sc;
        score[base + t] = sc;
        alive = nmask[base + t];
        ck = alive ? sc : -1.5f;
        sRaw[t] = ck;
        if (alive) atomicAdd(&cnt_s, 1);
    }
    __syncthreads();
    int k = (int)ceilf(0.8f * (float)cnt_s);
    if (t < S_NODES) {
        int rank = 0;
        for (int jj = 0; jj < S_NODES; ++jj) {
            float o = sRaw[jj];
            rank += (o > ck || (o == ck && jj < t)) ? 1 : 0;
        }
        int kp = (alive && rank < k) ? 1 : 0;
        sKeep[t] = kp;
        nmask[base + t] = kp;
    }
    __syncthreads();
    float mx = NEGF, sm = 0.f, cnt = 0.f;
    for (int o = 0; o < S_NODES; o += 4) {
        float v0 = x[(size_t)(base + o + 0) * HDF + t];
        float v1 = x[(size_t)(base + o + 1) * HDF + t];
        float v2 = x[(size_t)(base + o + 2) * HDF + t];
        float v3 = x[(size_t)(base + o + 3) * HDF + t];
        if (sKeep[o + 0]) { float v = v0 * sFin[o + 0]; mx = fmaxf(mx, v); sm += v; cnt += 1.f; }
        if (sKeep[o + 1]) { float v = v1 * sFin[o + 1]; mx = fmaxf(mx, v); sm += v; cnt += 1.f; }
        if (sKeep[o + 2]) { float v = v2 * sFin[o + 2]; mx = fmaxf(mx, v); sm += v; cnt += 1.f; }
        if (sKeep[o + 3]) { float v = v3 * sFin[o + 3]; mx = fmaxf(mx, v); sm += v; cnt += 1.f; }
    }
    acc[(size_t)g * 512 + t] += mx;
    acc[(size_t)g * 512 + 256 + t] += sm / fmaxf(cnt, 1.f);
}

// ---------------------------------------------------------------- MLP head
__global__ __launch_bounds__(128) void mlp_kernel(
    const float* __restrict__ acc1, const float* __restrict__ acc2,
    const float* __restrict__ W1, const float* __restrict__ b1,
    const float* __restrict__ W2, const float* __restrict__ b2,
    const float* __restrict__ W3, const float* __restrict__ b3,
    float* __restrict__ out)
{
    int g = blockIdx.x, t = threadIdx.x;
    __shared__ float hrow[1024];
    __shared__ float h1s[128];
    __shared__ float h2s[64];
    __shared__ float o3[10];
    for (int j = t; j < 512; j += 128) {
        hrow[j] = acc1[(size_t)g * 512 + j];
        hrow[512 + j] = acc2[(size_t)g * 512 + j];
    }
    __syncthreads();
    float s = b1[t];
    for (int kx = 0; kx < 1024; ++kx) s += hrow[kx] * W1[(size_t)kx * 128 + t];
    h1s[t] = fmaxf(s, 0.f);
    __syncthreads();
    if (t < 64) {
        float s2 = b2[t];
        for (int kx = 0; kx < 128; ++kx) s2 += h1s[kx] * W2[kx * 64 + t];
        h2s[t] = fmaxf(s2, 0.f);
    }
    __syncthreads();
    if (t < 10) {
        float s3 = b3[t];
        for (int kx = 0; kx < 64; ++kx) s3 += h2s[kx] * W3[kx * 10 + t];
        o3[t] = s3;
    }
    __syncthreads();
    if (t < 10) {
        float m = o3[0];
        for (int j = 1; j < 10; ++j) m = fmaxf(m, o3[j]);
        float se = 0.f;
        for (int j = 0; j < 10; ++j) se += expf(o3[j] - m);
        out[g * 10 + t] = o3[t] - m - logf(se);
    }
}

// ---------------------------------------------------------------- launch
extern "C" void kernel_launch(void* const* d_in, const int* in_sizes, int n_in,
                              void* d_out, int out_size, void* d_ws, size_t ws_size,
                              hipStream_t stream) {
    (void)n_in; (void)out_size; (void)ws_size;
    const float* x0 = (const float*)d_in[0];
    const int* src = (const int*)d_in[1];
    const int* dst = src + N_EDGES;

    bool dictOrder = (in_sizes[7] == 64 * 768);
    const float *gatW[3], *gatAtt[3], *gatB[3], *gatRes[3];
    const float *gtWqkv[3], *gtBqkv[3], *gtWskip[3], *gtBskip[3];
    const float *gatPool, *gtPool;
    if (dictOrder) {
        for (int l = 0; l < 3; ++l) {
            int b = 3 + l * 8;
            gatW[l]    = (const float*)d_in[b + 0];
            gatAtt[l]  = (const float*)d_in[b + 1];
            gatB[l]    = (const float*)d_in[b + 2];
            gatRes[l]  = (const float*)d_in[b + 3];
            gtWqkv[l]  = (const float*)d_in[b + 4];
            gtBqkv[l]  = (const float*)d_in[b + 5];
            gtWskip[l] = (const float*)d_in[b + 6];
            gtBskip[l] = (const float*)d_in[b + 7];
        }
        gatPool = (const float*)d_in[27];
        gtPool  = (const float*)d_in[28];
    } else {
        for (int l = 0; l < 3; ++l) {
            int b = 3 + l * 4;
            gatW[l]   = (const float*)d_in[b + 0];
            gatAtt[l] = (const float*)d_in[b + 1];
            gatB[l]   = (const float*)d_in[b + 2];
            gatRes[l] = (const float*)d_in[b + 3];
            int c = 16 + l * 4;
            gtWqkv[l]  = (const float*)d_in[c + 0];
            gtBqkv[l]  = (const float*)d_in[c + 1];
            gtWskip[l] = (const float*)d_in[c + 2];
            gtBskip[l] = (const float*)d_in[c + 3];
        }
        gatPool = (const float*)d_in[15];
        gtPool  = (const float*)d_in[28];
    }
    const float* lin1W = (const float*)d_in[29];
    const float* lin1b = (const float*)d_in[30];
    const float* lin2W = (const float*)d_in[31];
    const float* lin2b = (const float*)d_in[32];
    const float* lin3W = (const float*)d_in[33];
    const float* lin3b = (const float*)d_in[34];

    char* wsp = (char*)d_ws;
    size_t off = 0;
    auto carve = [&](size_t bytes) -> void* {
        void* p = wsp + off;
        off += (bytes + 255) & ~(size_t)255;
        return p;
    };
    float* bufX   = (float*)carve((size_t)N_NODES * HDF * 4);   // 52.4 MB
    float* bufH   = (float*)carve((size_t)N_NODES * 768 * 4);   // 157.3 MB
    float* aS     = (float*)carve((size_t)N_NODES * 4 * 4);
    float* aD     = (float*)carve((size_t)N_NODES * 4 * 4);
    float* scoreB = (float*)carve((size_t)N_NODES * 4);
    int* nmask    = (int*)carve((size_t)N_NODES * 4);
    int* deg      = (int*)carve((size_t)N_NODES * 4);
    int* rowStart = (int*)carve((size_t)(N_NODES + 1) * 4);
    int* cursor   = (int*)carve((size_t)N_NODES * 4);
    int* csrSrc   = (int*)carve((size_t)N_EDGES * 4);
    float* acc1   = (float*)carve((size_t)N_GRAPHS * 512 * 4);
    float* acc2   = (float*)carve((size_t)N_GRAPHS * 512 * 4);
    const int wElems = 884736;
    unsigned short* whBase = (unsigned short*)carve((size_t)wElems * 2);
    unsigned short* wlBase = (unsigned short*)carve((size_t)wElems * 2);
    float* ysec   = bufH + (size_t)N_NODES * HDF;   // spare 2nd third of bufH (GAT agg)

    // single packed weight-split launch
    unsigned short *WH[12], *WL[12];
    {
        WSplitPack pack;
        int o = 0, maxSz = 0;
        for (int l = 0; l < 3; ++l) {
            int fi = (l == 0) ? 64 : 256;
            int sz[4] = {fi * 256, fi * 256, fi * 768, fi * 256};
            const float* Wp[4] = {gatW[l], gatRes[l], gtWqkv[l], gtWskip[l]};
            int NCs[4] = {256, 256, 768, 256};
            for (int q = 0; q < 4; ++q) {
                int idx = l * 4 + q;
                WH[idx] = whBase + o;
                WL[idx] = wlBase + o;
                pack.d[idx] = {Wp[q], WH[idx], WL[idx], fi, NCs[q]};
                if (sz[q] > maxSz) maxSz = sz[q];
                o += sz[q];
            }
        }
        wsplit_all<<<dim3((maxSz + 255) / 256, 12), 256, 0, stream>>>(pack);
    }

    init_zero<<<(N_GRAPHS * 512) / 256, 256, 0, stream>>>(deg, cursor, acc1, acc2);
    count_deg<<<N_EDGES / 256, 256, 0, stream>>>(dst, deg);
    scan_deg<<<1, 1024, 0, stream>>>(deg, rowStart);
    scatter_edges<<<N_EDGES / 256, 256, 0, stream>>>(src, dst, cursor, rowStart, csrSrc);

    for (int br = 0; br < 2; ++br) {
        bool isGAT = (br == 0);
        float* acc = isGAT ? acc1 : acc2;
        const float* poolW = isGAT ? gatPool : gtPool;
        set_int<<<N_NODES / 256, 256, 0, stream>>>(nmask, 1, N_NODES);
        const float* xcur = x0;
        int fi = 64;
        for (int l = 0; l < 3; ++l) {
            const float* rs = (l == 0) ? nullptr : scoreB;
            const int* rsm = (l == 0) ? nullptr : nmask;
            if (isGAT) {
                mfma_gemm<<<dim3(1, N_NODES / 128), 512, 0, stream>>>(
                    xcur, WH[l * 4 + 0], WL[l * 4 + 0], nullptr, bufH, fi, 256,
                    nullptr, 0, nullptr, rs, rsm);
                gat_att_pw<<<N_NODES / 4, 256, 0, stream>>>(bufH, gatAtt[l], aS, aD);
                gat_edge_pg<<<2048, 256, 0, stream>>>(bufH, aS, aD, rowStart, csrSrc,
                                                      nmask, ysec);
                mfma_gemm<<<dim3(1, N_NODES / 128), 512, 0, stream>>>(
                    xcur, WH[l * 4 + 1], WL[l * 4 + 1], gatB[l], bufX, fi, 256,
                    ysec, HDF, nmask, rs, rsm);
            } else {
                mfma_gemm<<<dim3(3, N_NODES / 128), 512, 0, stream>>>(
                    xcur, WH[l * 4 + 2], WL[l * 4 + 2], gtBqkv[l], bufH, fi, 768,
                    nullptr, 0, nullptr, rs, rsm);
                gt_edge_pg<<<2048, 256, 0, stream>>>(bufH, rowStart, csrSrc, nmask);
                mfma_gemm<<<dim3(1, N_NODES / 128), 512, 0, stream>>>(
                    xcur, WH[l * 4 + 3], WL[l * 4 + 3], gtBskip[l], bufX, fi, 256,
                    bufH /*agg q-slots*/, 768, nmask, rs, rsm);
            }
            spr_kernel<<<N_GRAPHS, 256, 0, stream>>>(bufX, poolW + l * HDF,
                                                     scoreB, nmask, acc);
            xcur = bufX;
            fi = HDF;
        }
    }
    mlp_kernel<<<N_GRAPHS, 128, 0, stream>>>(acc1, acc2, lin1W, lin1b, lin2W, lin2b,
                                             lin3W, lin3b, (float*)d_out);
}

// Round 9
// 1328.919 us; speedup vs baseline: 2.5332x; 1.1304x over previous
//
#include <hip/hip_runtime.h>
#include <hip/hip_bf16.h>
#include <math.h>

#define N_NODES 51200
#define N_GRAPHS 512
#define S_NODES 100
#define N_EDGES 512000
#define HDF 256          // H*D
#define NEGF (-1e30f)
#define DCAP 128         // per-node degree cap (P[Poisson(10)>128] ~ 0)

typedef short bf16x8 __attribute__((ext_vector_type(8)));
typedef float f32x4 __attribute__((ext_vector_type(4)));

__device__ inline unsigned short f2b(float x) {   // fp32 -> bf16 RNE
    union { float f; unsigned u; } v; v.f = x;
    unsigned r = v.u + 0x7FFFu + ((v.u >> 16) & 1u);
    return (unsigned short)(r >> 16);
}
__device__ inline float b2f(unsigned short b) {
    union { float f; unsigned u; } v; v.u = ((unsigned)b) << 16; return v.f;
}

// ---------------------------------------------------------------- util
__global__ void set_int(int* __restrict__ p, int v, int n) {
    int i = blockIdx.x * 256 + threadIdx.x;
    if (i < n) p[i] = v;
}

__global__ void init_zero(int* __restrict__ deg, int* __restrict__ cursor,
                          float* __restrict__ acc1, float* __restrict__ acc2) {
    int i = blockIdx.x * 256 + threadIdx.x;   // grid covers 262144
    if (i < N_NODES) { deg[i] = 0; cursor[i] = 0; }
    acc1[i] = 0.f;
    acc2[i] = 0.f;
}

// pre-split weights: fp32 W[K x NC] -> bf16 hi/lo in MFMA fragment layout
// element (k,c) -> [(k>>3)*NC + c]*8 + (k&7)
struct WSplitDesc { const float* W; unsigned short* Wh; unsigned short* Wl; int K, NC; };
struct WSplitPack { WSplitDesc d[12]; };
__global__ void wsplit_all(WSplitPack p) {
    WSplitDesc d = p.d[blockIdx.y];
    int idx = blockIdx.x * 256 + threadIdx.x;
    if (idx >= d.K * d.NC) return;
    int k = idx / d.NC, c = idx - k * d.NC;
    float v = d.W[idx];
    unsigned short h = f2b(v);
    int o = ((k >> 3) * d.NC + c) * 8 + (k & 7);
    d.Wh[o] = h;
    d.Wl[o] = f2b(v - b2f(h));
}

// ------------------------------------------------- split-bf16 MFMA GEMM
// B fragments read DIRECTLY from pre-split global fragment layout
// (contiguous 16B per lane) -> no B LDS, 16 KB LDS/block.
__global__ __launch_bounds__(512) void mfma_gemm(
    const float* __restrict__ A,
    const unsigned short* __restrict__ Bh_g, const unsigned short* __restrict__ Bl_g,
    const float* __restrict__ bias, float* __restrict__ C,
    int K, int NC,
    const float* __restrict__ agg, int aggStride,
    const int* __restrict__ nmaskArr,
    const float* __restrict__ rowScale, const int* __restrict__ rsMask)
{
    __shared__ unsigned short Ah[4 * 128 * 8];   // [kg][row][j]
    __shared__ unsigned short Al[4 * 128 * 8];
    int row0 = blockIdx.y * 128, col0 = blockIdx.x * 256;
    int t = threadIdx.x;
    int lane = t & 63, w = t >> 6;
    int wr = w >> 2, wc = w & 3;          // 2 x 4 wave grid
    int l15 = lane & 15, l4 = lane >> 4;
    f32x4 acc[4][4];
    #pragma unroll
    for (int m = 0; m < 4; ++m)
        #pragma unroll
        for (int n = 0; n < 4; ++n) acc[m][n] = (f32x4){0.f, 0.f, 0.f, 0.f};

    int arow = t & 127, akg = t >> 7;     // A staging task (row, kgroup)
    float ascale = 1.f;
    if (rowScale) ascale = rsMask[row0 + arow] ? rowScale[row0 + arow] : 0.f;

    for (int k0 = 0; k0 < K; k0 += 32) {
        // ---- stage A (fp32 -> hi/lo bf16), folded top-k row scale
        const float* ap = A + (size_t)(row0 + arow) * K + k0 + akg * 8;
        float4 a0 = *(const float4*)ap;
        float4 a1 = *(const float4*)(ap + 4);
        float av[8] = {a0.x, a0.y, a0.z, a0.w, a1.x, a1.y, a1.z, a1.w};
        int abase = (akg * 128 + arow) * 8;
        #pragma unroll
        for (int j = 0; j < 8; ++j) {
            float s = av[j] * ascale;
            unsigned short h = f2b(s);
            Ah[abase + j] = h;
            Al[abase + j] = f2b(s - b2f(h));
        }
        __syncthreads();
        // ---- B fragments direct from global (pre-split fragment layout)
        bf16x8 bh[4], bl[4];
        size_t brow = (size_t)((k0 >> 3) + l4) * NC;
        #pragma unroll
        for (int n = 0; n < 4; ++n) {
            size_t gb = (brow + col0 + wc * 64 + n * 16 + l15) * 8;
            bh[n] = *(const bf16x8*)&Bh_g[gb];
            bl[n] = *(const bf16x8*)&Bl_g[gb];
        }
        #pragma unroll
        for (int m = 0; m < 4; ++m) {
            int idx = (l4 * 128 + wr * 64 + m * 16 + l15) * 8;
            bf16x8 ah = *(bf16x8*)&Ah[idx];
            bf16x8 al = *(bf16x8*)&Al[idx];
            #pragma unroll
            for (int n = 0; n < 4; ++n) {
                acc[m][n] = __builtin_amdgcn_mfma_f32_16x16x32_bf16(ah, bh[n], acc[m][n], 0, 0, 0);
                acc[m][n] = __builtin_amdgcn_mfma_f32_16x16x32_bf16(ah, bl[n], acc[m][n], 0, 0, 0);
                acc[m][n] = __builtin_amdgcn_mfma_f32_16x16x32_bf16(al, bh[n], acc[m][n], 0, 0, 0);
            }
        }
        __syncthreads();
    }
    // ---- epilogue
    bool fused = (agg != nullptr);
    #pragma unroll
    for (int m = 0; m < 4; ++m) {
        #pragma unroll
        for (int n = 0; n < 4; ++n) {
            int col = col0 + wc * 64 + n * 16 + l15;
            float bv = bias ? bias[col] : 0.f;
            #pragma unroll
            for (int r = 0; r < 4; ++r) {
                int row = row0 + wr * 64 + m * 16 + l4 * 4 + r;
                float v = acc[m][n][r] + bv;
                if (fused) {
                    v += agg[(size_t)row * aggStride + col];
                    float nm = nmaskArr[row] ? 1.f : 0.f;
                    C[(size_t)row * 256 + col] = fmaxf(v, 0.f) * nm;
                } else {
                    C[(size_t)row * NC + col] = v;
                }
            }
        }
    }
}

// ---------------------------------------------------------------- CSR build
__global__ void count_deg(const int* __restrict__ dst, int* __restrict__ deg) {
    int e = blockIdx.x * 256 + threadIdx.x;
    atomicAdd(&deg[dst[e]], 1);
}

__global__ __launch_bounds__(1024) void scan_deg(const int* __restrict__ deg,
                                                 int* __restrict__ rowStart) {
    __shared__ int part[1024];
    int t = threadIdx.x;
    const int chunk = N_NODES / 1024;      // 50
    int s = t * chunk;
    int sum = 0;
    for (int i = 0; i < chunk; ++i) sum += deg[s + i];
    part[t] = sum;
    __syncthreads();
    for (int d = 1; d < 1024; d <<= 1) {
        int v = (t >= d) ? part[t - d] : 0;
        __syncthreads();
        part[t] += v;
        __syncthreads();
    }
    int excl = (t == 0) ? 0 : part[t - 1];
    for (int i = 0; i < chunk; ++i) { rowStart[s + i] = excl; excl += deg[s + i]; }
    if (t == 1023) rowStart[N_NODES] = part[1023];
}

__global__ void scatter_edges(const int* __restrict__ src, const int* __restrict__ dst,
                              int* __restrict__ cursor, const int* __restrict__ rowStart,
                              int* __restrict__ csrSrc) {
    int e = blockIdx.x * 256 + threadIdx.x;
    int d = dst[e];
    int p = atomicAdd(&cursor[d], 1);
    csrSrc[rowStart[d] + p] = src[e];
}

// ---------------------------------------------------------------- GAT pieces
// one wave per node, 4 nodes per block
__global__ __launch_bounds__(256) void gat_att_pw(const float* __restrict__ hfeat,
                                                  const float* __restrict__ att,
                                                  float* __restrict__ aS,
                                                  float* __restrict__ aD) {
    int t = threadIdx.x, w = t >> 6, l = t & 63;
    int i = blockIdx.x * 4 + w;
    int h = l >> 4, g16 = l & 15;
    float4 hv = *(const float4*)&hfeat[i * HDF + l * 4];
    float4 a0 = *(const float4*)&att[l * 4];
    float4 a1 = *(const float4*)&att[256 + l * 4];
    float p0 = hv.x * a0.x + hv.y * a0.y + hv.z * a0.z + hv.w * a0.w;
    float p1 = hv.x * a1.x + hv.y * a1.y + hv.z * a1.z + hv.w * a1.w;
    p0 += __shfl_xor(p0, 1, 64);  p1 += __shfl_xor(p1, 1, 64);
    p0 += __shfl_xor(p0, 2, 64);  p1 += __shfl_xor(p1, 2, 64);
    p0 += __shfl_xor(p0, 4, 64);  p1 += __shfl_xor(p1, 4, 64);
    p0 += __shfl_xor(p0, 8, 64);  p1 += __shfl_xor(p1, 8, 64);
    if (g16 == 0) { aS[i * 4 + h] = p0; aD[i * 4 + h] = p1; }
}

// GAT aggregation: 12800 blocks x 4 waves, 1 node per wave; streaming window
// keeps ~10 graphs per XCD in L2. edge mask == nmask[src]; self-loop appended.
__global__ __launch_bounds__(256) void gat_edge_pg(
    const float* __restrict__ hfeat, const float* __restrict__ aS, const float* __restrict__ aD,
    const int* __restrict__ rowStart, const int* __restrict__ csrSrc,
    const int* __restrict__ nmask,
    float* __restrict__ aggOut)
{
    int bid = blockIdx.x;
    int t = threadIdx.x, w = t >> 6, l = t & 63;
    int i = (bid & 7) * (N_NODES / 8) + (bid >> 3) * 4 + w;   // XCD-streamed
    int h = l >> 4, g16 = l & 15;
    __shared__ float sL[4][4][DCAP + 8];
    __shared__ int   sS[4][DCAP + 8];
    if (!nmask[i]) {
        *(float4*)&aggOut[i * HDF + l * 4] = make_float4(0.f, 0.f, 0.f, 0.f);
        return;
    }
    int rs = rowStart[i];
    int deg = min(rowStart[i + 1] - rs, DCAP);
    float adh = aD[i * 4 + h];
    for (int j = 0; j < deg; ++j) {
        int s_ = csrSrc[rs + j];
        int ok = nmask[s_];
        float lg = aS[s_ * 4 + h] + adh;
        lg = (lg >= 0.f) ? lg : 0.2f * lg;
        if (g16 == 0) sL[w][h][j] = ok ? lg : NEGF;
        if (l == 0) sS[w][j] = ok ? s_ : -1;
    }
    {   // self loop (node alive here)
        float lg = aS[i * 4 + h] + adh;
        lg = (lg >= 0.f) ? lg : 0.2f * lg;
        if (g16 == 0) sL[w][h][deg] = lg;
        if (l == 0) sS[w][deg] = i;
    }
    int tot = deg + 1;
    // wave-local softmax per head (16-lane group)
    float m = NEGF;
    for (int j = g16; j < tot; j += 16) m = fmaxf(m, sL[w][h][j]);
    m = fmaxf(m, __shfl_xor(m, 1, 64));
    m = fmaxf(m, __shfl_xor(m, 2, 64));
    m = fmaxf(m, __shfl_xor(m, 4, 64));
    m = fmaxf(m, __shfl_xor(m, 8, 64));
    float sum = 0.f;
    for (int j = g16; j < tot; j += 16) {
        float lv = sL[w][h][j];
        float e = (lv > -1e29f) ? __expf(lv - m) : 0.f;
        sL[w][h][j] = e;
        sum += e;
    }
    sum += __shfl_xor(sum, 1, 64);
    sum += __shfl_xor(sum, 2, 64);
    sum += __shfl_xor(sum, 4, 64);
    sum += __shfl_xor(sum, 8, 64);
    float inv = 1.f / fmaxf(sum, 1e-16f);
    // gather
    float4 a4 = make_float4(0.f, 0.f, 0.f, 0.f);
    for (int j = 0; j < tot; ++j) {
        int s_ = sS[w][j];
        if (s_ < 0) continue;
        float a = sL[w][h][j] * inv;
        float4 v4 = *(const float4*)&hfeat[s_ * HDF + l * 4];
        a4.x += a * v4.x; a4.y += a * v4.y; a4.z += a * v4.z; a4.w += a * v4.w;
    }
    *(float4*)&aggOut[i * HDF + l * 4] = a4;
}

// GT attention: 12800 blocks x 4 waves, 1 node per wave; streaming window.
// qkv row: [q|k|v]; agg overwrites OWN q-slot (race-free).
__global__ __launch_bounds__(256) void gt_edge_pg(
    float* __restrict__ qkv,
    const int* __restrict__ rowStart, const int* __restrict__ csrSrc,
    const int* __restrict__ nmask)
{
    int bid = blockIdx.x;
    int t = threadIdx.x, w = t >> 6, l = t & 63;
    int i = (bid & 7) * (N_NODES / 8) + (bid >> 3) * 4 + w;   // XCD-streamed
    int h = l >> 4, g16 = l & 15;
    __shared__ float sL[4][4][DCAP + 8];
    __shared__ int   sS[4][DCAP + 8];
    if (!nmask[i]) {
        *(float4*)&qkv[i * 768 + l * 4] = make_float4(0.f, 0.f, 0.f, 0.f);
        return;
    }
    int rs = rowStart[i];
    int deg = min(rowStart[i + 1] - rs, DCAP);
    float4 q4 = *(const float4*)&qkv[i * 768 + l * 4];
    // logits
    for (int j = 0; j < deg; ++j) {
        int s_ = csrSrc[rs + j];
        int ok = nmask[s_];
        float4 k4 = *(const float4*)&qkv[s_ * 768 + 256 + l * 4];
        float p = q4.x * k4.x + q4.y * k4.y + q4.z * k4.z + q4.w * k4.w;
        p += __shfl_xor(p, 1, 64);
        p += __shfl_xor(p, 2, 64);
        p += __shfl_xor(p, 4, 64);
        p += __shfl_xor(p, 8, 64);
        if (g16 == 0) sL[w][h][j] = ok ? p * 0.125f : NEGF;
        if (l == 0) sS[w][j] = ok ? s_ : -1;
    }
    // wave-local softmax per head
    float m = NEGF;
    for (int j = g16; j < deg; j += 16) m = fmaxf(m, sL[w][h][j]);
    m = fmaxf(m, __shfl_xor(m, 1, 64));
    m = fmaxf(m, __shfl_xor(m, 2, 64));
    m = fmaxf(m, __shfl_xor(m, 4, 64));
    m = fmaxf(m, __shfl_xor(m, 8, 64));
    float sum = 0.f;
    for (int j = g16; j < deg; j += 16) {
        float lv = sL[w][h][j];
        float e = (lv > -1e29f) ? __expf(lv - m) : 0.f;
        sL[w][h][j] = e;
        sum += e;
    }
    sum += __shfl_xor(sum, 1, 64);
    sum += __shfl_xor(sum, 2, 64);
    sum += __shfl_xor(sum, 4, 64);
    sum += __shfl_xor(sum, 8, 64);
    float inv = 1.f / fmaxf(sum, 1e-16f);
    // V gather
    float4 a4 = make_float4(0.f, 0.f, 0.f, 0.f);
    for (int j = 0; j < deg; ++j) {
        int s_ = sS[w][j];
        if (s_ < 0) continue;
        float a = sL[w][h][j] * inv;
        float4 v4 = *(const float4*)&qkv[s_ * 768 + 512 + l * 4];
        a4.x += a * v4.x; a4.y += a * v4.y; a4.z += a * v4.z; a4.w += a * v4.w;
    }
    *(float4*)&qkv[i * 768 + l * 4] = a4;
}

// ---------------------------------------------------- fused score+pool+readout
__global__ __launch_bounds__(256) void spr_kernel(
    const float* __restrict__ x, const float* __restrict__ w,
    float* __restrict__ score, int* __restrict__ nmask, float* __restrict__ acc)
{
    int g = blockIdx.x, t = threadIdx.x;
    int wv = t >> 6, l = t & 63;
    __shared__ float sW[256];
    __shared__ float sRaw[104];
    __shared__ float sFin[104];
    __shared__ int   sKeep[104];
    __shared__ float swn;
    __shared__ int cnt_s;
    if (t == 0) cnt_s = 0;
    sW[t] = w[t];
    __syncthreads();
    if (wv == 0) {
        float dw = 0.f;
        #pragma unroll
        for (int c = 0; c < 4; ++c) { float v = sW[l + c * 64]; dw += v * v; }
        #pragma unroll
        for (int o = 32; o > 0; o >>= 1) dw += __shfl_down(dw, o, 64);
        if (l == 0) swn = sqrtf(dw);
    }
    int base = g * S_NODES;
    for (int u = 0; u < 25; ++u) {
        int nl = wv * 25 + u;
        float dx = 0.f;
        #pragma unroll
        for (int c = 0; c < 4; ++c) {
            int cc = l + c * 64;
            dx += x[(size_t)(base + nl) * HDF + cc] * sW[cc];
        }
        #pragma unroll
        for (int o = 32; o > 0; o >>= 1) dx += __shfl_down(dx, o, 64);
        if (l == 0) sRaw[nl] = dx;
    }
    __syncthreads();
    int alive = 0;
    float ck = -2.0f;
    if (t < S_NODES) {
        float sc = tanhf(sRaw[t] / swn);
        sFin[t] = sc;
        score[base + t] = sc;
        alive = nmask[base + t];
        ck = alive ? sc : -1.5f;
        sRaw[t] = ck;
        if (alive) atomicAdd(&cnt_s, 1);
    }
    __syncthreads();
    int k = (int)ceilf(0.8f * (float)cnt_s);
    if (t < S_NODES) {
        int rank = 0;
        for (int jj = 0; jj < S_NODES; ++jj) {
            float o = sRaw[jj];
            rank += (o > ck || (o == ck && jj < t)) ? 1 : 0;
        }
        int kp = (alive && rank < k) ? 1 : 0;
        sKeep[t] = kp;
        nmask[base + t] = kp;
    }
    __syncthreads();
    float mx = NEGF, sm = 0.f, cnt = 0.f;
    for (int o = 0; o < S_NODES; o += 4) {
        float v0 = x[(size_t)(base + o + 0) * HDF + t];
        float v1 = x[(size_t)(base + o + 1) * HDF + t];
        float v2 = x[(size_t)(base + o + 2) * HDF + t];
        float v3 = x[(size_t)(base + o + 3) * HDF + t];
        if (sKeep[o + 0]) { float v = v0 * sFin[o + 0]; mx = fmaxf(mx, v); sm += v; cnt += 1.f; }
        if (sKeep[o + 1]) { float v = v1 * sFin[o + 1]; mx = fmaxf(mx, v); sm += v; cnt += 1.f; }
        if (sKeep[o + 2]) { float v = v2 * sFin[o + 2]; mx = fmaxf(mx, v); sm += v; cnt += 1.f; }
        if (sKeep[o + 3]) { float v = v3 * sFin[o + 3]; mx = fmaxf(mx, v); sm += v; cnt += 1.f; }
    }
    acc[(size_t)g * 512 + t] += mx;
    acc[(size_t)g * 512 + 256 + t] += sm / fmaxf(cnt, 1.f);
}

// ---------------------------------------------------------------- MLP head
__global__ __launch_bounds__(128) void mlp_kernel(
    const float* __restrict__ acc1, const float* __restrict__ acc2,
    const float* __restrict__ W1, const float* __restrict__ b1,
    const float* __restrict__ W2, const float* __restrict__ b2,
    const float* __restrict__ W3, const float* __restrict__ b3,
    float* __restrict__ out)
{
    int g = blockIdx.x, t = threadIdx.x;
    __shared__ float hrow[1024];
    __shared__ float h1s[128];
    __shared__ float h2s[64];
    __shared__ float o3[10];
    for (int j = t; j < 512; j += 128) {
        hrow[j] = acc1[(size_t)g * 512 + j];
        hrow[512 + j] = acc2[(size_t)g * 512 + j];
    }
    __syncthreads();
    float s = b1[t];
    for (int kx = 0; kx < 1024; ++kx) s += hrow[kx] * W1[(size_t)kx * 128 + t];
    h1s[t] = fmaxf(s, 0.f);
    __syncthreads();
    if (t < 64) {
        float s2 = b2[t];
        for (int kx = 0; kx < 128; ++kx) s2 += h1s[kx] * W2[kx * 64 + t];
        h2s[t] = fmaxf(s2, 0.f);
    }
    __syncthreads();
    if (t < 10) {
        float s3 = b3[t];
        for (int kx = 0; kx < 64; ++kx) s3 += h2s[kx] * W3[kx * 10 + t];
        o3[t] = s3;
    }
    __syncthreads();
    if (t < 10) {
        float m = o3[0];
        for (int j = 1; j < 10; ++j) m = fmaxf(m, o3[j]);
        float se = 0.f;
        for (int j = 0; j < 10; ++j) se += expf(o3[j] - m);
        out[g * 10 + t] = o3[t] - m - logf(se);
    }
}

// ---------------------------------------------------------------- launch
extern "C" void kernel_launch(void* const* d_in, const int* in_sizes, int n_in,
                              void* d_out, int out_size, void* d_ws, size_t ws_size,
                              hipStream_t stream) {
    (void)n_in; (void)out_size; (void)ws_size;
    const float* x0 = (const float*)d_in[0];
    const int* src = (const int*)d_in[1];
    const int* dst = src + N_EDGES;

    bool dictOrder = (in_sizes[7] == 64 * 768);
    const float *gatW[3], *gatAtt[3], *gatB[3], *gatRes[3];
    const float *gtWqkv[3], *gtBqkv[3], *gtWskip[3], *gtBskip[3];
    const float *gatPool, *gtPool;
    if (dictOrder) {
        for (int l = 0; l < 3; ++l) {
            int b = 3 + l * 8;
            gatW[l]    = (const float*)d_in[b + 0];
            gatAtt[l]  = (const float*)d_in[b + 1];
            gatB[l]    = (const float*)d_in[b + 2];
            gatRes[l]  = (const float*)d_in[b + 3];
            gtWqkv[l]  = (const float*)d_in[b + 4];
            gtBqkv[l]  = (const float*)d_in[b + 5];
            gtWskip[l] = (const float*)d_in[b + 6];
            gtBskip[l] = (const float*)d_in[b + 7];
        }
        gatPool = (const float*)d_in[27];
        gtPool  = (const float*)d_in[28];
    } else {
        for (int l = 0; l < 3; ++l) {
            int b = 3 + l * 4;
            gatW[l]   = (const float*)d_in[b + 0];
            gatAtt[l] = (const float*)d_in[b + 1];
            gatB[l]   = (const float*)d_in[b + 2];
            gatRes[l] = (const float*)d_in[b + 3];
            int c = 16 + l * 4;
            gtWqkv[l]  = (const float*)d_in[c + 0];
            gtBqkv[l]  = (const float*)d_in[c + 1];
            gtWskip[l] = (const float*)d_in[c + 2];
            gtBskip[l] = (const float*)d_in[c + 3];
        }
        gatPool = (const float*)d_in[15];
        gtPool  = (const float*)d_in[28];
    }
    const float* lin1W = (const float*)d_in[29];
    const float* lin1b = (const float*)d_in[30];
    const float* lin2W = (const float*)d_in[31];
    const float* lin2b = (const float*)d_in[32];
    const float* lin3W = (const float*)d_in[33];
    const float* lin3b = (const float*)d_in[34];

    char* wsp = (char*)d_ws;
    size_t off = 0;
    auto carve = [&](size_t bytes) -> void* {
        void* p = wsp + off;
        off += (bytes + 255) & ~(size_t)255;
        return p;
    };
    float* bufX   = (float*)carve((size_t)N_NODES * HDF * 4);   // 52.4 MB
    float* bufH   = (float*)carve((size_t)N_NODES * 768 * 4);   // 157.3 MB
    float* aS     = (float*)carve((size_t)N_NODES * 4 * 4);
    float* aD     = (float*)carve((size_t)N_NODES * 4 * 4);
    float* scoreB = (float*)carve((size_t)N_NODES * 4);
    int* nmask    = (int*)carve((size_t)N_NODES * 4);
    int* deg      = (int*)carve((size_t)N_NODES * 4);
    int* rowStart = (int*)carve((size_t)(N_NODES + 1) * 4);
    int* cursor   = (int*)carve((size_t)N_NODES * 4);
    int* csrSrc   = (int*)carve((size_t)N_EDGES * 4);
    float* acc1   = (float*)carve((size_t)N_GRAPHS * 512 * 4);
    float* acc2   = (float*)carve((size_t)N_GRAPHS * 512 * 4);
    const int wElems = 884736;
    unsigned short* whBase = (unsigned short*)carve((size_t)wElems * 2);
    unsigned short* wlBase = (unsigned short*)carve((size_t)wElems * 2);
    float* ysec   = bufH + (size_t)N_NODES * HDF;   // spare 2nd third of bufH (GAT agg)

    // single packed weight-split launch
    unsigned short *WH[12], *WL[12];
    {
        WSplitPack pack;
        int o = 0, maxSz = 0;
        for (int l = 0; l < 3; ++l) {
            int fi = (l == 0) ? 64 : 256;
            int sz[4] = {fi * 256, fi * 256, fi * 768, fi * 256};
            const float* Wp[4] = {gatW[l], gatRes[l], gtWqkv[l], gtWskip[l]};
            int NCs[4] = {256, 256, 768, 256};
            for (int q = 0; q < 4; ++q) {
                int idx = l * 4 + q;
                WH[idx] = whBase + o;
                WL[idx] = wlBase + o;
                pack.d[idx] = {Wp[q], WH[idx], WL[idx], fi, NCs[q]};
                if (sz[q] > maxSz) maxSz = sz[q];
                o += sz[q];
            }
        }
        wsplit_all<<<dim3((maxSz + 255) / 256, 12), 256, 0, stream>>>(pack);
    }

    init_zero<<<(N_GRAPHS * 512) / 256, 256, 0, stream>>>(deg, cursor, acc1, acc2);
    count_deg<<<N_EDGES / 256, 256, 0, stream>>>(dst, deg);
    scan_deg<<<1, 1024, 0, stream>>>(deg, rowStart);
    scatter_edges<<<N_EDGES / 256, 256, 0, stream>>>(src, dst, cursor, rowStart, csrSrc);

    for (int br = 0; br < 2; ++br) {
        bool isGAT = (br == 0);
        float* acc = isGAT ? acc1 : acc2;
        const float* poolW = isGAT ? gatPool : gtPool;
        set_int<<<N_NODES / 256, 256, 0, stream>>>(nmask, 1, N_NODES);
        const float* xcur = x0;
        int fi = 64;
        for (int l = 0; l < 3; ++l) {
            const float* rs = (l == 0) ? nullptr : scoreB;
            const int* rsm = (l == 0) ? nullptr : nmask;
            if (isGAT) {
                mfma_gemm<<<dim3(1, N_NODES / 128), 512, 0, stream>>>(
                    xcur, WH[l * 4 + 0], WL[l * 4 + 0], nullptr, bufH, fi, 256,
                    nullptr, 0, nullptr, rs, rsm);
                gat_att_pw<<<N_NODES / 4, 256, 0, stream>>>(bufH, gatAtt[l], aS, aD);
                gat_edge_pg<<<N_NODES / 4, 256, 0, stream>>>(bufH, aS, aD, rowStart,
                                                             csrSrc, nmask, ysec);
                mfma_gemm<<<dim3(1, N_NODES / 128), 512, 0, stream>>>(
                    xcur, WH[l * 4 + 1], WL[l * 4 + 1], gatB[l], bufX, fi, 256,
                    ysec, HDF, nmask, rs, rsm);
            } else {
                mfma_gemm<<<dim3(3, N_NODES / 128), 512, 0, stream>>>(
                    xcur, WH[l * 4 + 2], WL[l * 4 + 2], gtBqkv[l], bufH, fi, 768,
                    nullptr, 0, nullptr, rs, rsm);
                gt_edge_pg<<<N_NODES / 4, 256, 0, stream>>>(bufH, rowStart, csrSrc,
                                                            nmask);
                mfma_gemm<<<dim3(1, N_NODES / 128), 512, 0, stream>>>(
                    xcur, WH[l * 4 + 3], WL[l * 4 + 3], gtBskip[l], bufX, fi, 256,
                    bufH /*agg q-slots*/, 768, nmask, rs, rsm);
            }
            spr_kernel<<<N_GRAPHS, 256, 0, stream>>>(bufX, poolW + l * HDF,
                                                     scoreB, nmask, acc);
            xcur = bufX;
            fi = HDF;
        }
    }
    mlp_kernel<<<N_GRAPHS, 128, 0, stream>>>(acc1, acc2, lin1W, lin1b, lin2W, lin2b,
                                             lin3W, lin3b, (float*)d_out);
}